// Round 11
// baseline (374.401 us; speedup 1.0000x reference)
//
#include <hip/hip_runtime.h>
#include <stdint.h>

// Shapes (fixed): B=4 L=2048 D=2048 H=16 KVH=4 HD=128 M=16 T=2032
typedef unsigned short u16;
typedef short s8v __attribute__((ext_vector_type(8)));   // 8 bf16 (4 VGPR) MFMA frag
typedef float f4v __attribute__((ext_vector_type(4)));   // 16x16 MFMA accum
typedef float f16v __attribute__((ext_vector_type(16))); // 32x32 MFMA accum

typedef __attribute__((address_space(1))) char gchar;
typedef __attribute__((address_space(3))) char lchar;

static __device__ __forceinline__ u16 f2bf(float f) {
  uint32_t x = __float_as_uint(f);
  x += 0x7fffu + ((x >> 16) & 1u);            // RNE
  return (u16)(x >> 16);
}
static __device__ __forceinline__ float bf2f(u16 u) {
  return __uint_as_float(((uint32_t)u) << 16);
}
// async global->LDS, 16B per lane. LDS dest must be wave-linear (base + lane*16).
static __device__ __forceinline__ void gload_lds16(const void* g, void* l) {
  __builtin_amdgcn_global_load_lds((gchar*)(uintptr_t)g,
                                   (lchar*)(uint32_t)(uintptr_t)l, 16, 0, 0);
}

// ---------------- fp32 -> bf16 convert (vectorized) ----------------
__global__ __launch_bounds__(256) void cvt_bf16(const float4* __restrict__ src,
                                                uint2* __restrict__ dst, int n4) {
  int i = blockIdx.x * 256 + threadIdx.x;
  int st = gridDim.x * 256;
  for (; i < n4; i += st) {
    float4 v = src[i];
    uint2 o;
    o.x = (uint32_t)f2bf(v.x) | ((uint32_t)f2bf(v.y) << 16);
    o.y = (uint32_t)f2bf(v.z) | ((uint32_t)f2bf(v.w) << 16);
    dst[i] = o;
  }
}

// all 4 weight matrices in one launch; dst regions are contiguous in ws.
__global__ __launch_bounds__(256) void cvt_bf16_w(const float4* __restrict__ s0,
                                                  const float4* __restrict__ s1,
                                                  const float4* __restrict__ s2,
                                                  const float4* __restrict__ s3,
                                                  uint2* __restrict__ dst) {
  // boundaries in float4 units: wq 1048576 | wk 262144 | wv 262144 | wp 1048576
  int i = blockIdx.x * 256 + threadIdx.x;
  int st = gridDim.x * 256;
  for (; i < 2621440; i += st) {
    const float4* s;
    int off;
    if (i < 1048576)      { s = s0; off = i; }
    else if (i < 1310720) { s = s1; off = i - 1048576; }
    else if (i < 1572864) { s = s2; off = i - 1310720; }
    else                  { s = s3; off = i - 1572864; }
    float4 v = s[off];
    uint2 o;
    o.x = (uint32_t)f2bf(v.x) | ((uint32_t)f2bf(v.y) << 16);
    o.y = (uint32_t)f2bf(v.z) | ((uint32_t)f2bf(v.w) << 16);
    dst[i] = o;
  }
}

// ---------------- RoPE cos/sin table: [T=2032][64] ----------------
__global__ __launch_bounds__(256) void rope_table(float* __restrict__ tc,
                                                  float* __restrict__ ts) {
  int i = blockIdx.x * 256 + threadIdx.x;
  if (i >= 2032 * 64) return;
  int t = i >> 6, f = i & 63;
  float invf = 1.0f / powf(10000.0f, (float)f * (1.0f / 64.0f)); // accurate powf
  float ang = (float)t * invf;
  float s, c;
  sincosf(ang, &s, &c);                                           // accurate sincos
  tc[i] = c;
  ts[i] = s;
}

// ---------------- 256xBN deep-pipelined NT GEMM, k-half region staging ----------------
// (unchanged from R10 — see R10 notes; ~<108us per GEMM, conflicts 0)
template <int BN, int OUT>
__global__ __launch_bounds__(512, 2) void gemm_nt(
    const u16* __restrict__ A, const u16* __restrict__ Wt,
    u16* __restrict__ Oa, u16* __restrict__ Ob2, float* __restrict__ OF) {
  constexpr int MI = (BN == 256) ? 8 : 4;      // wave M-frags (wave-tile MIx16 x 64)
  constexpr int BLOADS = (BN == 256) ? 2 : 1;  // B stage loads/thread/part
  __shared__ u16 lA[2][2][256 * 32];
  __shared__ u16 lB[2][2][BN * 32];
  const int tid = threadIdx.x;
  const int lane = tid & 63, wid = tid >> 6;
  const int wr = (BN == 256) ? (wid >> 2) : (wid >> 1);
  const int wc = (BN == 256) ? (wid & 3) : (wid & 1);
  const int l15 = lane & 15, l4 = lane >> 4;

  const int bid = blockIdx.x;
  const int swz = (bid & 7) * 32 + (bid >> 3);   // XCD chunk (grid always 256)
  const int bn = swz >> 5, bm = swz & 31;        // col-major: 1 B-panel per XCD
  const int m0 = bm * 256;
  const int n0r = bn * BN;

  auto stage_part = [&](int kt, int bs, int ks) {
    const int kb = kt * 64 + ks * 32;
#pragma unroll
    for (int c = 0; c < 2; ++c) {                // A region: 1024 chunks
      int cidx = tid + c * 512;
      int r = cidx >> 2, q = cidx & 3;
      int cc = q ^ ((r >> 2) & 3);
      gload_lds16(A + (size_t)(m0 + r) * 2048 + kb + cc * 8,
                  &lA[bs][ks][cidx * 8]);
    }
#pragma unroll
    for (int c = 0; c < BLOADS; ++c) {           // B region: BN*4 chunks
      int cidx = tid + c * 512;
      int r = cidx >> 2, q = cidx & 3;
      int cc = q ^ ((r >> 2) & 3);
      gload_lds16(Wt + (size_t)(n0r + r) * 2048 + kb + cc * 8,
                  &lB[bs][ks][cidx * 8]);
    }
  };
  auto roff = [&](int fr, int c) {               // u16 index within a region
    return (fr * 4 + (c ^ ((fr >> 2) & 3))) * 8;
  };

  const f4v Z4 = {0.f, 0.f, 0.f, 0.f};
  f4v acc[MI][4];
#pragma unroll
  for (int i = 0; i < MI; i++)
#pragma unroll
    for (int j = 0; j < 4; j++) acc[i][j] = Z4;

  // prologue: tiles 0,1 fully staged (2L loads/thread outstanding)
  stage_part(0, 0, 0); stage_part(0, 0, 1);
  stage_part(1, 1, 0); stage_part(1, 1, 1);

  const int NT = 32;                 // 2048 / 64
  for (int t = 0; t < NT; ++t) {
    const int bs = t & 1;
    if (t + 1 < NT) {                // drain tile t's L loads, keep t+1's in flight
      if constexpr (BN == 256) asm volatile("s_waitcnt vmcnt(8)" ::: "memory");
      else                     asm volatile("s_waitcnt vmcnt(6)" ::: "memory");
    } else {
      asm volatile("s_waitcnt vmcnt(0)" ::: "memory");
    }
    asm volatile("s_barrier" ::: "memory");      // RAW: ALL waves' tile t landed
    const bool pf = (t + 2 < NT);
#pragma unroll
    for (int ks = 0; ks < 2; ++ks) {
      s8v afrg[MI], bfrg[4];
#pragma unroll
      for (int i = 0; i < MI; ++i)
        afrg[i] = *(const s8v*)&lA[bs][ks][roff(wr * (MI * 16) + i * 16 + l15, l4)];
#pragma unroll
      for (int j = 0; j < 4; ++j)
        bfrg[j] = *(const s8v*)&lB[bs][ks][roff(wc * 64 + j * 16 + l15, l4)];
      asm volatile("s_waitcnt lgkmcnt(0)" ::: "memory");
      __builtin_amdgcn_sched_barrier(0);
      asm volatile("s_barrier" ::: "memory");    // WAR: region [bs][ks] fully read
      if (pf) stage_part(t + 2, bs, ks);         // overwrite the freed region
      __builtin_amdgcn_s_setprio(1);
#pragma unroll
      for (int i = 0; i < MI; ++i)
#pragma unroll
        for (int j = 0; j < 4; ++j)
          acc[i][j] = __builtin_amdgcn_mfma_f32_16x16x32_bf16(afrg[i], bfrg[j], acc[i][j], 0, 0, 0);
      __builtin_amdgcn_s_setprio(0);
      // no trailing barrier: next phase reads [bs][ks^1]; next tile gated at top
    }
  }

  const int colg = bn * BN + wc * 64;
  if constexpr (OUT == 0) {                      // Q: (B,16,L,128) bf16
    const int hh = colg >> 7, d0 = colg & 127;
#pragma unroll
    for (int i = 0; i < MI; i++)
#pragma unroll
      for (int r = 0; r < 4; r++) {
        int m = m0 + wr * (MI * 16) + i * 16 + l4 * 4 + r;
        int b = m >> 11, l = m & 2047;
        size_t base = ((size_t)(b * 16 + hh) * 2048 + l) * 128 + d0;
#pragma unroll
        for (int j = 0; j < 4; j++)
          Oa[base + j * 16 + l15] = f2bf(acc[i][j][r]);
      }
  } else if constexpr (OUT == 1) {               // K|V: (B,4,L,128) bf16 each
    u16* Ob = (colg < 512) ? Oa : Ob2;
    const int hh = (colg & 511) >> 7, d0 = colg & 127;
#pragma unroll
    for (int i = 0; i < MI; i++)
#pragma unroll
      for (int r = 0; r < 4; r++) {
        int m = m0 + wr * (MI * 16) + i * 16 + l4 * 4 + r;
        int b = m >> 11, l = m & 2047;
        size_t base = ((size_t)(b * 4 + hh) * 2048 + l) * 128 + d0;
#pragma unroll
        for (int j = 0; j < 4; j++)
          Ob[base + j * 16 + l15] = f2bf(acc[i][j][r]);
      }
  } else {                                       // proj: fp32 row-major
#pragma unroll
    for (int i = 0; i < MI; i++)
#pragma unroll
      for (int r = 0; r < 4; r++) {
        int m = m0 + wr * (MI * 16) + i * 16 + l4 * 4 + r;
#pragma unroll
        for (int j = 0; j < 4; j++)
          OF[(size_t)m * 2048 + colg + j * 16 + l15] = acc[i][j][r];
      }
  }
}

// ---------------- RMSNorm + RoPE for K ONLY (q fused into attn) ----------------
// k rows: 32768 x 128 bf16, in place. No gain, no exp2 fold (that lives on q).
__global__ __launch_bounds__(256) void norm_rope_k(u16* __restrict__ buf,
                                                   const float* __restrict__ tc,
                                                   const float* __restrict__ ts) {
  const int lane = threadIdx.x & 63;
  const int gw = blockIdx.x * 4 + (threadIdx.x >> 6);
  const int nw = gridDim.x * 4;
  for (int row = gw; row < 32768; row += nw) {
    int l = row & 2047;
    u16* p = buf + (size_t)row * 128;
    float x1 = bf2f(p[lane]);
    float x2 = bf2f(p[lane + 64]);
    float ss = x1 * x1 + x2 * x2;
#pragma unroll
    for (int off = 32; off > 0; off >>= 1) ss += __shfl_xor(ss, off, 64);
    float r = rsqrtf(ss * (1.0f / 128.0f) + 1.1920929e-07f);
    x1 *= r; x2 *= r;
    if (l >= 16) {
      int t = l - 16;
      float c = tc[t * 64 + lane], s = ts[t * 64 + lane];
      float o1 = x1 * c + x2 * s;
      float o2 = -x1 * s + x2 * c;
      x1 = o1; x2 = o2;
    }
    p[lane] = f2bf(x1);
    p[lane + 64] = f2bf(x2);
  }
}

// ---------------- V transpose: (bg,L,128) -> (bg,128,L), 64x64 LDS tiles, XOR swizzle
__global__ __launch_bounds__(256) void transpose_v(const u16* __restrict__ v,
                                                   u16* __restrict__ vt) {
  __shared__ u16 t[64][64];
  const int l0 = blockIdx.x * 64, d0 = blockIdx.y * 64, bg = blockIdx.z;
  const int tid = threadIdx.x;
#pragma unroll
  for (int it = 0; it < 2; ++it) {
    int lin = it * 256 + tid;
    int r = lin >> 3, cb = lin & 7;
    s8v val = *(const s8v*)&v[((bg * 2048 + l0 + r) * 128) + d0 + cb * 8];
    *(s8v*)&t[r][(cb ^ (r & 7)) * 8] = val;
  }
  __syncthreads();
#pragma unroll
  for (int it = 0; it < 2; ++it) {
    int lin = it * 256 + tid;
    int r2 = lin >> 3, c2 = (lin & 7) * 8;   // r2 = d idx, c2 = l idx
    s8v o;
#pragma unroll
    for (int j = 0; j < 8; ++j) {
      int rr = c2 + j, cc = r2;
      o[j] = (short)t[rr][(cc & 7) + 8 * ((cc >> 3) ^ (rr & 7))];
    }
    *(s8v*)&vt[((bg * 128 + d0 + r2) * 2048) + l0 + c2] = o;
  }
}

// ---------------- flash attention v2: 64-row q-tiles, fused Q-norm ----------------
// block = 512 threads = 8 waves = 4 heads x 2 row-halves; ONE 64-row q-tile per
// block -> single KV loop (nt = qt+1). Staging volume and barrier count per (b,g)
// HALVED vs the paired-2x32 scheme (528 vs 1088 stage-iters); 32KB staged now
// feeds 512 block-MFMA. Heavy-first dispatch (qt = 31-qi); XCD grouping kept.
// Q RMSNorm + RoPE + gain*scale*log2e fused at Q-load (q_bf is raw GEMM output):
// row's 128 dims live in lanes (l31,hi=0/1) -> RMS reduce = one shfl_xor(32);
// RoPE pairs (d,d+64) sit in frags ks,ks+4 of the same lane.
// PV P-exchange via v_permlane32_swap_b32 (T12): swap(A0,B0) yields uu0,uu2
// directly — replaces 2 ds_bpermute + 4 selects per ks.
__global__ __launch_bounds__(512, 2) void attn(const u16* __restrict__ q,
                                               const u16* __restrict__ k,
                                               const u16* __restrict__ vt,
                                               u16* __restrict__ y,
                                               const float* __restrict__ qg,
                                               const float* __restrict__ tc,
                                               const float* __restrict__ ts) {
  __shared__ u16 lK[2][64 * 128];   // row kv: 16 slots of 8 u16, slot s holds d-block s^(kv&7)
  __shared__ u16 lVT[2][128 * 64];  // row d:   8 slots of 8 u16, slot s holds kv-block s^(d&7)
  const int tid = threadIdx.x;
  const int lane = tid & 63, wid = tid >> 6;
  const int l31 = lane & 31, hi = lane >> 5;

  // XCD-aware remap: all 32 q-tile blocks of one (b,g) land on one XCD
  const int db = (int)blockIdx.y * 32 + (int)blockIdx.x;  // 0..511
  const int half = db >> 8, rem = db & 255;
  const int bg = (rem & 7) + 8 * half;                    // 0..15
  const int qi = rem >> 3;                                // 0..31, dispatch order
  const int qt = 31 - qi;                                 // heavy first
  const int b = bg >> 2, g = bg & 3;
  const int h = g * 4 + (wid & 3);
  const int se = wid >> 2;                                // row-half 0/1
  const int q0 = qt * 64;
  const int nt = qt + 1;                                  // KV tiles of 64

  const u16* qh = q + (size_t)(b * 16 + h) * 2048 * 128;
  const u16* kb0 = k + (size_t)(b * 4 + g) * 2048 * 128;
  const u16* vtb0 = vt + (size_t)(b * 4 + g) * 128 * 2048;

  // ---- fused Q: RMSNorm + RoPE + gain*(1/sqrt(128))*log2(e), pack B-frags ----
  const int pos = q0 + 32 * se + l31;
  const float gscale = qg[h] * (0.08838834764831845f * 1.4426950408889634f);
  s8v qf[8];
  {
    const u16* qp = qh + (size_t)pos * 128 + hi * 8;
    s8v qr[8];
#pragma unroll
    for (int ks = 0; ks < 8; ++ks) qr[ks] = *(const s8v*)&qp[ks * 16];
    float ssum = 0.f;
#pragma unroll
    for (int ks = 0; ks < 8; ++ks)
#pragma unroll
      for (int j = 0; j < 8; ++j) {
        float v = bf2f((u16)qr[ks][j]);
        ssum += v * v;
      }
    ssum += __shfl_xor(ssum, 32, 64);
    const float rn = rsqrtf(ssum * (1.0f / 128.0f) + 1.1920929e-07f) * gscale;
    const bool rot = (pos >= 16);
    const int tt = pos - 16;
#pragma unroll
    for (int ks = 0; ks < 4; ++ks) {
      float cv[8], sv[8];
      if (rot) {
        const float* cp = &tc[tt * 64 + ks * 16 + hi * 8];
        const float* sp = &ts[tt * 64 + ks * 16 + hi * 8];
        *(float4*)&cv[0] = *(const float4*)cp;
        *(float4*)&cv[4] = *(const float4*)(cp + 4);
        *(float4*)&sv[0] = *(const float4*)sp;
        *(float4*)&sv[4] = *(const float4*)(sp + 4);
      }
      uint32_t wlo[4], whi[4];
#pragma unroll
      for (int j2 = 0; j2 < 4; ++j2) {
        float o1[2], o2[2];
#pragma unroll
        for (int e = 0; e < 2; ++e) {
          const int j = j2 * 2 + e;
          float x1 = bf2f((u16)qr[ks][j]);
          float x2 = bf2f((u16)qr[ks + 4][j]);
          float a = x1, bb = x2;
          if (rot) { a = x1 * cv[j] + x2 * sv[j]; bb = x2 * cv[j] - x1 * sv[j]; }
          o1[e] = a * rn;
          o2[e] = bb * rn;
        }
        asm("v_cvt_pk_bf16_f32 %0, %1, %2" : "=v"(wlo[j2]) : "v"(o1[0]), "v"(o1[1]));
        asm("v_cvt_pk_bf16_f32 %0, %1, %2" : "=v"(whi[j2]) : "v"(o2[0]), "v"(o2[1]));
      }
      union { uint32_t u[4]; s8v v; } ua, ub;
      ua.u[0] = wlo[0]; ua.u[1] = wlo[1]; ua.u[2] = wlo[2]; ua.u[3] = wlo[3];
      ub.u[0] = whi[0]; ub.u[1] = whi[1]; ub.u[2] = whi[2]; ub.u[3] = whi[3];
      qf[ks] = ua.v;
      qf[ks + 4] = ub.v;
    }
  }

  auto stage = [&](int t, int bufsel) {
    const int kv0 = t * 64;
#pragma unroll
    for (int it = 0; it < 2; ++it) {        // K tile 64x128 (16KB), swizzled source
      int lin = it * 512 + tid;
      int kj = lin >> 4, s = lin & 15;
      gload_lds16(kb0 + (size_t)(kv0 + kj) * 128 + ((s ^ (kj & 7)) * 8),
                  &lK[bufsel][lin * 8]);
    }
#pragma unroll
    for (int it = 0; it < 2; ++it) {        // VT tile 128x64 (16KB), swizzled source
      int lin = it * 512 + tid;
      int d = lin >> 3, s = lin & 7;
      gload_lds16(vtb0 + (size_t)d * 2048 + kv0 + ((s ^ (d & 7)) * 8),
                  &lVT[bufsel][lin * 8]);
    }
  };

  f16v yacc[4];
#pragma unroll
  for (int j = 0; j < 4; ++j)
#pragma unroll
    for (int r = 0; r < 16; ++r) yacc[j][r] = 0.f;
  float mrow = -1e30f, lrow = 0.f;

  stage(0, 0);
  __syncthreads();

  for (int t = 0; t < nt; ++t) {
    const int cur = t & 1;
    if (t + 1 < nt) stage(t + 1, cur ^ 1);
    const int kv0 = t * 64;

    // ---- QK^T swapped: S^T[kv][q] in exp2 domain, two 32-kv chunks ----
    f16v s0a, s1a;
#pragma unroll
    for (int r = 0; r < 16; ++r) { s0a[r] = 0.f; s1a[r] = 0.f; }
    __builtin_amdgcn_s_setprio(1);
#pragma unroll
    for (int ks = 0; ks < 8; ++ks) {
      const int slot = (2 * ks + hi) ^ (l31 & 7);
      s8v kf0 = *(const s8v*)&lK[cur][(l31)*128 + slot * 8];
      s8v kf1 = *(const s8v*)&lK[cur][(32 + l31) * 128 + slot * 8];
      s0a = __builtin_amdgcn_mfma_f32_32x32x16_bf16(kf0, qf[ks], s0a, 0, 0, 0);
      s1a = __builtin_amdgcn_mfma_f32_32x32x16_bf16(kf1, qf[ks], s1a, 0, 0, 0);
    }
    __builtin_amdgcn_s_setprio(0);

    // ---- causal mask + row max (in-register; scores already log2-scaled) ----
    const bool last = (t == nt - 1);
    float p0[16], p1[16];
    float pmax = -1e30f;
#pragma unroll
    for (int r = 0; r < 16; ++r) {
      const int kvloc = (r & 3) + 8 * (r >> 2) + 4 * hi;
      float v0 = s0a[r];
      float v1 = s1a[r];
      if (last) {
        if (kv0 + kvloc > pos) v0 = -1e30f;
        if (kv0 + 32 + kvloc > pos) v1 = -1e30f;
      }
      p0[r] = v0; p1[r] = v1;
      pmax = fmaxf(pmax, fmaxf(v0, v1));
    }
    pmax = fmaxf(pmax, __shfl_xor(pmax, 32, 64));

    // ---- defer-max (T13): THR = 8*log2e in exp2 domain ----
    if (!__all(pmax - mrow <= 11.541560327111707f)) {
      float mnew = fmaxf(mrow, pmax);
      float corr = __builtin_amdgcn_exp2f(mrow - mnew);
#pragma unroll
      for (int r = 0; r < 16; ++r) {
        const int qloc = (r & 3) + 8 * (r >> 2) + 4 * hi;
        float cb = __shfl(corr, qloc, 64);
        yacc[0][r] *= cb; yacc[1][r] *= cb; yacc[2][r] *= cb; yacc[3][r] *= cb;
      }
      lrow *= corr;
      mrow = mnew;
    }

    // ---- exp2 + fp32 row sum (denominator unrounded) ----
    float ps = 0.f;
#pragma unroll
    for (int r = 0; r < 16; ++r) {
      float e0 = __builtin_amdgcn_exp2f(p0[r] - mrow);
      float e1 = __builtin_amdgcn_exp2f(p1[r] - mrow);
      p0[r] = e0; p1[r] = e1;
      ps += e0 + e1;
    }
    ps += __shfl_xor(ps, 32, 64);
    lrow += ps;

    // ---- PV: cvt_pk pack + permlane32_swap exchange + MFMA ----
    __builtin_amdgcn_s_setprio(1);
#pragma unroll
    for (int ks = 0; ks < 4; ++ks) {
      const float* pc = (ks < 2) ? p0 : p1;
      const int rb = 8 * (ks & 1);
      uint32_t A0, A1, B0, B1;
      asm("v_cvt_pk_bf16_f32 %0, %1, %2" : "=v"(A0) : "v"(pc[rb + 0]), "v"(pc[rb + 1]));
      asm("v_cvt_pk_bf16_f32 %0, %1, %2" : "=v"(A1) : "v"(pc[rb + 2]), "v"(pc[rb + 3]));
      asm("v_cvt_pk_bf16_f32 %0, %1, %2" : "=v"(B0) : "v"(pc[rb + 4]), "v"(pc[rb + 5]));
      asm("v_cvt_pk_bf16_f32 %0, %1, %2" : "=v"(B1) : "v"(pc[rb + 6]), "v"(pc[rb + 7]));
      // after swap: A0 = [A0_lo|B0_lo] = uu0, B0 = [A0_hi|B0_hi] = uu2 (ditto A1/B1)
      asm("v_permlane32_swap_b32 %0, %1" : "+v"(A0), "+v"(B0));
      asm("v_permlane32_swap_b32 %0, %1" : "+v"(A1), "+v"(B1));
      union { uint32_t u[4]; s8v v; } uu;
      uu.u[0] = A0; uu.u[1] = A1; uu.u[2] = B0; uu.u[3] = B1;
#pragma unroll
      for (int jd = 0; jd < 4; ++jd) {
        const int rowd = 32 * jd + l31;
        const int slot = (2 * ks + hi) ^ (l31 & 7);
        s8v vf = *(const s8v*)&lVT[cur][rowd * 64 + slot * 8];
        yacc[jd] = __builtin_amdgcn_mfma_f32_32x32x16_bf16(uu.v, vf, yacc[jd], 0, 0, 0);
      }
    }
    __builtin_amdgcn_s_setprio(0);
    __syncthreads();
  }

  // ---- finalize: broadcast 1/l per C-row, write y (B,L,H*128) bf16 ----
  float inv = 1.0f / lrow;
#pragma unroll
  for (int r = 0; r < 16; ++r) {
    const int qloc = (r & 3) + 8 * (r >> 2) + 4 * hi;
    float ib = __shfl(inv, qloc, 64);
    const int qrow = q0 + 32 * se + qloc;
    size_t base = ((size_t)(b * 2048 + qrow)) * 2048 + h * 128 + l31;
#pragma unroll
    for (int jd = 0; jd < 4; ++jd)
      y[base + 32 * jd] = f2bf(yacc[jd][r] * ib);
  }
}

extern "C" void kernel_launch(void* const* d_in, const int* in_sizes, int n_in,
                              void* d_out, int out_size, void* d_ws, size_t ws_size,
                              hipStream_t stream) {
  const float* x  = (const float*)d_in[0];
  const float* Wq = (const float*)d_in[1];
  const float* Wk = (const float*)d_in[2];
  const float* Wv = (const float*)d_in[3];
  const float* Wp = (const float*)d_in[4];
  const float* qg = (const float*)d_in[5];
  float* out = (float*)d_out;

  char* ws = (char*)d_ws;
  size_t off = 0;
  auto alloc = [&](size_t bytes) {
    void* p = ws + off;
    off += (bytes + 255) & ~(size_t)255;
    return p;
  };
  u16* x_bf  = (u16*)alloc((size_t)8192 * 2048 * 2);   // also reused as y_bf
  u16* wq_bf = (u16*)alloc((size_t)2048 * 2048 * 2);   // also reused as vt_bf
  u16* wk_bf = (u16*)alloc((size_t)512 * 2048 * 2);    // wk|wv contiguous = KV weight
  u16* wv_bf = (u16*)alloc((size_t)512 * 2048 * 2);
  u16* wp_bf = (u16*)alloc((size_t)2048 * 2048 * 2);
  u16* q_bf  = (u16*)alloc((size_t)4 * 16 * 2048 * 128 * 2);
  u16* k_bf  = (u16*)alloc((size_t)4 * 4 * 2048 * 128 * 2);
  u16* v_bf  = (u16*)alloc((size_t)4 * 4 * 2048 * 128 * 2);
  float* tab = (float*)alloc((size_t)2032 * 64 * 2 * 4);
  u16* y_bf  = x_bf;    // x dead after QKV GEMMs
  u16* vt_bf = wq_bf;   // Wq dead after Q GEMM (same size)

  cvt_bf16<<<2048, 256, 0, stream>>>((const float4*)x, (uint2*)x_bf, 8192 * 2048 / 4);
  cvt_bf16_w<<<1024, 256, 0, stream>>>((const float4*)Wq, (const float4*)Wk,
                                       (const float4*)Wv, (const float4*)Wp,
                                       (uint2*)wq_bf);   // wq|wk|wv|wp contiguous
  rope_table<<<(2032 * 64 + 255) / 256, 256, 0, stream>>>(tab, tab + 2032 * 64);

  gemm_nt<256, 0><<<dim3(256), 512, 0, stream>>>(x_bf, wq_bf, q_bf, nullptr, nullptr);
  gemm_nt<128, 1><<<dim3(256), 512, 0, stream>>>(x_bf, wk_bf, k_bf, v_bf, nullptr);
  norm_rope_k<<<256, 256, 0, stream>>>(k_bf, tab, tab + 2032 * 64);
  transpose_v<<<dim3(32, 2, 16), 256, 0, stream>>>(v_bf, vt_bf);
  attn<<<dim3(32, 16), 512, 0, stream>>>(q_bf, k_bf, vt_bf, y_bf, qg,
                                         tab, tab + 2032 * 64);
  gemm_nt<256, 2><<<dim3(256), 512, 0, stream>>>(y_bf, wp_bf, nullptr, nullptr, out);
}

// Round 12
// 353.731 us; speedup vs baseline: 1.0584x; 1.0584x over previous
//
#include <hip/hip_runtime.h>
#include <stdint.h>

// Shapes (fixed): B=4 L=2048 D=2048 H=16 KVH=4 HD=128 M=16 T=2032
typedef unsigned short u16;
typedef short s8v __attribute__((ext_vector_type(8)));   // 8 bf16 (4 VGPR) MFMA frag
typedef float f4v __attribute__((ext_vector_type(4)));   // 16x16 MFMA accum
typedef float f16v __attribute__((ext_vector_type(16))); // 32x32 MFMA accum

typedef __attribute__((address_space(1))) char gchar;
typedef __attribute__((address_space(3))) char lchar;

static __device__ __forceinline__ u16 f2bf(float f) {
  uint32_t x = __float_as_uint(f);
  x += 0x7fffu + ((x >> 16) & 1u);            // RNE
  return (u16)(x >> 16);
}
static __device__ __forceinline__ float bf2f(u16 u) {
  return __uint_as_float(((uint32_t)u) << 16);
}
// async global->LDS, 16B per lane. LDS dest must be wave-linear (base + lane*16).
static __device__ __forceinline__ void gload_lds16(const void* g, void* l) {
  __builtin_amdgcn_global_load_lds((gchar*)(uintptr_t)g,
                                   (lchar*)(uint32_t)(uintptr_t)l, 16, 0, 0);
}

// ---------------- fp32 -> bf16 convert (vectorized) ----------------
__global__ __launch_bounds__(256) void cvt_bf16(const float4* __restrict__ src,
                                                uint2* __restrict__ dst, int n4) {
  int i = blockIdx.x * 256 + threadIdx.x;
  int st = gridDim.x * 256;
  for (; i < n4; i += st) {
    float4 v = src[i];
    uint2 o;
    o.x = (uint32_t)f2bf(v.x) | ((uint32_t)f2bf(v.y) << 16);
    o.y = (uint32_t)f2bf(v.z) | ((uint32_t)f2bf(v.w) << 16);
    dst[i] = o;
  }
}

// all 4 weight matrices in one launch; dst regions are contiguous in ws.
__global__ __launch_bounds__(256) void cvt_bf16_w(const float4* __restrict__ s0,
                                                  const float4* __restrict__ s1,
                                                  const float4* __restrict__ s2,
                                                  const float4* __restrict__ s3,
                                                  uint2* __restrict__ dst) {
  // boundaries in float4 units: wq 1048576 | wk 262144 | wv 262144 | wp 1048576
  int i = blockIdx.x * 256 + threadIdx.x;
  int st = gridDim.x * 256;
  for (; i < 2621440; i += st) {
    const float4* s;
    int off;
    if (i < 1048576)      { s = s0; off = i; }
    else if (i < 1310720) { s = s1; off = i - 1048576; }
    else if (i < 1572864) { s = s2; off = i - 1310720; }
    else                  { s = s3; off = i - 1572864; }
    float4 v = s[off];
    uint2 o;
    o.x = (uint32_t)f2bf(v.x) | ((uint32_t)f2bf(v.y) << 16);
    o.y = (uint32_t)f2bf(v.z) | ((uint32_t)f2bf(v.w) << 16);
    dst[i] = o;
  }
}

// ---------------- RoPE cos/sin table: [T=2032][64] ----------------
__global__ __launch_bounds__(256) void rope_table(float* __restrict__ tc,
                                                  float* __restrict__ ts) {
  int i = blockIdx.x * 256 + threadIdx.x;
  if (i >= 2032 * 64) return;
  int t = i >> 6, f = i & 63;
  float invf = 1.0f / powf(10000.0f, (float)f * (1.0f / 64.0f)); // accurate powf
  float ang = (float)t * invf;
  float s, c;
  sincosf(ang, &s, &c);                                           // accurate sincos
  tc[i] = c;
  ts[i] = s;
}

// ---------------- 256xBN deep-pipelined NT GEMM, k-half region staging ----------------
// (unchanged from R10 — see R10 notes; ~<108us per GEMM, conflicts 0)
template <int BN, int OUT>
__global__ __launch_bounds__(512, 2) void gemm_nt(
    const u16* __restrict__ A, const u16* __restrict__ Wt,
    u16* __restrict__ Oa, u16* __restrict__ Ob2, float* __restrict__ OF) {
  constexpr int MI = (BN == 256) ? 8 : 4;      // wave M-frags (wave-tile MIx16 x 64)
  constexpr int BLOADS = (BN == 256) ? 2 : 1;  // B stage loads/thread/part
  __shared__ u16 lA[2][2][256 * 32];
  __shared__ u16 lB[2][2][BN * 32];
  const int tid = threadIdx.x;
  const int lane = tid & 63, wid = tid >> 6;
  const int wr = (BN == 256) ? (wid >> 2) : (wid >> 1);
  const int wc = (BN == 256) ? (wid & 3) : (wid & 1);
  const int l15 = lane & 15, l4 = lane >> 4;

  const int bid = blockIdx.x;
  const int swz = (bid & 7) * 32 + (bid >> 3);   // XCD chunk (grid always 256)
  const int bn = swz >> 5, bm = swz & 31;        // col-major: 1 B-panel per XCD
  const int m0 = bm * 256;
  const int n0r = bn * BN;

  auto stage_part = [&](int kt, int bs, int ks) {
    const int kb = kt * 64 + ks * 32;
#pragma unroll
    for (int c = 0; c < 2; ++c) {                // A region: 1024 chunks
      int cidx = tid + c * 512;
      int r = cidx >> 2, q = cidx & 3;
      int cc = q ^ ((r >> 2) & 3);
      gload_lds16(A + (size_t)(m0 + r) * 2048 + kb + cc * 8,
                  &lA[bs][ks][cidx * 8]);
    }
#pragma unroll
    for (int c = 0; c < BLOADS; ++c) {           // B region: BN*4 chunks
      int cidx = tid + c * 512;
      int r = cidx >> 2, q = cidx & 3;
      int cc = q ^ ((r >> 2) & 3);
      gload_lds16(Wt + (size_t)(n0r + r) * 2048 + kb + cc * 8,
                  &lB[bs][ks][cidx * 8]);
    }
  };
  auto roff = [&](int fr, int c) {               // u16 index within a region
    return (fr * 4 + (c ^ ((fr >> 2) & 3))) * 8;
  };

  const f4v Z4 = {0.f, 0.f, 0.f, 0.f};
  f4v acc[MI][4];
#pragma unroll
  for (int i = 0; i < MI; i++)
#pragma unroll
    for (int j = 0; j < 4; j++) acc[i][j] = Z4;

  // prologue: tiles 0,1 fully staged (2L loads/thread outstanding)
  stage_part(0, 0, 0); stage_part(0, 0, 1);
  stage_part(1, 1, 0); stage_part(1, 1, 1);

  const int NT = 32;                 // 2048 / 64
  for (int t = 0; t < NT; ++t) {
    const int bs = t & 1;
    if (t + 1 < NT) {                // drain tile t's L loads, keep t+1's in flight
      if constexpr (BN == 256) asm volatile("s_waitcnt vmcnt(8)" ::: "memory");
      else                     asm volatile("s_waitcnt vmcnt(6)" ::: "memory");
    } else {
      asm volatile("s_waitcnt vmcnt(0)" ::: "memory");
    }
    asm volatile("s_barrier" ::: "memory");      // RAW: ALL waves' tile t landed
    const bool pf = (t + 2 < NT);
#pragma unroll
    for (int ks = 0; ks < 2; ++ks) {
      s8v afrg[MI], bfrg[4];
#pragma unroll
      for (int i = 0; i < MI; ++i)
        afrg[i] = *(const s8v*)&lA[bs][ks][roff(wr * (MI * 16) + i * 16 + l15, l4)];
#pragma unroll
      for (int j = 0; j < 4; ++j)
        bfrg[j] = *(const s8v*)&lB[bs][ks][roff(wc * 64 + j * 16 + l15, l4)];
      asm volatile("s_waitcnt lgkmcnt(0)" ::: "memory");
      __builtin_amdgcn_sched_barrier(0);
      asm volatile("s_barrier" ::: "memory");    // WAR: region [bs][ks] fully read
      if (pf) stage_part(t + 2, bs, ks);         // overwrite the freed region
      __builtin_amdgcn_s_setprio(1);
#pragma unroll
      for (int i = 0; i < MI; ++i)
#pragma unroll
        for (int j = 0; j < 4; ++j)
          acc[i][j] = __builtin_amdgcn_mfma_f32_16x16x32_bf16(afrg[i], bfrg[j], acc[i][j], 0, 0, 0);
      __builtin_amdgcn_s_setprio(0);
      // no trailing barrier: next phase reads [bs][ks^1]; next tile gated at top
    }
  }

  const int colg = bn * BN + wc * 64;
  if constexpr (OUT == 0) {                      // Q: (B,16,L,128) bf16
    const int hh = colg >> 7, d0 = colg & 127;
#pragma unroll
    for (int i = 0; i < MI; i++)
#pragma unroll
      for (int r = 0; r < 4; r++) {
        int m = m0 + wr * (MI * 16) + i * 16 + l4 * 4 + r;
        int b = m >> 11, l = m & 2047;
        size_t base = ((size_t)(b * 16 + hh) * 2048 + l) * 128 + d0;
#pragma unroll
        for (int j = 0; j < 4; j++)
          Oa[base + j * 16 + l15] = f2bf(acc[i][j][r]);
      }
  } else if constexpr (OUT == 1) {               // K|V: (B,4,L,128) bf16 each
    u16* Ob = (colg < 512) ? Oa : Ob2;
    const int hh = (colg & 511) >> 7, d0 = colg & 127;
#pragma unroll
    for (int i = 0; i < MI; i++)
#pragma unroll
      for (int r = 0; r < 4; r++) {
        int m = m0 + wr * (MI * 16) + i * 16 + l4 * 4 + r;
        int b = m >> 11, l = m & 2047;
        size_t base = ((size_t)(b * 4 + hh) * 2048 + l) * 128 + d0;
#pragma unroll
        for (int j = 0; j < 4; j++)
          Ob[base + j * 16 + l15] = f2bf(acc[i][j][r]);
      }
  } else {                                       // proj: fp32 row-major
#pragma unroll
    for (int i = 0; i < MI; i++)
#pragma unroll
      for (int r = 0; r < 4; r++) {
        int m = m0 + wr * (MI * 16) + i * 16 + l4 * 4 + r;
#pragma unroll
        for (int j = 0; j < 4; j++)
          OF[(size_t)m * 2048 + colg + j * 16 + l15] = acc[i][j][r];
      }
  }
}

// ---------------- RMSNorm + RoPE for K ONLY (q fused into attn) ----------------
// k rows: 32768 x 128 bf16, in place. No gain, no exp2 fold (that lives on q).
__global__ __launch_bounds__(256) void norm_rope_k(u16* __restrict__ buf,
                                                   const float* __restrict__ tc,
                                                   const float* __restrict__ ts) {
  const int lane = threadIdx.x & 63;
  const int gw = blockIdx.x * 4 + (threadIdx.x >> 6);
  const int nw = gridDim.x * 4;
  for (int row = gw; row < 32768; row += nw) {
    int l = row & 2047;
    u16* p = buf + (size_t)row * 128;
    float x1 = bf2f(p[lane]);
    float x2 = bf2f(p[lane + 64]);
    float ss = x1 * x1 + x2 * x2;
#pragma unroll
    for (int off = 32; off > 0; off >>= 1) ss += __shfl_xor(ss, off, 64);
    float r = rsqrtf(ss * (1.0f / 128.0f) + 1.1920929e-07f);
    x1 *= r; x2 *= r;
    if (l >= 16) {
      int t = l - 16;
      float c = tc[t * 64 + lane], s = ts[t * 64 + lane];
      float o1 = x1 * c + x2 * s;
      float o2 = -x1 * s + x2 * c;
      x1 = o1; x2 = o2;
    }
    p[lane] = f2bf(x1);
    p[lane + 64] = f2bf(x2);
  }
}

// ---------------- V transpose: (bg,L,128) -> (bg,128,L), 64x64 LDS tiles, XOR swizzle
__global__ __launch_bounds__(256) void transpose_v(const u16* __restrict__ v,
                                                   u16* __restrict__ vt) {
  __shared__ u16 t[64][64];
  const int l0 = blockIdx.x * 64, d0 = blockIdx.y * 64, bg = blockIdx.z;
  const int tid = threadIdx.x;
#pragma unroll
  for (int it = 0; it < 2; ++it) {
    int lin = it * 256 + tid;
    int r = lin >> 3, cb = lin & 7;
    s8v val = *(const s8v*)&v[((bg * 2048 + l0 + r) * 128) + d0 + cb * 8];
    *(s8v*)&t[r][(cb ^ (r & 7)) * 8] = val;
  }
  __syncthreads();
#pragma unroll
  for (int it = 0; it < 2; ++it) {
    int lin = it * 256 + tid;
    int r2 = lin >> 3, c2 = (lin & 7) * 8;   // r2 = d idx, c2 = l idx
    s8v o;
#pragma unroll
    for (int j = 0; j < 8; ++j) {
      int rr = c2 + j, cc = r2;
      o[j] = (short)t[rr][(cc & 7) + 8 * ((cc >> 3) ^ (rr & 7))];
    }
    *(s8v*)&vt[((bg * 128 + d0 + r2) * 2048) + l0 + c2] = o;
  }
}

// ---------------- flash attention v3: paired 64-row q-tiles, fused Q-norm ----------------
// R11 post-mortem: variable nt blocks (1..32) with full co-residency -> worst CU
// hosts 2x(qt=31) = 64 tile-iters vs 33 avg (1.9x makespan). v3 restores R10's
// balance invariant: each block processes q-tile pair {pairi, 31-pairi}
// sequentially -> uniform 33 KV-tile-iters/block; 256 blocks, 1/CU, zero tail.
// Per-phase body identical to R11 (fused Q RMSNorm+RoPE+gain*log2e at Q-load,
// swapped QK^T in exp2 domain, in-register softmax, cvt_pk + permlane32_swap
// P-exchange, defer-max THR=8*log2e). XCD grouping: bid&7 -> bg {2k,2k+1}
// (2MB KV per XCD L2).
__global__ __launch_bounds__(512, 2) void attn(const u16* __restrict__ q,
                                               const u16* __restrict__ k,
                                               const u16* __restrict__ vt,
                                               u16* __restrict__ y,
                                               const float* __restrict__ qg,
                                               const float* __restrict__ tc,
                                               const float* __restrict__ ts) {
  __shared__ u16 lK[2][64 * 128];   // row kv: 16 slots of 8 u16, slot s holds d-block s^(kv&7)
  __shared__ u16 lVT[2][128 * 64];  // row d:   8 slots of 8 u16, slot s holds kv-block s^(d&7)
  const int tid = threadIdx.x;
  const int lane = tid & 63, wid = tid >> 6;
  const int l31 = lane & 31, hi = lane >> 5;

  const int bid = (int)blockIdx.x;                 // 0..255
  const int bg = (bid & 7) * 2 + (bid >> 7);       // XCD k hosts bg {2k,2k+1}
  const int pairi = (bid >> 3) & 15;               // 0..15
  const int b = bg >> 2, g = bg & 3;
  const int h = g * 4 + (wid & 3);
  const int se = wid >> 2;                         // row-half 0/1

  const u16* qh = q + (size_t)(b * 16 + h) * 2048 * 128;
  const u16* kb0 = k + (size_t)(b * 4 + g) * 2048 * 128;
  const u16* vtb0 = vt + (size_t)(b * 4 + g) * 128 * 2048;
  const float gscale = qg[h] * (0.08838834764831845f * 1.4426950408889634f);

  auto stage = [&](int t, int bufsel) {
    const int kv0 = t * 64;
#pragma unroll
    for (int it = 0; it < 2; ++it) {        // K tile 64x128 (16KB), swizzled source
      int lin = it * 512 + tid;
      int kj = lin >> 4, s = lin & 15;
      gload_lds16(kb0 + (size_t)(kv0 + kj) * 128 + ((s ^ (kj & 7)) * 8),
                  &lK[bufsel][lin * 8]);
    }
#pragma unroll
    for (int it = 0; it < 2; ++it) {        // VT tile 128x64 (16KB), swizzled source
      int lin = it * 512 + tid;
      int d = lin >> 3, s = lin & 7;
      gload_lds16(vtb0 + (size_t)d * 2048 + kv0 + ((s ^ (d & 7)) * 8),
                  &lVT[bufsel][lin * 8]);
    }
  };

  for (int ph = 0; ph < 2; ++ph) {
    const int qt = ph ? (31 - pairi) : pairi;
    const int q0 = qt * 64;
    const int nt = qt + 1;                  // KV tiles of 64
    const int pos = q0 + 32 * se + l31;

    // ---- fused Q: RMSNorm + RoPE + gain*(1/sqrt(128))*log2(e), pack B-frags ----
    s8v qf[8];
    {
      const u16* qp = qh + (size_t)pos * 128 + hi * 8;
      s8v qr[8];
#pragma unroll
      for (int ks = 0; ks < 8; ++ks) qr[ks] = *(const s8v*)&qp[ks * 16];
      float ssum = 0.f;
#pragma unroll
      for (int ks = 0; ks < 8; ++ks)
#pragma unroll
        for (int j = 0; j < 8; ++j) {
          float v = bf2f((u16)qr[ks][j]);
          ssum += v * v;
        }
      ssum += __shfl_xor(ssum, 32, 64);
      const float rn = rsqrtf(ssum * (1.0f / 128.0f) + 1.1920929e-07f) * gscale;
      const bool rot = (pos >= 16);
      const int tt = pos - 16;
#pragma unroll
      for (int ks = 0; ks < 4; ++ks) {
        float cv[8], sv[8];
        if (rot) {
          const float* cp = &tc[tt * 64 + ks * 16 + hi * 8];
          const float* sp = &ts[tt * 64 + ks * 16 + hi * 8];
          *(float4*)&cv[0] = *(const float4*)cp;
          *(float4*)&cv[4] = *(const float4*)(cp + 4);
          *(float4*)&sv[0] = *(const float4*)sp;
          *(float4*)&sv[4] = *(const float4*)(sp + 4);
        }
        uint32_t wlo[4], whi[4];
#pragma unroll
        for (int j2 = 0; j2 < 4; ++j2) {
          float o1[2], o2[2];
#pragma unroll
          for (int e = 0; e < 2; ++e) {
            const int j = j2 * 2 + e;
            float x1 = bf2f((u16)qr[ks][j]);
            float x2 = bf2f((u16)qr[ks + 4][j]);
            float a = x1, bb = x2;
            if (rot) { a = x1 * cv[j] + x2 * sv[j]; bb = x2 * cv[j] - x1 * sv[j]; }
            o1[e] = a * rn;
            o2[e] = bb * rn;
          }
          asm("v_cvt_pk_bf16_f32 %0, %1, %2" : "=v"(wlo[j2]) : "v"(o1[0]), "v"(o1[1]));
          asm("v_cvt_pk_bf16_f32 %0, %1, %2" : "=v"(whi[j2]) : "v"(o2[0]), "v"(o2[1]));
        }
        union { uint32_t u[4]; s8v v; } ua, ub;
        ua.u[0] = wlo[0]; ua.u[1] = wlo[1]; ua.u[2] = wlo[2]; ua.u[3] = wlo[3];
        ub.u[0] = whi[0]; ub.u[1] = whi[1]; ub.u[2] = whi[2]; ub.u[3] = whi[3];
        qf[ks] = ua.v;
        qf[ks + 4] = ub.v;
      }
    }

    f16v yacc[4];
#pragma unroll
    for (int j = 0; j < 4; ++j)
#pragma unroll
      for (int r = 0; r < 16; ++r) yacc[j][r] = 0.f;
    float mrow = -1e30f, lrow = 0.f;

    stage(0, 0);
    __syncthreads();

    for (int t = 0; t < nt; ++t) {
      const int cur = t & 1;
      if (t + 1 < nt) stage(t + 1, cur ^ 1);
      const int kv0 = t * 64;

      // ---- QK^T swapped: S^T[kv][q] in exp2 domain, two 32-kv chunks ----
      f16v s0a, s1a;
#pragma unroll
      for (int r = 0; r < 16; ++r) { s0a[r] = 0.f; s1a[r] = 0.f; }
      __builtin_amdgcn_s_setprio(1);
#pragma unroll
      for (int ks = 0; ks < 8; ++ks) {
        const int slot = (2 * ks + hi) ^ (l31 & 7);
        s8v kf0 = *(const s8v*)&lK[cur][(l31)*128 + slot * 8];
        s8v kf1 = *(const s8v*)&lK[cur][(32 + l31) * 128 + slot * 8];
        s0a = __builtin_amdgcn_mfma_f32_32x32x16_bf16(kf0, qf[ks], s0a, 0, 0, 0);
        s1a = __builtin_amdgcn_mfma_f32_32x32x16_bf16(kf1, qf[ks], s1a, 0, 0, 0);
      }
      __builtin_amdgcn_s_setprio(0);

      // ---- causal mask + row max (in-register; scores already log2-scaled) ----
      const bool last = (t == nt - 1);
      float p0[16], p1[16];
      float pmax = -1e30f;
#pragma unroll
      for (int r = 0; r < 16; ++r) {
        const int kvloc = (r & 3) + 8 * (r >> 2) + 4 * hi;
        float v0 = s0a[r];
        float v1 = s1a[r];
        if (last) {
          if (kv0 + kvloc > pos) v0 = -1e30f;
          if (kv0 + 32 + kvloc > pos) v1 = -1e30f;
        }
        p0[r] = v0; p1[r] = v1;
        pmax = fmaxf(pmax, fmaxf(v0, v1));
      }
      pmax = fmaxf(pmax, __shfl_xor(pmax, 32, 64));

      // ---- defer-max (T13): THR = 8*log2e in exp2 domain ----
      if (!__all(pmax - mrow <= 11.541560327111707f)) {
        float mnew = fmaxf(mrow, pmax);
        float corr = __builtin_amdgcn_exp2f(mrow - mnew);
#pragma unroll
        for (int r = 0; r < 16; ++r) {
          const int qloc = (r & 3) + 8 * (r >> 2) + 4 * hi;
          float cb = __shfl(corr, qloc, 64);
          yacc[0][r] *= cb; yacc[1][r] *= cb; yacc[2][r] *= cb; yacc[3][r] *= cb;
        }
        lrow *= corr;
        mrow = mnew;
      }

      // ---- exp2 + fp32 row sum (denominator unrounded) ----
      float ps = 0.f;
#pragma unroll
      for (int r = 0; r < 16; ++r) {
        float e0 = __builtin_amdgcn_exp2f(p0[r] - mrow);
        float e1 = __builtin_amdgcn_exp2f(p1[r] - mrow);
        p0[r] = e0; p1[r] = e1;
        ps += e0 + e1;
      }
      ps += __shfl_xor(ps, 32, 64);
      lrow += ps;

      // ---- PV: cvt_pk pack + permlane32_swap exchange + MFMA ----
      __builtin_amdgcn_s_setprio(1);
#pragma unroll
      for (int ks = 0; ks < 4; ++ks) {
        const float* pc = (ks < 2) ? p0 : p1;
        const int rb = 8 * (ks & 1);
        uint32_t A0, A1, B0, B1;
        asm("v_cvt_pk_bf16_f32 %0, %1, %2" : "=v"(A0) : "v"(pc[rb + 0]), "v"(pc[rb + 1]));
        asm("v_cvt_pk_bf16_f32 %0, %1, %2" : "=v"(A1) : "v"(pc[rb + 2]), "v"(pc[rb + 3]));
        asm("v_cvt_pk_bf16_f32 %0, %1, %2" : "=v"(B0) : "v"(pc[rb + 4]), "v"(pc[rb + 5]));
        asm("v_cvt_pk_bf16_f32 %0, %1, %2" : "=v"(B1) : "v"(pc[rb + 6]), "v"(pc[rb + 7]));
        // after swap: A0 = [A0_lo|B0_lo] = uu0, B0 = [A0_hi|B0_hi] = uu2 (ditto A1/B1)
        asm("v_permlane32_swap_b32 %0, %1" : "+v"(A0), "+v"(B0));
        asm("v_permlane32_swap_b32 %0, %1" : "+v"(A1), "+v"(B1));
        union { uint32_t u[4]; s8v v; } uu;
        uu.u[0] = A0; uu.u[1] = A1; uu.u[2] = B0; uu.u[3] = B1;
#pragma unroll
        for (int jd = 0; jd < 4; ++jd) {
          const int rowd = 32 * jd + l31;
          const int slot = (2 * ks + hi) ^ (l31 & 7);
          s8v vf = *(const s8v*)&lVT[cur][rowd * 64 + slot * 8];
          yacc[jd] = __builtin_amdgcn_mfma_f32_32x32x16_bf16(uu.v, vf, yacc[jd], 0, 0, 0);
        }
      }
      __builtin_amdgcn_s_setprio(0);
      __syncthreads();
    }

    // ---- finalize: broadcast 1/l per C-row, write y (B,L,H*128) bf16 ----
    float inv = 1.0f / lrow;
#pragma unroll
    for (int r = 0; r < 16; ++r) {
      const int qloc = (r & 3) + 8 * (r >> 2) + 4 * hi;
      float ib = __shfl(inv, qloc, 64);
      const int qrow = q0 + 32 * se + qloc;
      size_t base = ((size_t)(b * 2048 + qrow)) * 2048 + h * 128 + l31;
#pragma unroll
      for (int jd = 0; jd < 4; ++jd)
        y[base + 32 * jd] = f2bf(yacc[jd][r] * ib);
    }
  }
}

extern "C" void kernel_launch(void* const* d_in, const int* in_sizes, int n_in,
                              void* d_out, int out_size, void* d_ws, size_t ws_size,
                              hipStream_t stream) {
  const float* x  = (const float*)d_in[0];
  const float* Wq = (const float*)d_in[1];
  const float* Wk = (const float*)d_in[2];
  const float* Wv = (const float*)d_in[3];
  const float* Wp = (const float*)d_in[4];
  const float* qg = (const float*)d_in[5];
  float* out = (float*)d_out;

  char* ws = (char*)d_ws;
  size_t off = 0;
  auto alloc = [&](size_t bytes) {
    void* p = ws + off;
    off += (bytes + 255) & ~(size_t)255;
    return p;
  };
  u16* x_bf  = (u16*)alloc((size_t)8192 * 2048 * 2);   // also reused as y_bf
  u16* wq_bf = (u16*)alloc((size_t)2048 * 2048 * 2);   // also reused as vt_bf
  u16* wk_bf = (u16*)alloc((size_t)512 * 2048 * 2);    // wk|wv contiguous = KV weight
  u16* wv_bf = (u16*)alloc((size_t)512 * 2048 * 2);
  u16* wp_bf = (u16*)alloc((size_t)2048 * 2048 * 2);
  u16* q_bf  = (u16*)alloc((size_t)4 * 16 * 2048 * 128 * 2);
  u16* k_bf  = (u16*)alloc((size_t)4 * 4 * 2048 * 128 * 2);
  u16* v_bf  = (u16*)alloc((size_t)4 * 4 * 2048 * 128 * 2);
  float* tab = (float*)alloc((size_t)2032 * 64 * 2 * 4);
  u16* y_bf  = x_bf;    // x dead after QKV GEMMs
  u16* vt_bf = wq_bf;   // Wq dead after Q GEMM (same size)

  cvt_bf16<<<2048, 256, 0, stream>>>((const float4*)x, (uint2*)x_bf, 8192 * 2048 / 4);
  cvt_bf16_w<<<1024, 256, 0, stream>>>((const float4*)Wq, (const float4*)Wk,
                                       (const float4*)Wv, (const float4*)Wp,
                                       (uint2*)wq_bf);   // wq|wk|wv|wp contiguous
  rope_table<<<(2032 * 64 + 255) / 256, 256, 0, stream>>>(tab, tab + 2032 * 64);

  gemm_nt<256, 0><<<dim3(256), 512, 0, stream>>>(x_bf, wq_bf, q_bf, nullptr, nullptr);
  gemm_nt<128, 1><<<dim3(256), 512, 0, stream>>>(x_bf, wk_bf, k_bf, v_bf, nullptr);
  norm_rope_k<<<256, 256, 0, stream>>>(k_bf, tab, tab + 2032 * 64);
  transpose_v<<<dim3(32, 2, 16), 256, 0, stream>>>(v_bf, vt_bf);
  attn<<<dim3(256), 512, 0, stream>>>(q_bf, k_bf, vt_bf, y_bf, qg,
                                      tab, tab + 2032 * 64);
  gemm_nt<256, 2><<<dim3(256), 512, 0, stream>>>(y_bf, wp_bf, nullptr, nullptr, out);
}

// Round 13
// 344.050 us; speedup vs baseline: 1.0882x; 1.0281x over previous
//
#include <hip/hip_runtime.h>
#include <stdint.h>

// Shapes (fixed): B=4 L=2048 D=2048 H=16 KVH=4 HD=128 M=16 T=2032
typedef unsigned short u16;
typedef short s8v __attribute__((ext_vector_type(8)));   // 8 bf16 (4 VGPR) MFMA frag
typedef float f4v __attribute__((ext_vector_type(4)));   // 16x16 MFMA accum
typedef float f16v __attribute__((ext_vector_type(16))); // 32x32 MFMA accum

typedef __attribute__((address_space(1))) char gchar;
typedef __attribute__((address_space(3))) char lchar;

static __device__ __forceinline__ u16 f2bf(float f) {
  uint32_t x = __float_as_uint(f);
  x += 0x7fffu + ((x >> 16) & 1u);            // RNE
  return (u16)(x >> 16);
}
static __device__ __forceinline__ float bf2f(u16 u) {
  return __uint_as_float(((uint32_t)u) << 16);
}
// async global->LDS, 16B per lane. LDS dest must be wave-linear (base + lane*16).
static __device__ __forceinline__ void gload_lds16(const void* g, void* l) {
  __builtin_amdgcn_global_load_lds((gchar*)(uintptr_t)g,
                                   (lchar*)(uint32_t)(uintptr_t)l, 16, 0, 0);
}

// ---------------- fp32 -> bf16 convert (vectorized) ----------------
__global__ __launch_bounds__(256) void cvt_bf16(const float4* __restrict__ src,
                                                uint2* __restrict__ dst, int n4) {
  int i = blockIdx.x * 256 + threadIdx.x;
  int st = gridDim.x * 256;
  for (; i < n4; i += st) {
    float4 v = src[i];
    uint2 o;
    o.x = (uint32_t)f2bf(v.x) | ((uint32_t)f2bf(v.y) << 16);
    o.y = (uint32_t)f2bf(v.z) | ((uint32_t)f2bf(v.w) << 16);
    dst[i] = o;
  }
}

// all 4 weight matrices in one launch; dst regions are contiguous in ws.
__global__ __launch_bounds__(256) void cvt_bf16_w(const float4* __restrict__ s0,
                                                  const float4* __restrict__ s1,
                                                  const float4* __restrict__ s2,
                                                  const float4* __restrict__ s3,
                                                  uint2* __restrict__ dst) {
  // boundaries in float4 units: wq 1048576 | wk 262144 | wv 262144 | wp 1048576
  int i = blockIdx.x * 256 + threadIdx.x;
  int st = gridDim.x * 256;
  for (; i < 2621440; i += st) {
    const float4* s;
    int off;
    if (i < 1048576)      { s = s0; off = i; }
    else if (i < 1310720) { s = s1; off = i - 1048576; }
    else if (i < 1572864) { s = s2; off = i - 1310720; }
    else                  { s = s3; off = i - 1572864; }
    float4 v = s[off];
    uint2 o;
    o.x = (uint32_t)f2bf(v.x) | ((uint32_t)f2bf(v.y) << 16);
    o.y = (uint32_t)f2bf(v.z) | ((uint32_t)f2bf(v.w) << 16);
    dst[i] = o;
  }
}

// ---------------- RoPE cos/sin table: [T=2032][64] ----------------
__global__ __launch_bounds__(256) void rope_table(float* __restrict__ tc,
                                                  float* __restrict__ ts) {
  int i = blockIdx.x * 256 + threadIdx.x;
  if (i >= 2032 * 64) return;
  int t = i >> 6, f = i & 63;
  float invf = 1.0f / powf(10000.0f, (float)f * (1.0f / 64.0f)); // accurate powf
  float ang = (float)t * invf;
  float s, c;
  sincosf(ang, &s, &c);                                           // accurate sincos
  tc[i] = c;
  ts[i] = s;
}

// ---------------- 256x256 8-phase GEMM (m201-template port) ----------------
// 512 thr = 8 waves (2M x 4N), wave-tile 128x64, BK=64, LDS 128KB:
//   [dbuf][A/B][region][128][64] u16; A regions by row-bit6 (mh), B by col-bit5 (nh).
// 4 phases/tile = C-quadrant (mh,nh) x K=64, 16 MFMA each. Per-phase region
// staging into JUST-FREED regions:  p0: B[nh1](t+1) | p1: A[mh0](t+2) |
// p3: A[mh1](t+2)+B[nh0](t+2). Wait ledger (FIFO-simulated):
//   steady outstanding entering tile t = 6 (A0,A1,Bnh0 of t+1);
//   p3: vmcnt(6) drains the 8 oldest of 14 = ALL of tile t+1 -> closing barrier
//   is the RAW gate; every region certified a full tile before first read.
//   WAR: each stage follows the closing barrier of its region's last-read phase.
// Phase: {ds_reads(4 or 12); stage(0/2/4); s_barrier; lgkmcnt(0); sched_barrier;
//         setprio(1) 16 MFMA setprio(0); [p3: vmcnt] ; s_barrier}
// XOR chunk swizzle: phys = (ks*4+l4) ^ (rr&7) -> 2 lanes/bank (free, m136).
// Grid 256 = 32bm x 8bn, col-major XCD chunk (1 B-panel per XCD L2).
// OUT 0: Q -> bf16 (B,16,L,128) scatter. OUT 2: proj -> fp32 row-major.
template <int OUT>
__global__ __launch_bounds__(512, 2) void gemm8(
    const u16* __restrict__ A, const u16* __restrict__ Wt,
    u16* __restrict__ Oa, float* __restrict__ OF) {
  __shared__ u16 lA[2][2][128 * 64];
  __shared__ u16 lB[2][2][128 * 64];
  const int tid = threadIdx.x;
  const int lane = tid & 63, wid = tid >> 6;
  const int wr = wid >> 2, wc = wid & 3;
  const int l15 = lane & 15, l4 = lane >> 4;

  const int bid = blockIdx.x;
  const int swz = (bid & 7) * 32 + (bid >> 3);   // XCD chunk (grid = 256)
  const int bn = swz >> 5, bm = swz & 31;        // col-major: 1 B-panel per XCD
  const int m0 = bm * 256;
  const int n0r = bn * 256;

  auto stageA = [&](int kt, int bs, int mh) {    // one 16KB region, 2 loads/thr
    const int kb = kt * 64;
#pragma unroll
    for (int c = 0; c < 2; ++c) {
      int cidx = tid + c * 512;
      int rr = cidx >> 3, pc = cidx & 7;
      int grow = mh * 64 + (rr & 63) + ((rr >> 6) << 7);   // rows with bit6==mh
      int kc = pc ^ (rr & 7);
      gload_lds16(A + (size_t)(m0 + grow) * 2048 + kb + kc * 8,
                  &lA[bs][mh][cidx * 8]);
    }
  };
  auto stageB = [&](int kt, int bs, int nh) {
    const int kb = kt * 64;
#pragma unroll
    for (int c = 0; c < 2; ++c) {
      int cidx = tid + c * 512;
      int rr = cidx >> 3, pc = cidx & 7;
      int gn = ((rr >> 5) << 6) + nh * 32 + (rr & 31);     // cols with bit5==nh
      int kc = pc ^ (rr & 7);
      gload_lds16(Wt + (size_t)(n0r + gn) * 2048 + kb + kc * 8,
                  &lB[bs][nh][cidx * 8]);
    }
  };
  auto readA = [&](int bs, int mh, int i, int ks) {
    int rr = wr * 64 + i * 16 + l15;
    return *(const s8v*)&lA[bs][mh][rr * 64 + (((ks * 4 + l4) ^ (rr & 7)) << 3)];
  };
  auto readB = [&](int bs, int nh, int j, int ks) {
    int rr = wc * 32 + j * 16 + l15;
    return *(const s8v*)&lB[bs][nh][rr * 64 + (((ks * 4 + l4) ^ (rr & 7)) << 3)];
  };

  const f4v Z4 = {0.f, 0.f, 0.f, 0.f};
  f4v acc[8][4];                 // [mh*4+i][nh*2+j]
#pragma unroll
  for (int i = 0; i < 8; i++)
#pragma unroll
    for (int j = 0; j < 4; j++) acc[i][j] = Z4;

  // prologue: tile0 full (8 loads) + tile1 minus B[nh1] (6 loads)
  stageA(0, 0, 0); stageA(0, 0, 1); stageB(0, 0, 0); stageB(0, 0, 1);
  stageA(1, 1, 0); stageA(1, 1, 1); stageB(1, 1, 0);
  asm volatile("s_waitcnt vmcnt(6)" ::: "memory");   // tile0 certified
  asm volatile("s_barrier" ::: "memory");

  const int NT = 32;                 // 2048 / 64
  for (int t = 0; t < NT; ++t) {
    const int bs = t & 1, nbs = bs ^ 1;
    s8v a[4][2], b[2][2];
    // ---------- phase 0: (mh0, nh0) ----------
#pragma unroll
    for (int i = 0; i < 4; ++i)
#pragma unroll
      for (int ks = 0; ks < 2; ++ks) a[i][ks] = readA(bs, 0, i, ks);
#pragma unroll
    for (int j = 0; j < 2; ++j)
#pragma unroll
      for (int ks = 0; ks < 2; ++ks) b[j][ks] = readB(bs, 0, j, ks);
    if (t + 1 < NT) stageB(t + 1, nbs, 1);
    asm volatile("s_barrier" ::: "memory");
    asm volatile("s_waitcnt lgkmcnt(0)" ::: "memory");
    __builtin_amdgcn_sched_barrier(0);
    __builtin_amdgcn_s_setprio(1);
#pragma unroll
    for (int i = 0; i < 4; ++i)
#pragma unroll
      for (int j = 0; j < 2; ++j)
#pragma unroll
        for (int ks = 0; ks < 2; ++ks)
          acc[i][j] = __builtin_amdgcn_mfma_f32_16x16x32_bf16(a[i][ks], b[j][ks], acc[i][j], 0, 0, 0);
    __builtin_amdgcn_s_setprio(0);
    asm volatile("s_barrier" ::: "memory");
    // ---------- phase 1: (mh0, nh1) ----------
#pragma unroll
    for (int j = 0; j < 2; ++j)
#pragma unroll
      for (int ks = 0; ks < 2; ++ks) b[j][ks] = readB(bs, 1, j, ks);
    if (t + 2 < NT) stageA(t + 2, bs, 0);
    asm volatile("s_barrier" ::: "memory");
    asm volatile("s_waitcnt lgkmcnt(0)" ::: "memory");
    __builtin_amdgcn_sched_barrier(0);
    __builtin_amdgcn_s_setprio(1);
#pragma unroll
    for (int i = 0; i < 4; ++i)
#pragma unroll
      for (int j = 0; j < 2; ++j)
#pragma unroll
        for (int ks = 0; ks < 2; ++ks)
          acc[i][2 + j] = __builtin_amdgcn_mfma_f32_16x16x32_bf16(a[i][ks], b[j][ks], acc[i][2 + j], 0, 0, 0);
    __builtin_amdgcn_s_setprio(0);
    asm volatile("s_barrier" ::: "memory");
    // ---------- phase 2: (mh1, nh0) ----------
#pragma unroll
    for (int i = 0; i < 4; ++i)
#pragma unroll
      for (int ks = 0; ks < 2; ++ks) a[i][ks] = readA(bs, 1, i, ks);
#pragma unroll
    for (int j = 0; j < 2; ++j)
#pragma unroll
      for (int ks = 0; ks < 2; ++ks) b[j][ks] = readB(bs, 0, j, ks);
    asm volatile("s_barrier" ::: "memory");
    asm volatile("s_waitcnt lgkmcnt(0)" ::: "memory");
    __builtin_amdgcn_sched_barrier(0);
    __builtin_amdgcn_s_setprio(1);
#pragma unroll
    for (int i = 0; i < 4; ++i)
#pragma unroll
      for (int j = 0; j < 2; ++j)
#pragma unroll
        for (int ks = 0; ks < 2; ++ks)
          acc[4 + i][j] = __builtin_amdgcn_mfma_f32_16x16x32_bf16(a[i][ks], b[j][ks], acc[4 + i][j], 0, 0, 0);
    __builtin_amdgcn_s_setprio(0);
    asm volatile("s_barrier" ::: "memory");
    // ---------- phase 3: (mh1, nh1) ----------
#pragma unroll
    for (int j = 0; j < 2; ++j)
#pragma unroll
      for (int ks = 0; ks < 2; ++ks) b[j][ks] = readB(bs, 1, j, ks);
    if (t + 2 < NT) { stageA(t + 2, bs, 1); stageB(t + 2, bs, 0); }
    asm volatile("s_barrier" ::: "memory");
    asm volatile("s_waitcnt lgkmcnt(0)" ::: "memory");
    __builtin_amdgcn_sched_barrier(0);
    __builtin_amdgcn_s_setprio(1);
#pragma unroll
    for (int i = 0; i < 4; ++i)
#pragma unroll
      for (int j = 0; j < 2; ++j)
#pragma unroll
        for (int ks = 0; ks < 2; ++ks)
          acc[4 + i][2 + j] = __builtin_amdgcn_mfma_f32_16x16x32_bf16(a[i][ks], b[j][ks], acc[4 + i][2 + j], 0, 0, 0);
    __builtin_amdgcn_s_setprio(0);
    if (t + 2 < NT)      asm volatile("s_waitcnt vmcnt(6)" ::: "memory");
    else if (t + 1 < NT) asm volatile("s_waitcnt vmcnt(0)" ::: "memory");
    asm volatile("s_barrier" ::: "memory");      // RAW gate: tile t+1 certified
  }

  const int colg0 = bn * 256 + wc * 64;
  if constexpr (OUT == 0) {                      // Q: (B,16,L,128) bf16
    const int hh = colg0 >> 7, d0 = colg0 & 127;
#pragma unroll
    for (int i = 0; i < 8; i++)
#pragma unroll
      for (int r = 0; r < 4; r++) {
        int m = m0 + wr * 128 + (i >> 2) * 64 + (i & 3) * 16 + l4 * 4 + r;
        int b2 = m >> 11, l = m & 2047;
        size_t base = ((size_t)(b2 * 16 + hh) * 2048 + l) * 128 + d0;
#pragma unroll
        for (int j = 0; j < 4; j++)
          Oa[base + (j >> 1) * 32 + (j & 1) * 16 + l15] = f2bf(acc[i][j][r]);
      }
  } else {                                       // proj: fp32 row-major
#pragma unroll
    for (int i = 0; i < 8; i++)
#pragma unroll
      for (int r = 0; r < 4; r++) {
        int m = m0 + wr * 128 + (i >> 2) * 64 + (i & 3) * 16 + l4 * 4 + r;
#pragma unroll
        for (int j = 0; j < 4; j++)
          OF[(size_t)m * 2048 + colg0 + (j >> 1) * 32 + (j & 1) * 16 + l15] = acc[i][j][r];
      }
  }
}

// ---------------- 256x128 KV GEMM (R10 region structure, unchanged) ----------------
__global__ __launch_bounds__(512, 2) void gemm_kv(
    const u16* __restrict__ A, const u16* __restrict__ Wt,
    u16* __restrict__ Oa, u16* __restrict__ Ob2) {
  constexpr int MI = 4;
  __shared__ u16 lA[2][2][256 * 32];
  __shared__ u16 lB[2][2][128 * 32];
  const int tid = threadIdx.x;
  const int lane = tid & 63, wid = tid >> 6;
  const int wr = wid >> 1, wc = wid & 1;
  const int l15 = lane & 15, l4 = lane >> 4;

  const int bid = blockIdx.x;
  const int swz = (bid & 7) * 32 + (bid >> 3);
  const int bn = swz >> 5, bm = swz & 31;
  const int m0 = bm * 256;
  const int n0r = bn * 128;

  auto stage_part = [&](int kt, int bs, int ks) {
    const int kb = kt * 64 + ks * 32;
#pragma unroll
    for (int c = 0; c < 2; ++c) {
      int cidx = tid + c * 512;
      int r = cidx >> 2, q = cidx & 3;
      int cc = q ^ ((r >> 2) & 3);
      gload_lds16(A + (size_t)(m0 + r) * 2048 + kb + cc * 8,
                  &lA[bs][ks][cidx * 8]);
    }
    {
      int cidx = tid;
      int r = cidx >> 2, q = cidx & 3;
      int cc = q ^ ((r >> 2) & 3);
      gload_lds16(Wt + (size_t)(n0r + r) * 2048 + kb + cc * 8,
                  &lB[bs][ks][cidx * 8]);
    }
  };
  auto roff = [&](int fr, int c) {
    return (fr * 4 + (c ^ ((fr >> 2) & 3))) * 8;
  };

  const f4v Z4 = {0.f, 0.f, 0.f, 0.f};
  f4v acc[MI][4];
#pragma unroll
  for (int i = 0; i < MI; i++)
#pragma unroll
    for (int j = 0; j < 4; j++) acc[i][j] = Z4;

  stage_part(0, 0, 0); stage_part(0, 0, 1);
  stage_part(1, 1, 0); stage_part(1, 1, 1);

  const int NT = 32;
  for (int t = 0; t < NT; ++t) {
    const int bs = t & 1;
    if (t + 1 < NT) asm volatile("s_waitcnt vmcnt(6)" ::: "memory");
    else            asm volatile("s_waitcnt vmcnt(0)" ::: "memory");
    asm volatile("s_barrier" ::: "memory");
    const bool pf = (t + 2 < NT);
#pragma unroll
    for (int ks = 0; ks < 2; ++ks) {
      s8v afrg[MI], bfrg[4];
#pragma unroll
      for (int i = 0; i < MI; ++i)
        afrg[i] = *(const s8v*)&lA[bs][ks][roff(wr * (MI * 16) + i * 16 + l15, l4)];
#pragma unroll
      for (int j = 0; j < 4; ++j)
        bfrg[j] = *(const s8v*)&lB[bs][ks][roff(wc * 64 + j * 16 + l15, l4)];
      asm volatile("s_waitcnt lgkmcnt(0)" ::: "memory");
      __builtin_amdgcn_sched_barrier(0);
      asm volatile("s_barrier" ::: "memory");
      if (pf) stage_part(t + 2, bs, ks);
      __builtin_amdgcn_s_setprio(1);
#pragma unroll
      for (int i = 0; i < MI; ++i)
#pragma unroll
        for (int j = 0; j < 4; ++j)
          acc[i][j] = __builtin_amdgcn_mfma_f32_16x16x32_bf16(afrg[i], bfrg[j], acc[i][j], 0, 0, 0);
      __builtin_amdgcn_s_setprio(0);
    }
  }

  const int colg = bn * 128 + wc * 64;
  u16* Ob = (colg < 512) ? Oa : Ob2;
  const int hh = (colg & 511) >> 7, d0 = colg & 127;
#pragma unroll
  for (int i = 0; i < MI; i++)
#pragma unroll
    for (int r = 0; r < 4; r++) {
      int m = m0 + wr * (MI * 16) + i * 16 + l4 * 4 + r;
      int b = m >> 11, l = m & 2047;
      size_t base = ((size_t)(b * 4 + hh) * 2048 + l) * 128 + d0;
#pragma unroll
      for (int j = 0; j < 4; j++)
        Ob[base + j * 16 + l15] = f2bf(acc[i][j][r]);
    }
}

// ---------------- RMSNorm + RoPE for K ONLY (q fused into attn) ----------------
__global__ __launch_bounds__(256) void norm_rope_k(u16* __restrict__ buf,
                                                   const float* __restrict__ tc,
                                                   const float* __restrict__ ts) {
  const int lane = threadIdx.x & 63;
  const int gw = blockIdx.x * 4 + (threadIdx.x >> 6);
  const int nw = gridDim.x * 4;
  for (int row = gw; row < 32768; row += nw) {
    int l = row & 2047;
    u16* p = buf + (size_t)row * 128;
    float x1 = bf2f(p[lane]);
    float x2 = bf2f(p[lane + 64]);
    float ss = x1 * x1 + x2 * x2;
#pragma unroll
    for (int off = 32; off > 0; off >>= 1) ss += __shfl_xor(ss, off, 64);
    float r = rsqrtf(ss * (1.0f / 128.0f) + 1.1920929e-07f);
    x1 *= r; x2 *= r;
    if (l >= 16) {
      int t = l - 16;
      float c = tc[t * 64 + lane], s = ts[t * 64 + lane];
      float o1 = x1 * c + x2 * s;
      float o2 = -x1 * s + x2 * c;
      x1 = o1; x2 = o2;
    }
    p[lane] = f2bf(x1);
    p[lane + 64] = f2bf(x2);
  }
}

// ---------------- V transpose: (bg,L,128) -> (bg,128,L), 64x64 LDS tiles, XOR swizzle
__global__ __launch_bounds__(256) void transpose_v(const u16* __restrict__ v,
                                                   u16* __restrict__ vt) {
  __shared__ u16 t[64][64];
  const int l0 = blockIdx.x * 64, d0 = blockIdx.y * 64, bg = blockIdx.z;
  const int tid = threadIdx.x;
#pragma unroll
  for (int it = 0; it < 2; ++it) {
    int lin = it * 256 + tid;
    int r = lin >> 3, cb = lin & 7;
    s8v val = *(const s8v*)&v[((bg * 2048 + l0 + r) * 128) + d0 + cb * 8];
    *(s8v*)&t[r][(cb ^ (r & 7)) * 8] = val;
  }
  __syncthreads();
#pragma unroll
  for (int it = 0; it < 2; ++it) {
    int lin = it * 256 + tid;
    int r2 = lin >> 3, c2 = (lin & 7) * 8;   // r2 = d idx, c2 = l idx
    s8v o;
#pragma unroll
    for (int j = 0; j < 8; ++j) {
      int rr = c2 + j, cc = r2;
      o[j] = (short)t[rr][(cc & 7) + 8 * ((cc >> 3) ^ (rr & 7))];
    }
    *(s8v*)&vt[((bg * 128 + d0 + r2) * 2048) + l0 + c2] = o;
  }
}

// ---------------- flash attention v3 (unchanged from R12) ----------------
__global__ __launch_bounds__(512, 2) void attn(const u16* __restrict__ q,
                                               const u16* __restrict__ k,
                                               const u16* __restrict__ vt,
                                               u16* __restrict__ y,
                                               const float* __restrict__ qg,
                                               const float* __restrict__ tc,
                                               const float* __restrict__ ts) {
  __shared__ u16 lK[2][64 * 128];   // row kv: 16 slots of 8 u16, slot s holds d-block s^(kv&7)
  __shared__ u16 lVT[2][128 * 64];  // row d:   8 slots of 8 u16, slot s holds kv-block s^(d&7)
  const int tid = threadIdx.x;
  const int lane = tid & 63, wid = tid >> 6;
  const int l31 = lane & 31, hi = lane >> 5;

  const int bid = (int)blockIdx.x;                 // 0..255
  const int bg = (bid & 7) * 2 + (bid >> 7);       // XCD k hosts bg {2k,2k+1}
  const int pairi = (bid >> 3) & 15;               // 0..15
  const int b = bg >> 2, g = bg & 3;
  const int h = g * 4 + (wid & 3);
  const int se = wid >> 2;                         // row-half 0/1

  const u16* qh = q + (size_t)(b * 16 + h) * 2048 * 128;
  const u16* kb0 = k + (size_t)(b * 4 + g) * 2048 * 128;
  const u16* vtb0 = vt + (size_t)(b * 4 + g) * 128 * 2048;
  const float gscale = qg[h] * (0.08838834764831845f * 1.4426950408889634f);

  auto stage = [&](int t, int bufsel) {
    const int kv0 = t * 64;
#pragma unroll
    for (int it = 0; it < 2; ++it) {        // K tile 64x128 (16KB), swizzled source
      int lin = it * 512 + tid;
      int kj = lin >> 4, s = lin & 15;
      gload_lds16(kb0 + (size_t)(kv0 + kj) * 128 + ((s ^ (kj & 7)) * 8),
                  &lK[bufsel][lin * 8]);
    }
#pragma unroll
    for (int it = 0; it < 2; ++it) {        // VT tile 128x64 (16KB), swizzled source
      int lin = it * 512 + tid;
      int d = lin >> 3, s = lin & 7;
      gload_lds16(vtb0 + (size_t)d * 2048 + kv0 + ((s ^ (d & 7)) * 8),
                  &lVT[bufsel][lin * 8]);
    }
  };

  for (int ph = 0; ph < 2; ++ph) {
    const int qt = ph ? (31 - pairi) : pairi;
    const int q0 = qt * 64;
    const int nt = qt + 1;                  // KV tiles of 64
    const int pos = q0 + 32 * se + l31;

    // ---- fused Q: RMSNorm + RoPE + gain*(1/sqrt(128))*log2(e), pack B-frags ----
    s8v qf[8];
    {
      const u16* qp = qh + (size_t)pos * 128 + hi * 8;
      s8v qr[8];
#pragma unroll
      for (int ks = 0; ks < 8; ++ks) qr[ks] = *(const s8v*)&qp[ks * 16];
      float ssum = 0.f;
#pragma unroll
      for (int ks = 0; ks < 8; ++ks)
#pragma unroll
        for (int j = 0; j < 8; ++j) {
          float v = bf2f((u16)qr[ks][j]);
          ssum += v * v;
        }
      ssum += __shfl_xor(ssum, 32, 64);
      const float rn = rsqrtf(ssum * (1.0f / 128.0f) + 1.1920929e-07f) * gscale;
      const bool rot = (pos >= 16);
      const int tt = pos - 16;
#pragma unroll
      for (int ks = 0; ks < 4; ++ks) {
        float cv[8], sv[8];
        if (rot) {
          const float* cp = &tc[tt * 64 + ks * 16 + hi * 8];
          const float* sp = &ts[tt * 64 + ks * 16 + hi * 8];
          *(float4*)&cv[0] = *(const float4*)cp;
          *(float4*)&cv[4] = *(const float4*)(cp + 4);
          *(float4*)&sv[0] = *(const float4*)sp;
          *(float4*)&sv[4] = *(const float4*)(sp + 4);
        }
        uint32_t wlo[4], whi[4];
#pragma unroll
        for (int j2 = 0; j2 < 4; ++j2) {
          float o1[2], o2[2];
#pragma unroll
          for (int e = 0; e < 2; ++e) {
            const int j = j2 * 2 + e;
            float x1 = bf2f((u16)qr[ks][j]);
            float x2 = bf2f((u16)qr[ks + 4][j]);
            float a = x1, bb = x2;
            if (rot) { a = x1 * cv[j] + x2 * sv[j]; bb = x2 * cv[j] - x1 * sv[j]; }
            o1[e] = a * rn;
            o2[e] = bb * rn;
          }
          asm("v_cvt_pk_bf16_f32 %0, %1, %2" : "=v"(wlo[j2]) : "v"(o1[0]), "v"(o1[1]));
          asm("v_cvt_pk_bf16_f32 %0, %1, %2" : "=v"(whi[j2]) : "v"(o2[0]), "v"(o2[1]));
        }
        union { uint32_t u[4]; s8v v; } ua, ub;
        ua.u[0] = wlo[0]; ua.u[1] = wlo[1]; ua.u[2] = wlo[2]; ua.u[3] = wlo[3];
        ub.u[0] = whi[0]; ub.u[1] = whi[1]; ub.u[2] = whi[2]; ub.u[3] = whi[3];
        qf[ks] = ua.v;
        qf[ks + 4] = ub.v;
      }
    }

    f16v yacc[4];
#pragma unroll
    for (int j = 0; j < 4; ++j)
#pragma unroll
      for (int r = 0; r < 16; ++r) yacc[j][r] = 0.f;
    float mrow = -1e30f, lrow = 0.f;

    stage(0, 0);
    __syncthreads();

    for (int t = 0; t < nt; ++t) {
      const int cur = t & 1;
      if (t + 1 < nt) stage(t + 1, cur ^ 1);
      const int kv0 = t * 64;

      // ---- QK^T swapped: S^T[kv][q] in exp2 domain, two 32-kv chunks ----
      f16v s0a, s1a;
#pragma unroll
      for (int r = 0; r < 16; ++r) { s0a[r] = 0.f; s1a[r] = 0.f; }
      __builtin_amdgcn_s_setprio(1);
#pragma unroll
      for (int ks = 0; ks < 8; ++ks) {
        const int slot = (2 * ks + hi) ^ (l31 & 7);
        s8v kf0 = *(const s8v*)&lK[cur][(l31)*128 + slot * 8];
        s8v kf1 = *(const s8v*)&lK[cur][(32 + l31) * 128 + slot * 8];
        s0a = __builtin_amdgcn_mfma_f32_32x32x16_bf16(kf0, qf[ks], s0a, 0, 0, 0);
        s1a = __builtin_amdgcn_mfma_f32_32x32x16_bf16(kf1, qf[ks], s1a, 0, 0, 0);
      }
      __builtin_amdgcn_s_setprio(0);

      // ---- causal mask + row max (in-register; scores already log2-scaled) ----
      const bool last = (t == nt - 1);
      float p0[16], p1[16];
      float pmax = -1e30f;
#pragma unroll
      for (int r = 0; r < 16; ++r) {
        const int kvloc = (r & 3) + 8 * (r >> 2) + 4 * hi;
        float v0 = s0a[r];
        float v1 = s1a[r];
        if (last) {
          if (kv0 + kvloc > pos) v0 = -1e30f;
          if (kv0 + 32 + kvloc > pos) v1 = -1e30f;
        }
        p0[r] = v0; p1[r] = v1;
        pmax = fmaxf(pmax, fmaxf(v0, v1));
      }
      pmax = fmaxf(pmax, __shfl_xor(pmax, 32, 64));

      // ---- defer-max (T13): THR = 8*log2e in exp2 domain ----
      if (!__all(pmax - mrow <= 11.541560327111707f)) {
        float mnew = fmaxf(mrow, pmax);
        float corr = __builtin_amdgcn_exp2f(mrow - mnew);
#pragma unroll
        for (int r = 0; r < 16; ++r) {
          const int qloc = (r & 3) + 8 * (r >> 2) + 4 * hi;
          float cb = __shfl(corr, qloc, 64);
          yacc[0][r] *= cb; yacc[1][r] *= cb; yacc[2][r] *= cb; yacc[3][r] *= cb;
        }
        lrow *= corr;
        mrow = mnew;
      }

      // ---- exp2 + fp32 row sum (denominator unrounded) ----
      float ps = 0.f;
#pragma unroll
      for (int r = 0; r < 16; ++r) {
        float e0 = __builtin_amdgcn_exp2f(p0[r] - mrow);
        float e1 = __builtin_amdgcn_exp2f(p1[r] - mrow);
        p0[r] = e0; p1[r] = e1;
        ps += e0 + e1;
      }
      ps += __shfl_xor(ps, 32, 64);
      lrow += ps;

      // ---- PV: cvt_pk pack + permlane32_swap exchange + MFMA ----
      __builtin_amdgcn_s_setprio(1);
#pragma unroll
      for (int ks = 0; ks < 4; ++ks) {
        const float* pc = (ks < 2) ? p0 : p1;
        const int rb = 8 * (ks & 1);
        uint32_t A0, A1, B0, B1;
        asm("v_cvt_pk_bf16_f32 %0, %1, %2" : "=v"(A0) : "v"(pc[rb + 0]), "v"(pc[rb + 1]));
        asm("v_cvt_pk_bf16_f32 %0, %1, %2" : "=v"(A1) : "v"(pc[rb + 2]), "v"(pc[rb + 3]));
        asm("v_cvt_pk_bf16_f32 %0, %1, %2" : "=v"(B0) : "v"(pc[rb + 4]), "v"(pc[rb + 5]));
        asm("v_cvt_pk_bf16_f32 %0, %1, %2" : "=v"(B1) : "v"(pc[rb + 6]), "v"(pc[rb + 7]));
        // after swap: A0 = [A0_lo|B0_lo] = uu0, B0 = [A0_hi|B0_hi] = uu2 (ditto A1/B1)
        asm("v_permlane32_swap_b32 %0, %1" : "+v"(A0), "+v"(B0));
        asm("v_permlane32_swap_b32 %0, %1" : "+v"(A1), "+v"(B1));
        union { uint32_t u[4]; s8v v; } uu;
        uu.u[0] = A0; uu.u[1] = A1; uu.u[2] = B0; uu.u[3] = B1;
#pragma unroll
        for (int jd = 0; jd < 4; ++jd) {
          const int rowd = 32 * jd + l31;
          const int slot = (2 * ks + hi) ^ (l31 & 7);
          s8v vf = *(const s8v*)&lVT[cur][rowd * 64 + slot * 8];
          yacc[jd] = __builtin_amdgcn_mfma_f32_32x32x16_bf16(uu.v, vf, yacc[jd], 0, 0, 0);
        }
      }
      __builtin_amdgcn_s_setprio(0);
      __syncthreads();
    }

    // ---- finalize: broadcast 1/l per C-row, write y (B,L,H*128) bf16 ----
    float inv = 1.0f / lrow;
#pragma unroll
    for (int r = 0; r < 16; ++r) {
      const int qloc = (r & 3) + 8 * (r >> 2) + 4 * hi;
      float ib = __shfl(inv, qloc, 64);
      const int qrow = q0 + 32 * se + qloc;
      size_t base = ((size_t)(b * 2048 + qrow)) * 2048 + h * 128 + l31;
#pragma unroll
      for (int jd = 0; jd < 4; ++jd)
        y[base + 32 * jd] = f2bf(yacc[jd][r] * ib);
    }
  }
}

extern "C" void kernel_launch(void* const* d_in, const int* in_sizes, int n_in,
                              void* d_out, int out_size, void* d_ws, size_t ws_size,
                              hipStream_t stream) {
  const float* x  = (const float*)d_in[0];
  const float* Wq = (const float*)d_in[1];
  const float* Wk = (const float*)d_in[2];
  const float* Wv = (const float*)d_in[3];
  const float* Wp = (const float*)d_in[4];
  const float* qg = (const float*)d_in[5];
  float* out = (float*)d_out;

  char* ws = (char*)d_ws;
  size_t off = 0;
  auto alloc = [&](size_t bytes) {
    void* p = ws + off;
    off += (bytes + 255) & ~(size_t)255;
    return p;
  };
  u16* x_bf  = (u16*)alloc((size_t)8192 * 2048 * 2);   // also reused as y_bf
  u16* wq_bf = (u16*)alloc((size_t)2048 * 2048 * 2);   // also reused as vt_bf
  u16* wk_bf = (u16*)alloc((size_t)512 * 2048 * 2);    // wk|wv contiguous = KV weight
  u16* wv_bf = (u16*)alloc((size_t)512 * 2048 * 2);
  u16* wp_bf = (u16*)alloc((size_t)2048 * 2048 * 2);
  u16* q_bf  = (u16*)alloc((size_t)4 * 16 * 2048 * 128 * 2);
  u16* k_bf  = (u16*)alloc((size_t)4 * 4 * 2048 * 128 * 2);
  u16* v_bf  = (u16*)alloc((size_t)4 * 4 * 2048 * 128 * 2);
  float* tab = (float*)alloc((size_t)2032 * 64 * 2 * 4);
  u16* y_bf  = x_bf;    // x dead after QKV GEMMs
  u16* vt_bf = wq_bf;   // Wq dead after Q GEMM (same size)

  cvt_bf16<<<2048, 256, 0, stream>>>((const float4*)x, (uint2*)x_bf, 8192 * 2048 / 4);
  cvt_bf16_w<<<1024, 256, 0, stream>>>((const float4*)Wq, (const float4*)Wk,
                                       (const float4*)Wv, (const float4*)Wp,
                                       (uint2*)wq_bf);   // wq|wk|wv|wp contiguous
  rope_table<<<(2032 * 64 + 255) / 256, 256, 0, stream>>>(tab, tab + 2032 * 64);

  gemm8<0><<<dim3(256), 512, 0, stream>>>(x_bf, wq_bf, q_bf, nullptr);
  gemm_kv<<<dim3(256), 512, 0, stream>>>(x_bf, wk_bf, k_bf, v_bf);
  norm_rope_k<<<256, 256, 0, stream>>>(k_bf, tab, tab + 2032 * 64);
  transpose_v<<<dim3(32, 2, 16), 256, 0, stream>>>(v_bf, vt_bf);
  attn<<<dim3(256), 512, 0, stream>>>(q_bf, k_bf, vt_bf, y_bf, qg,
                                      tab, tab + 2032 * 64);
  gemm8<2><<<dim3(256), 512, 0, stream>>>(y_bf, wp_bf, nullptr, out);
}

// Round 14
// 333.252 us; speedup vs baseline: 1.1235x; 1.0324x over previous
//
#include <hip/hip_runtime.h>
#include <stdint.h>

// Shapes (fixed): B=4 L=2048 D=2048 H=16 KVH=4 HD=128 M=16 T=2032
typedef unsigned short u16;
typedef short s8v __attribute__((ext_vector_type(8)));   // 8 bf16 (4 VGPR) MFMA frag
typedef float f4v __attribute__((ext_vector_type(4)));   // 16x16 MFMA accum
typedef float f16v __attribute__((ext_vector_type(16))); // 32x32 MFMA accum

typedef __attribute__((address_space(1))) char gchar;
typedef __attribute__((address_space(3))) char lchar;

static __device__ __forceinline__ u16 f2bf(float f) {
  uint32_t x = __float_as_uint(f);
  x += 0x7fffu + ((x >> 16) & 1u);            // RNE
  return (u16)(x >> 16);
}
static __device__ __forceinline__ float bf2f(u16 u) {
  return __uint_as_float(((uint32_t)u) << 16);
}
// async global->LDS, 16B per lane. LDS dest must be wave-linear (base + lane*16).
static __device__ __forceinline__ void gload_lds16(const void* g, void* l) {
  __builtin_amdgcn_global_load_lds((gchar*)(uintptr_t)g,
                                   (lchar*)(uint32_t)(uintptr_t)l, 16, 0, 0);
}

// ---------------- fp32 -> bf16 convert (vectorized) ----------------
__global__ __launch_bounds__(256) void cvt_bf16(const float4* __restrict__ src,
                                                uint2* __restrict__ dst, int n4) {
  int i = blockIdx.x * 256 + threadIdx.x;
  int st = gridDim.x * 256;
  for (; i < n4; i += st) {
    float4 v = src[i];
    uint2 o;
    o.x = (uint32_t)f2bf(v.x) | ((uint32_t)f2bf(v.y) << 16);
    o.y = (uint32_t)f2bf(v.z) | ((uint32_t)f2bf(v.w) << 16);
    dst[i] = o;
  }
}

// all 4 weight matrices in one launch; dst regions are contiguous in ws.
__global__ __launch_bounds__(256) void cvt_bf16_w(const float4* __restrict__ s0,
                                                  const float4* __restrict__ s1,
                                                  const float4* __restrict__ s2,
                                                  const float4* __restrict__ s3,
                                                  uint2* __restrict__ dst) {
  // boundaries in float4 units: wq 1048576 | wk 262144 | wv 262144 | wp 1048576
  int i = blockIdx.x * 256 + threadIdx.x;
  int st = gridDim.x * 256;
  for (; i < 2621440; i += st) {
    const float4* s;
    int off;
    if (i < 1048576)      { s = s0; off = i; }
    else if (i < 1310720) { s = s1; off = i - 1048576; }
    else if (i < 1572864) { s = s2; off = i - 1310720; }
    else                  { s = s3; off = i - 1572864; }
    float4 v = s[off];
    uint2 o;
    o.x = (uint32_t)f2bf(v.x) | ((uint32_t)f2bf(v.y) << 16);
    o.y = (uint32_t)f2bf(v.z) | ((uint32_t)f2bf(v.w) << 16);
    dst[i] = o;
  }
}

// ---------------- RoPE cos/sin table: [T=2032][64] ----------------
__global__ __launch_bounds__(256) void rope_table(float* __restrict__ tc,
                                                  float* __restrict__ ts) {
  int i = blockIdx.x * 256 + threadIdx.x;
  if (i >= 2032 * 64) return;
  int t = i >> 6, f = i & 63;
  float invf = 1.0f / powf(10000.0f, (float)f * (1.0f / 64.0f)); // accurate powf
  float ang = (float)t * invf;
  float s, c;
  sincosf(ang, &s, &c);                                           // accurate sincos
  tc[i] = c;
  ts[i] = s;
}

// ---------------- 256x256 8-phase GEMM (m201-template port, unchanged R13) ----------------
template <int OUT>
__global__ __launch_bounds__(512, 2) void gemm8(
    const u16* __restrict__ A, const u16* __restrict__ Wt,
    u16* __restrict__ Oa, float* __restrict__ OF) {
  __shared__ u16 lA[2][2][128 * 64];
  __shared__ u16 lB[2][2][128 * 64];
  const int tid = threadIdx.x;
  const int lane = tid & 63, wid = tid >> 6;
  const int wr = wid >> 2, wc = wid & 3;
  const int l15 = lane & 15, l4 = lane >> 4;

  const int bid = blockIdx.x;
  const int swz = (bid & 7) * 32 + (bid >> 3);   // XCD chunk (grid = 256)
  const int bn = swz >> 5, bm = swz & 31;        // col-major: 1 B-panel per XCD
  const int m0 = bm * 256;
  const int n0r = bn * 256;

  auto stageA = [&](int kt, int bs, int mh) {    // one 16KB region, 2 loads/thr
    const int kb = kt * 64;
#pragma unroll
    for (int c = 0; c < 2; ++c) {
      int cidx = tid + c * 512;
      int rr = cidx >> 3, pc = cidx & 7;
      int grow = mh * 64 + (rr & 63) + ((rr >> 6) << 7);   // rows with bit6==mh
      int kc = pc ^ (rr & 7);
      gload_lds16(A + (size_t)(m0 + grow) * 2048 + kb + kc * 8,
                  &lA[bs][mh][cidx * 8]);
    }
  };
  auto stageB = [&](int kt, int bs, int nh) {
    const int kb = kt * 64;
#pragma unroll
    for (int c = 0; c < 2; ++c) {
      int cidx = tid + c * 512;
      int rr = cidx >> 3, pc = cidx & 7;
      int gn = ((rr >> 5) << 6) + nh * 32 + (rr & 31);     // cols with bit5==nh
      int kc = pc ^ (rr & 7);
      gload_lds16(Wt + (size_t)(n0r + gn) * 2048 + kb + kc * 8,
                  &lB[bs][nh][cidx * 8]);
    }
  };
  auto readA = [&](int bs, int mh, int i, int ks) {
    int rr = wr * 64 + i * 16 + l15;
    return *(const s8v*)&lA[bs][mh][rr * 64 + (((ks * 4 + l4) ^ (rr & 7)) << 3)];
  };
  auto readB = [&](int bs, int nh, int j, int ks) {
    int rr = wc * 32 + j * 16 + l15;
    return *(const s8v*)&lB[bs][nh][rr * 64 + (((ks * 4 + l4) ^ (rr & 7)) << 3)];
  };

  const f4v Z4 = {0.f, 0.f, 0.f, 0.f};
  f4v acc[8][4];                 // [mh*4+i][nh*2+j]
#pragma unroll
  for (int i = 0; i < 8; i++)
#pragma unroll
    for (int j = 0; j < 4; j++) acc[i][j] = Z4;

  // prologue: tile0 full (8 loads) + tile1 minus B[nh1] (6 loads)
  stageA(0, 0, 0); stageA(0, 0, 1); stageB(0, 0, 0); stageB(0, 0, 1);
  stageA(1, 1, 0); stageA(1, 1, 1); stageB(1, 1, 0);
  asm volatile("s_waitcnt vmcnt(6)" ::: "memory");   // tile0 certified
  asm volatile("s_barrier" ::: "memory");

  const int NT = 32;                 // 2048 / 64
  for (int t = 0; t < NT; ++t) {
    const int bs = t & 1, nbs = bs ^ 1;
    s8v a[4][2], b[2][2];
    // ---------- phase 0: (mh0, nh0) ----------
#pragma unroll
    for (int i = 0; i < 4; ++i)
#pragma unroll
      for (int ks = 0; ks < 2; ++ks) a[i][ks] = readA(bs, 0, i, ks);
#pragma unroll
    for (int j = 0; j < 2; ++j)
#pragma unroll
      for (int ks = 0; ks < 2; ++ks) b[j][ks] = readB(bs, 0, j, ks);
    if (t + 1 < NT) stageB(t + 1, nbs, 1);
    asm volatile("s_barrier" ::: "memory");
    asm volatile("s_waitcnt lgkmcnt(0)" ::: "memory");
    __builtin_amdgcn_sched_barrier(0);
    __builtin_amdgcn_s_setprio(1);
#pragma unroll
    for (int i = 0; i < 4; ++i)
#pragma unroll
      for (int j = 0; j < 2; ++j)
#pragma unroll
        for (int ks = 0; ks < 2; ++ks)
          acc[i][j] = __builtin_amdgcn_mfma_f32_16x16x32_bf16(a[i][ks], b[j][ks], acc[i][j], 0, 0, 0);
    __builtin_amdgcn_s_setprio(0);
    asm volatile("s_barrier" ::: "memory");
    // ---------- phase 1: (mh0, nh1) ----------
#pragma unroll
    for (int j = 0; j < 2; ++j)
#pragma unroll
      for (int ks = 0; ks < 2; ++ks) b[j][ks] = readB(bs, 1, j, ks);
    if (t + 2 < NT) stageA(t + 2, bs, 0);
    asm volatile("s_barrier" ::: "memory");
    asm volatile("s_waitcnt lgkmcnt(0)" ::: "memory");
    __builtin_amdgcn_sched_barrier(0);
    __builtin_amdgcn_s_setprio(1);
#pragma unroll
    for (int i = 0; i < 4; ++i)
#pragma unroll
      for (int j = 0; j < 2; ++j)
#pragma unroll
        for (int ks = 0; ks < 2; ++ks)
          acc[i][2 + j] = __builtin_amdgcn_mfma_f32_16x16x32_bf16(a[i][ks], b[j][ks], acc[i][2 + j], 0, 0, 0);
    __builtin_amdgcn_s_setprio(0);
    asm volatile("s_barrier" ::: "memory");
    // ---------- phase 2: (mh1, nh0) ----------
#pragma unroll
    for (int i = 0; i < 4; ++i)
#pragma unroll
      for (int ks = 0; ks < 2; ++ks) a[i][ks] = readA(bs, 1, i, ks);
#pragma unroll
    for (int j = 0; j < 2; ++j)
#pragma unroll
      for (int ks = 0; ks < 2; ++ks) b[j][ks] = readB(bs, 0, j, ks);
    asm volatile("s_barrier" ::: "memory");
    asm volatile("s_waitcnt lgkmcnt(0)" ::: "memory");
    __builtin_amdgcn_sched_barrier(0);
    __builtin_amdgcn_s_setprio(1);
#pragma unroll
    for (int i = 0; i < 4; ++i)
#pragma unroll
      for (int j = 0; j < 2; ++j)
#pragma unroll
        for (int ks = 0; ks < 2; ++ks)
          acc[4 + i][j] = __builtin_amdgcn_mfma_f32_16x16x32_bf16(a[i][ks], b[j][ks], acc[4 + i][j], 0, 0, 0);
    __builtin_amdgcn_s_setprio(0);
    asm volatile("s_barrier" ::: "memory");
    // ---------- phase 3: (mh1, nh1) ----------
#pragma unroll
    for (int j = 0; j < 2; ++j)
#pragma unroll
      for (int ks = 0; ks < 2; ++ks) b[j][ks] = readB(bs, 1, j, ks);
    if (t + 2 < NT) { stageA(t + 2, bs, 1); stageB(t + 2, bs, 0); }
    asm volatile("s_barrier" ::: "memory");
    asm volatile("s_waitcnt lgkmcnt(0)" ::: "memory");
    __builtin_amdgcn_sched_barrier(0);
    __builtin_amdgcn_s_setprio(1);
#pragma unroll
    for (int i = 0; i < 4; ++i)
#pragma unroll
      for (int j = 0; j < 2; ++j)
#pragma unroll
        for (int ks = 0; ks < 2; ++ks)
          acc[4 + i][2 + j] = __builtin_amdgcn_mfma_f32_16x16x32_bf16(a[i][ks], b[j][ks], acc[4 + i][2 + j], 0, 0, 0);
    __builtin_amdgcn_s_setprio(0);
    if (t + 2 < NT)      asm volatile("s_waitcnt vmcnt(6)" ::: "memory");
    else if (t + 1 < NT) asm volatile("s_waitcnt vmcnt(0)" ::: "memory");
    asm volatile("s_barrier" ::: "memory");      // RAW gate: tile t+1 certified
  }

  const int colg0 = bn * 256 + wc * 64;
  if constexpr (OUT == 0) {                      // Q: (B,16,L,128) bf16
    const int hh = colg0 >> 7, d0 = colg0 & 127;
#pragma unroll
    for (int i = 0; i < 8; i++)
#pragma unroll
      for (int r = 0; r < 4; r++) {
        int m = m0 + wr * 128 + (i >> 2) * 64 + (i & 3) * 16 + l4 * 4 + r;
        int b2 = m >> 11, l = m & 2047;
        size_t base = ((size_t)(b2 * 16 + hh) * 2048 + l) * 128 + d0;
#pragma unroll
        for (int j = 0; j < 4; j++)
          Oa[base + (j >> 1) * 32 + (j & 1) * 16 + l15] = f2bf(acc[i][j][r]);
      }
  } else {                                       // proj: fp32 row-major
#pragma unroll
    for (int i = 0; i < 8; i++)
#pragma unroll
      for (int r = 0; r < 4; r++) {
        int m = m0 + wr * 128 + (i >> 2) * 64 + (i & 3) * 16 + l4 * 4 + r;
#pragma unroll
        for (int j = 0; j < 4; j++)
          OF[(size_t)m * 2048 + colg0 + (j >> 1) * 32 + (j & 1) * 16 + l15] = acc[i][j][r];
      }
  }
}

// ---------------- 256x128 KV GEMM (R10 region structure, unchanged) ----------------
__global__ __launch_bounds__(512, 2) void gemm_kv(
    const u16* __restrict__ A, const u16* __restrict__ Wt,
    u16* __restrict__ Oa, u16* __restrict__ Ob2) {
  constexpr int MI = 4;
  __shared__ u16 lA[2][2][256 * 32];
  __shared__ u16 lB[2][2][128 * 32];
  const int tid = threadIdx.x;
  const int lane = tid & 63, wid = tid >> 6;
  const int wr = wid >> 1, wc = wid & 1;
  const int l15 = lane & 15, l4 = lane >> 4;

  const int bid = blockIdx.x;
  const int swz = (bid & 7) * 32 + (bid >> 3);
  const int bn = swz >> 5, bm = swz & 31;
  const int m0 = bm * 256;
  const int n0r = bn * 128;

  auto stage_part = [&](int kt, int bs, int ks) {
    const int kb = kt * 64 + ks * 32;
#pragma unroll
    for (int c = 0; c < 2; ++c) {
      int cidx = tid + c * 512;
      int r = cidx >> 2, q = cidx & 3;
      int cc = q ^ ((r >> 2) & 3);
      gload_lds16(A + (size_t)(m0 + r) * 2048 + kb + cc * 8,
                  &lA[bs][ks][cidx * 8]);
    }
    {
      int cidx = tid;
      int r = cidx >> 2, q = cidx & 3;
      int cc = q ^ ((r >> 2) & 3);
      gload_lds16(Wt + (size_t)(n0r + r) * 2048 + kb + cc * 8,
                  &lB[bs][ks][cidx * 8]);
    }
  };
  auto roff = [&](int fr, int c) {
    return (fr * 4 + (c ^ ((fr >> 2) & 3))) * 8;
  };

  const f4v Z4 = {0.f, 0.f, 0.f, 0.f};
  f4v acc[MI][4];
#pragma unroll
  for (int i = 0; i < MI; i++)
#pragma unroll
    for (int j = 0; j < 4; j++) acc[i][j] = Z4;

  stage_part(0, 0, 0); stage_part(0, 0, 1);
  stage_part(1, 1, 0); stage_part(1, 1, 1);

  const int NT = 32;
  for (int t = 0; t < NT; ++t) {
    const int bs = t & 1;
    if (t + 1 < NT) asm volatile("s_waitcnt vmcnt(6)" ::: "memory");
    else            asm volatile("s_waitcnt vmcnt(0)" ::: "memory");
    asm volatile("s_barrier" ::: "memory");
    const bool pf = (t + 2 < NT);
#pragma unroll
    for (int ks = 0; ks < 2; ++ks) {
      s8v afrg[MI], bfrg[4];
#pragma unroll
      for (int i = 0; i < MI; ++i)
        afrg[i] = *(const s8v*)&lA[bs][ks][roff(wr * (MI * 16) + i * 16 + l15, l4)];
#pragma unroll
      for (int j = 0; j < 4; ++j)
        bfrg[j] = *(const s8v*)&lB[bs][ks][roff(wc * 64 + j * 16 + l15, l4)];
      asm volatile("s_waitcnt lgkmcnt(0)" ::: "memory");
      __builtin_amdgcn_sched_barrier(0);
      asm volatile("s_barrier" ::: "memory");
      if (pf) stage_part(t + 2, bs, ks);
      __builtin_amdgcn_s_setprio(1);
#pragma unroll
      for (int i = 0; i < MI; ++i)
#pragma unroll
        for (int j = 0; j < 4; ++j)
          acc[i][j] = __builtin_amdgcn_mfma_f32_16x16x32_bf16(afrg[i], bfrg[j], acc[i][j], 0, 0, 0);
      __builtin_amdgcn_s_setprio(0);
    }
  }

  const int colg = bn * 128 + wc * 64;
  u16* Ob = (colg < 512) ? Oa : Ob2;
  const int hh = (colg & 511) >> 7, d0 = colg & 127;
#pragma unroll
  for (int i = 0; i < MI; i++)
#pragma unroll
    for (int r = 0; r < 4; r++) {
      int m = m0 + wr * (MI * 16) + i * 16 + l4 * 4 + r;
      int b = m >> 11, l = m & 2047;
      size_t base = ((size_t)(b * 4 + hh) * 2048 + l) * 128 + d0;
#pragma unroll
      for (int j = 0; j < 4; j++)
        Ob[base + j * 16 + l15] = f2bf(acc[i][j][r]);
    }
}

// ---------------- RMSNorm + RoPE for K ONLY (q fused into attn) ----------------
__global__ __launch_bounds__(256) void norm_rope_k(u16* __restrict__ buf,
                                                   const float* __restrict__ tc,
                                                   const float* __restrict__ ts) {
  const int lane = threadIdx.x & 63;
  const int gw = blockIdx.x * 4 + (threadIdx.x >> 6);
  const int nw = gridDim.x * 4;
  for (int row = gw; row < 32768; row += nw) {
    int l = row & 2047;
    u16* p = buf + (size_t)row * 128;
    float x1 = bf2f(p[lane]);
    float x2 = bf2f(p[lane + 64]);
    float ss = x1 * x1 + x2 * x2;
#pragma unroll
    for (int off = 32; off > 0; off >>= 1) ss += __shfl_xor(ss, off, 64);
    float r = rsqrtf(ss * (1.0f / 128.0f) + 1.1920929e-07f);
    x1 *= r; x2 *= r;
    if (l >= 16) {
      int t = l - 16;
      float c = tc[t * 64 + lane], s = ts[t * 64 + lane];
      float o1 = x1 * c + x2 * s;
      float o2 = -x1 * s + x2 * c;
      x1 = o1; x2 = o2;
    }
    p[lane] = f2bf(x1);
    p[lane + 64] = f2bf(x2);
  }
}

// ---------------- V transpose: (bg,L,128) -> (bg,128,L), 64x64 LDS tiles, XOR swizzle
__global__ __launch_bounds__(256) void transpose_v(const u16* __restrict__ v,
                                                   u16* __restrict__ vt) {
  __shared__ u16 t[64][64];
  const int l0 = blockIdx.x * 64, d0 = blockIdx.y * 64, bg = blockIdx.z;
  const int tid = threadIdx.x;
#pragma unroll
  for (int it = 0; it < 2; ++it) {
    int lin = it * 256 + tid;
    int r = lin >> 3, cb = lin & 7;
    s8v val = *(const s8v*)&v[((bg * 2048 + l0 + r) * 128) + d0 + cb * 8];
    *(s8v*)&t[r][(cb ^ (r & 7)) * 8] = val;
  }
  __syncthreads();
#pragma unroll
  for (int it = 0; it < 2; ++it) {
    int lin = it * 256 + tid;
    int r2 = lin >> 3, c2 = (lin & 7) * 8;   // r2 = d idx, c2 = l idx
    s8v o;
#pragma unroll
    for (int j = 0; j < 8; ++j) {
      int rr = c2 + j, cc = r2;
      o[j] = (short)t[rr][(cc & 7) + 8 * ((cc >> 3) ^ (rr & 7))];
    }
    *(s8v*)&vt[((bg * 128 + d0 + r2) * 2048) + l0 + c2] = o;
  }
}

// ---------------- flash attention v3 + full-width LDS swizzle ----------------
// Identical structure to R12/R13; ONLY the LDS bank layout changed:
//  K: row kv (256B = 16 chunks); phys chunk = logical ^ (kv & 15)  [was &7]
//     -> read lanes l31 / l31+16 share a chunk value but differ in row: 2-way (free).
//  V: two d-rows packed per 256B line (line = d>>1; logical g = (d&1)*8 + kvchunk);
//     phys chunk = g ^ (line & 15) -> 32 lanes cover all 16 chunks twice: 2-way.
// Previous layout XOR'd only row&7 -> 4-way conflicts on EVERY ds_read_b128
// (SQ_LDS_BANK_CONFLICT stuck at 8.65M since R6). Rule #21 kept: linear dest,
// inverse-swizzled global source, matching swizzled read.
__global__ __launch_bounds__(512, 2) void attn(const u16* __restrict__ q,
                                               const u16* __restrict__ k,
                                               const u16* __restrict__ vt,
                                               u16* __restrict__ y,
                                               const float* __restrict__ qg,
                                               const float* __restrict__ tc,
                                               const float* __restrict__ ts) {
  __shared__ u16 lK[2][64 * 128];   // row kv: 16 chunks, phys = logical ^ (kv&15)
  __shared__ u16 lVT[2][64 * 128];  // line d>>1: 16 chunks, phys = ((d&1)*8+kc) ^ (line&15)
  const int tid = threadIdx.x;
  const int lane = tid & 63, wid = tid >> 6;
  const int l31 = lane & 31, hi = lane >> 5;

  const int bid = (int)blockIdx.x;                 // 0..255
  const int bg = (bid & 7) * 2 + (bid >> 7);       // XCD k hosts bg {2k,2k+1}
  const int pairi = (bid >> 3) & 15;               // 0..15
  const int b = bg >> 2, g = bg & 3;
  const int h = g * 4 + (wid & 3);
  const int se = wid >> 2;                         // row-half 0/1

  const u16* qh = q + (size_t)(b * 16 + h) * 2048 * 128;
  const u16* kb0 = k + (size_t)(b * 4 + g) * 2048 * 128;
  const u16* vtb0 = vt + (size_t)(b * 4 + g) * 128 * 2048;
  const float gscale = qg[h] * (0.08838834764831845f * 1.4426950408889634f);

  auto stage = [&](int t, int bufsel) {
    const int kv0 = t * 64;
#pragma unroll
    for (int it = 0; it < 2; ++it) {        // K tile 64x128 (16KB)
      int lin = it * 512 + tid;
      int kj = lin >> 4, s = lin & 15;
      gload_lds16(kb0 + (size_t)(kv0 + kj) * 128 + ((s ^ (kj & 15)) * 8),
                  &lK[bufsel][lin * 8]);
    }
#pragma unroll
    for (int it = 0; it < 2; ++it) {        // VT tile 128x64 (16KB), paired-d lines
      int lin = it * 512 + tid;
      int r = lin >> 4, c = lin & 15;
      int gl = c ^ (r & 15);
      int d = 2 * r + (gl >> 3);
      gload_lds16(vtb0 + (size_t)d * 2048 + kv0 + ((gl & 7) * 8),
                  &lVT[bufsel][lin * 8]);
    }
  };

  for (int ph = 0; ph < 2; ++ph) {
    const int qt = ph ? (31 - pairi) : pairi;
    const int q0 = qt * 64;
    const int nt = qt + 1;                  // KV tiles of 64
    const int pos = q0 + 32 * se + l31;

    // ---- fused Q: RMSNorm + RoPE + gain*(1/sqrt(128))*log2(e), pack B-frags ----
    s8v qf[8];
    {
      const u16* qp = qh + (size_t)pos * 128 + hi * 8;
      s8v qr[8];
#pragma unroll
      for (int ks = 0; ks < 8; ++ks) qr[ks] = *(const s8v*)&qp[ks * 16];
      float ssum = 0.f;
#pragma unroll
      for (int ks = 0; ks < 8; ++ks)
#pragma unroll
        for (int j = 0; j < 8; ++j) {
          float v = bf2f((u16)qr[ks][j]);
          ssum += v * v;
        }
      ssum += __shfl_xor(ssum, 32, 64);
      const float rn = rsqrtf(ssum * (1.0f / 128.0f) + 1.1920929e-07f) * gscale;
      const bool rot = (pos >= 16);
      const int tt = pos - 16;
#pragma unroll
      for (int ks = 0; ks < 4; ++ks) {
        float cv[8], sv[8];
        if (rot) {
          const float* cp = &tc[tt * 64 + ks * 16 + hi * 8];
          const float* sp = &ts[tt * 64 + ks * 16 + hi * 8];
          *(float4*)&cv[0] = *(const float4*)cp;
          *(float4*)&cv[4] = *(const float4*)(cp + 4);
          *(float4*)&sv[0] = *(const float4*)sp;
          *(float4*)&sv[4] = *(const float4*)(sp + 4);
        }
        uint32_t wlo[4], whi[4];
#pragma unroll
        for (int j2 = 0; j2 < 4; ++j2) {
          float o1[2], o2[2];
#pragma unroll
          for (int e = 0; e < 2; ++e) {
            const int j = j2 * 2 + e;
            float x1 = bf2f((u16)qr[ks][j]);
            float x2 = bf2f((u16)qr[ks + 4][j]);
            float a = x1, bb = x2;
            if (rot) { a = x1 * cv[j] + x2 * sv[j]; bb = x2 * cv[j] - x1 * sv[j]; }
            o1[e] = a * rn;
            o2[e] = bb * rn;
          }
          asm("v_cvt_pk_bf16_f32 %0, %1, %2" : "=v"(wlo[j2]) : "v"(o1[0]), "v"(o1[1]));
          asm("v_cvt_pk_bf16_f32 %0, %1, %2" : "=v"(whi[j2]) : "v"(o2[0]), "v"(o2[1]));
        }
        union { uint32_t u[4]; s8v v; } ua, ub;
        ua.u[0] = wlo[0]; ua.u[1] = wlo[1]; ua.u[2] = wlo[2]; ua.u[3] = wlo[3];
        ub.u[0] = whi[0]; ub.u[1] = whi[1]; ub.u[2] = whi[2]; ub.u[3] = whi[3];
        qf[ks] = ua.v;
        qf[ks + 4] = ub.v;
      }
    }

    f16v yacc[4];
#pragma unroll
    for (int j = 0; j < 4; ++j)
#pragma unroll
      for (int r = 0; r < 16; ++r) yacc[j][r] = 0.f;
    float mrow = -1e30f, lrow = 0.f;

    stage(0, 0);
    __syncthreads();

    for (int t = 0; t < nt; ++t) {
      const int cur = t & 1;
      if (t + 1 < nt) stage(t + 1, cur ^ 1);
      const int kv0 = t * 64;

      // ---- QK^T swapped: S^T[kv][q] in exp2 domain, two 32-kv chunks ----
      f16v s0a, s1a;
#pragma unroll
      for (int r = 0; r < 16; ++r) { s0a[r] = 0.f; s1a[r] = 0.f; }
      __builtin_amdgcn_s_setprio(1);
#pragma unroll
      for (int ks = 0; ks < 8; ++ks) {
        const int slot = (2 * ks + hi) ^ (l31 & 15);
        s8v kf0 = *(const s8v*)&lK[cur][(l31)*128 + slot * 8];
        s8v kf1 = *(const s8v*)&lK[cur][(32 + l31) * 128 + slot * 8];
        s0a = __builtin_amdgcn_mfma_f32_32x32x16_bf16(kf0, qf[ks], s0a, 0, 0, 0);
        s1a = __builtin_amdgcn_mfma_f32_32x32x16_bf16(kf1, qf[ks], s1a, 0, 0, 0);
      }
      __builtin_amdgcn_s_setprio(0);

      // ---- causal mask + row max (in-register; scores already log2-scaled) ----
      const bool last = (t == nt - 1);
      float p0[16], p1[16];
      float pmax = -1e30f;
#pragma unroll
      for (int r = 0; r < 16; ++r) {
        const int kvloc = (r & 3) + 8 * (r >> 2) + 4 * hi;
        float v0 = s0a[r];
        float v1 = s1a[r];
        if (last) {
          if (kv0 + kvloc > pos) v0 = -1e30f;
          if (kv0 + 32 + kvloc > pos) v1 = -1e30f;
        }
        p0[r] = v0; p1[r] = v1;
        pmax = fmaxf(pmax, fmaxf(v0, v1));
      }
      pmax = fmaxf(pmax, __shfl_xor(pmax, 32, 64));

      // ---- defer-max (T13): THR = 8*log2e in exp2 domain ----
      if (!__all(pmax - mrow <= 11.541560327111707f)) {
        float mnew = fmaxf(mrow, pmax);
        float corr = __builtin_amdgcn_exp2f(mrow - mnew);
#pragma unroll
        for (int r = 0; r < 16; ++r) {
          const int qloc = (r & 3) + 8 * (r >> 2) + 4 * hi;
          float cb = __shfl(corr, qloc, 64);
          yacc[0][r] *= cb; yacc[1][r] *= cb; yacc[2][r] *= cb; yacc[3][r] *= cb;
        }
        lrow *= corr;
        mrow = mnew;
      }

      // ---- exp2 + fp32 row sum (denominator unrounded) ----
      float ps = 0.f;
#pragma unroll
      for (int r = 0; r < 16; ++r) {
        float e0 = __builtin_amdgcn_exp2f(p0[r] - mrow);
        float e1 = __builtin_amdgcn_exp2f(p1[r] - mrow);
        p0[r] = e0; p1[r] = e1;
        ps += e0 + e1;
      }
      ps += __shfl_xor(ps, 32, 64);
      lrow += ps;

      // ---- PV: cvt_pk pack + permlane32_swap exchange + MFMA ----
      __builtin_amdgcn_s_setprio(1);
#pragma unroll
      for (int ks = 0; ks < 4; ++ks) {
        const float* pc = (ks < 2) ? p0 : p1;
        const int rb = 8 * (ks & 1);
        uint32_t A0, A1, B0, B1;
        asm("v_cvt_pk_bf16_f32 %0, %1, %2" : "=v"(A0) : "v"(pc[rb + 0]), "v"(pc[rb + 1]));
        asm("v_cvt_pk_bf16_f32 %0, %1, %2" : "=v"(A1) : "v"(pc[rb + 2]), "v"(pc[rb + 3]));
        asm("v_cvt_pk_bf16_f32 %0, %1, %2" : "=v"(B0) : "v"(pc[rb + 4]), "v"(pc[rb + 5]));
        asm("v_cvt_pk_bf16_f32 %0, %1, %2" : "=v"(B1) : "v"(pc[rb + 6]), "v"(pc[rb + 7]));
        // after swap: A0 = [A0_lo|B0_lo] = uu0, B0 = [A0_hi|B0_hi] = uu2 (ditto A1/B1)
        asm("v_permlane32_swap_b32 %0, %1" : "+v"(A0), "+v"(B0));
        asm("v_permlane32_swap_b32 %0, %1" : "+v"(A1), "+v"(B1));
        union { uint32_t u[4]; s8v v; } uu;
        uu.u[0] = A0; uu.u[1] = A1; uu.u[2] = B0; uu.u[3] = B1;
#pragma unroll
        for (int jd = 0; jd < 4; ++jd) {
          const int rowd = 32 * jd + l31;
          const int line = rowd >> 1;
          const int gl = ((rowd & 1) << 3) | (2 * ks + hi);
          const int c = gl ^ (line & 15);
          s8v vf = *(const s8v*)&lVT[cur][line * 128 + c * 8];
          yacc[jd] = __builtin_amdgcn_mfma_f32_32x32x16_bf16(uu.v, vf, yacc[jd], 0, 0, 0);
        }
      }
      __builtin_amdgcn_s_setprio(0);
      __syncthreads();
    }

    // ---- finalize: broadcast 1/l per C-row, write y (B,L,H*128) bf16 ----
    float inv = 1.0f / lrow;
#pragma unroll
    for (int r = 0; r < 16; ++r) {
      const int qloc = (r & 3) + 8 * (r >> 2) + 4 * hi;
      float ib = __shfl(inv, qloc, 64);
      const int qrow = q0 + 32 * se + qloc;
      size_t base = ((size_t)(b * 2048 + qrow)) * 2048 + h * 128 + l31;
#pragma unroll
      for (int jd = 0; jd < 4; ++jd)
        y[base + 32 * jd] = f2bf(yacc[jd][r] * ib);
    }
  }
}

extern "C" void kernel_launch(void* const* d_in, const int* in_sizes, int n_in,
                              void* d_out, int out_size, void* d_ws, size_t ws_size,
                              hipStream_t stream) {
  const float* x  = (const float*)d_in[0];
  const float* Wq = (const float*)d_in[1];
  const float* Wk = (const float*)d_in[2];
  const float* Wv = (const float*)d_in[3];
  const float* Wp = (const float*)d_in[4];
  const float* qg = (const float*)d_in[5];
  float* out = (float*)d_out;

  char* ws = (char*)d_ws;
  size_t off = 0;
  auto alloc = [&](size_t bytes) {
    void* p = ws + off;
    off += (bytes + 255) & ~(size_t)255;
    return p;
  };
  u16* x_bf  = (u16*)alloc((size_t)8192 * 2048 * 2);   // also reused as y_bf
  u16* wq_bf = (u16*)alloc((size_t)2048 * 2048 * 2);   // also reused as vt_bf
  u16* wk_bf = (u16*)alloc((size_t)512 * 2048 * 2);    // wk|wv contiguous = KV weight
  u16* wv_bf = (u16*)alloc((size_t)512 * 2048 * 2);
  u16* wp_bf = (u16*)alloc((size_t)2048 * 2048 * 2);
  u16* q_bf  = (u16*)alloc((size_t)4 * 16 * 2048 * 128 * 2);
  u16* k_bf  = (u16*)alloc((size_t)4 * 4 * 2048 * 128 * 2);
  u16* v_bf  = (u16*)alloc((size_t)4 * 4 * 2048 * 128 * 2);
  float* tab = (float*)alloc((size_t)2032 * 64 * 2 * 4);
  u16* y_bf  = x_bf;    // x dead after QKV GEMMs
  u16* vt_bf = wq_bf;   // Wq dead after Q GEMM (same size)

  cvt_bf16<<<2048, 256, 0, stream>>>((const float4*)x, (uint2*)x_bf, 8192 * 2048 / 4);
  cvt_bf16_w<<<1024, 256, 0, stream>>>((const float4*)Wq, (const float4*)Wk,
                                       (const float4*)Wv, (const float4*)Wp,
                                       (uint2*)wq_bf);   // wq|wk|wv|wp contiguous
  rope_table<<<(2032 * 64 + 255) / 256, 256, 0, stream>>>(tab, tab + 2032 * 64);

  gemm8<0><<<dim3(256), 512, 0, stream>>>(x_bf, wq_bf, q_bf, nullptr);
  gemm_kv<<<dim3(256), 512, 0, stream>>>(x_bf, wk_bf, k_bf, v_bf);
  norm_rope_k<<<256, 256, 0, stream>>>(k_bf, tab, tab + 2032 * 64);
  transpose_v<<<dim3(32, 2, 16), 256, 0, stream>>>(v_bf, vt_bf);
  attn<<<dim3(256), 512, 0, stream>>>(q_bf, k_bf, vt_bf, y_bf, qg,
                                      tab, tab + 2032 * 64);
  gemm8<2><<<dim3(256), 512, 0, stream>>>(y_bf, wp_bf, nullptr, out);
}

// Round 15
// 332.561 us; speedup vs baseline: 1.1258x; 1.0021x over previous
//
#include <hip/hip_runtime.h>
#include <stdint.h>

// Shapes (fixed): B=4 L=2048 D=2048 H=16 KVH=4 HD=128 M=16 T=2032
typedef unsigned short u16;
typedef short s8v __attribute__((ext_vector_type(8)));   // 8 bf16 (4 VGPR) MFMA frag
typedef float f4v __attribute__((ext_vector_type(4)));   // 16x16 MFMA accum
typedef float f16v __attribute__((ext_vector_type(16))); // 32x32 MFMA accum

typedef __attribute__((address_space(1))) char gchar;
typedef __attribute__((address_space(3))) char lchar;

static __device__ __forceinline__ u16 f2bf(float f) {
  uint32_t x = __float_as_uint(f);
  x += 0x7fffu + ((x >> 16) & 1u);            // RNE
  return (u16)(x >> 16);
}
static __device__ __forceinline__ float bf2f(u16 u) {
  return __uint_as_float(((uint32_t)u) << 16);
}
// async global->LDS, 16B per lane. LDS dest must be wave-linear (base + lane*16).
static __device__ __forceinline__ void gload_lds16(const void* g, void* l) {
  __builtin_amdgcn_global_load_lds((gchar*)(uintptr_t)g,
                                   (lchar*)(uint32_t)(uintptr_t)l, 16, 0, 0);
}

// ---------------- prep: x->bf16, weights->bf16, rope table (one launch) ----------------
__global__ __launch_bounds__(256) void prep(const float4* __restrict__ x,
                                            const float4* __restrict__ wq,
                                            const float4* __restrict__ wk,
                                            const float4* __restrict__ wv,
                                            const float4* __restrict__ wp,
                                            uint2* __restrict__ xbf,
                                            uint2* __restrict__ wbf,
                                            float* __restrict__ tc,
                                            float* __restrict__ ts) {
  const int gid = blockIdx.x * 256 + threadIdx.x;
  const int st = gridDim.x * 256;
  for (int i = gid; i < 4194304; i += st) {            // x: 8192x2048 fp32
    float4 v = x[i];
    uint2 o;
    o.x = (uint32_t)f2bf(v.x) | ((uint32_t)f2bf(v.y) << 16);
    o.y = (uint32_t)f2bf(v.z) | ((uint32_t)f2bf(v.w) << 16);
    xbf[i] = o;
  }
  for (int i = gid; i < 2621440; i += st) {            // wq|wk|wv|wp contiguous dst
    const float4* s;
    int off;
    if (i < 1048576)      { s = wq; off = i; }
    else if (i < 1310720) { s = wk; off = i - 1048576; }
    else if (i < 1572864) { s = wv; off = i - 1310720; }
    else                  { s = wp; off = i - 1572864; }
    float4 v = s[off];
    uint2 o;
    o.x = (uint32_t)f2bf(v.x) | ((uint32_t)f2bf(v.y) << 16);
    o.y = (uint32_t)f2bf(v.z) | ((uint32_t)f2bf(v.w) << 16);
    wbf[i] = o;
  }
  for (int i = gid; i < 2032 * 64; i += st) {          // rope table [T][64]
    int t = i >> 6, f = i & 63;
    float invf = 1.0f / powf(10000.0f, (float)f * (1.0f / 64.0f));
    float ang = (float)t * invf;
    float s, c;
    sincosf(ang, &s, &c);
    tc[i] = c;
    ts[i] = s;
  }
}

// ---------------- gemm8 body: 256x256 8-phase (R13 structure, smem-arena form) ----------------
// smem layout (u16 idx): A region (bs,mh) at (bs*2+mh)*8192 ; B region (bs,nh) at 32768+(bs*2+nh)*8192
template <int OUT>
static __device__ __forceinline__ void gemm8_body(
    u16* sm, int bid, const u16* __restrict__ A, const u16* __restrict__ Wt,
    u16* __restrict__ Oa, float* __restrict__ OF) {
  const int tid = threadIdx.x;
  const int lane = tid & 63, wid = tid >> 6;
  const int wr = wid >> 2, wc = wid & 3;
  const int l15 = lane & 15, l4 = lane >> 4;

  const int swz = (bid & 7) * 32 + (bid >> 3);   // XCD chunk (256-block path)
  const int bn = swz >> 5, bm = swz & 31;        // col-major: 1 B-panel per XCD
  const int m0 = bm * 256;
  const int n0r = bn * 256;

  auto pA = [&](int bs, int mh) { return sm + (bs * 2 + mh) * 8192; };
  auto pB = [&](int bs, int nh) { return sm + 32768 + (bs * 2 + nh) * 8192; };

  auto stageA = [&](int kt, int bs, int mh) {
    const int kb = kt * 64;
#pragma unroll
    for (int c = 0; c < 2; ++c) {
      int cidx = tid + c * 512;
      int rr = cidx >> 3, pc = cidx & 7;
      int grow = mh * 64 + (rr & 63) + ((rr >> 6) << 7);
      int kc = pc ^ (rr & 7);
      gload_lds16(A + (size_t)(m0 + grow) * 2048 + kb + kc * 8,
                  pA(bs, mh) + cidx * 8);
    }
  };
  auto stageB = [&](int kt, int bs, int nh) {
    const int kb = kt * 64;
#pragma unroll
    for (int c = 0; c < 2; ++c) {
      int cidx = tid + c * 512;
      int rr = cidx >> 3, pc = cidx & 7;
      int gn = ((rr >> 5) << 6) + nh * 32 + (rr & 31);
      int kc = pc ^ (rr & 7);
      gload_lds16(Wt + (size_t)(n0r + gn) * 2048 + kb + kc * 8,
                  pB(bs, nh) + cidx * 8);
    }
  };
  auto readA = [&](int bs, int mh, int i, int ks) {
    int rr = wr * 64 + i * 16 + l15;
    return *(const s8v*)&pA(bs, mh)[rr * 64 + (((ks * 4 + l4) ^ (rr & 7)) << 3)];
  };
  auto readB = [&](int bs, int nh, int j, int ks) {
    int rr = wc * 32 + j * 16 + l15;
    return *(const s8v*)&pB(bs, nh)[rr * 64 + (((ks * 4 + l4) ^ (rr & 7)) << 3)];
  };

  const f4v Z4 = {0.f, 0.f, 0.f, 0.f};
  f4v acc[8][4];                 // [mh*4+i][nh*2+j]
#pragma unroll
  for (int i = 0; i < 8; i++)
#pragma unroll
    for (int j = 0; j < 4; j++) acc[i][j] = Z4;

  stageA(0, 0, 0); stageA(0, 0, 1); stageB(0, 0, 0); stageB(0, 0, 1);
  stageA(1, 1, 0); stageA(1, 1, 1); stageB(1, 1, 0);
  asm volatile("s_waitcnt vmcnt(6)" ::: "memory");   // tile0 certified
  asm volatile("s_barrier" ::: "memory");

  const int NT = 32;
  for (int t = 0; t < NT; ++t) {
    const int bs = t & 1, nbs = bs ^ 1;
    s8v a[4][2], b[2][2];
    // phase 0: (mh0, nh0)
#pragma unroll
    for (int i = 0; i < 4; ++i)
#pragma unroll
      for (int ks = 0; ks < 2; ++ks) a[i][ks] = readA(bs, 0, i, ks);
#pragma unroll
    for (int j = 0; j < 2; ++j)
#pragma unroll
      for (int ks = 0; ks < 2; ++ks) b[j][ks] = readB(bs, 0, j, ks);
    if (t + 1 < NT) stageB(t + 1, nbs, 1);
    asm volatile("s_barrier" ::: "memory");
    asm volatile("s_waitcnt lgkmcnt(0)" ::: "memory");
    __builtin_amdgcn_sched_barrier(0);
    __builtin_amdgcn_s_setprio(1);
#pragma unroll
    for (int i = 0; i < 4; ++i)
#pragma unroll
      for (int j = 0; j < 2; ++j)
#pragma unroll
        for (int ks = 0; ks < 2; ++ks)
          acc[i][j] = __builtin_amdgcn_mfma_f32_16x16x32_bf16(a[i][ks], b[j][ks], acc[i][j], 0, 0, 0);
    __builtin_amdgcn_s_setprio(0);
    asm volatile("s_barrier" ::: "memory");
    // phase 1: (mh0, nh1)
#pragma unroll
    for (int j = 0; j < 2; ++j)
#pragma unroll
      for (int ks = 0; ks < 2; ++ks) b[j][ks] = readB(bs, 1, j, ks);
    if (t + 2 < NT) stageA(t + 2, bs, 0);
    asm volatile("s_barrier" ::: "memory");
    asm volatile("s_waitcnt lgkmcnt(0)" ::: "memory");
    __builtin_amdgcn_sched_barrier(0);
    __builtin_amdgcn_s_setprio(1);
#pragma unroll
    for (int i = 0; i < 4; ++i)
#pragma unroll
      for (int j = 0; j < 2; ++j)
#pragma unroll
        for (int ks = 0; ks < 2; ++ks)
          acc[i][2 + j] = __builtin_amdgcn_mfma_f32_16x16x32_bf16(a[i][ks], b[j][ks], acc[i][2 + j], 0, 0, 0);
    __builtin_amdgcn_s_setprio(0);
    asm volatile("s_barrier" ::: "memory");
    // phase 2: (mh1, nh0)
#pragma unroll
    for (int i = 0; i < 4; ++i)
#pragma unroll
      for (int ks = 0; ks < 2; ++ks) a[i][ks] = readA(bs, 1, i, ks);
#pragma unroll
    for (int j = 0; j < 2; ++j)
#pragma unroll
      for (int ks = 0; ks < 2; ++ks) b[j][ks] = readB(bs, 0, j, ks);
    asm volatile("s_barrier" ::: "memory");
    asm volatile("s_waitcnt lgkmcnt(0)" ::: "memory");
    __builtin_amdgcn_sched_barrier(0);
    __builtin_amdgcn_s_setprio(1);
#pragma unroll
    for (int i = 0; i < 4; ++i)
#pragma unroll
      for (int j = 0; j < 2; ++j)
#pragma unroll
        for (int ks = 0; ks < 2; ++ks)
          acc[4 + i][j] = __builtin_amdgcn_mfma_f32_16x16x32_bf16(a[i][ks], b[j][ks], acc[4 + i][j], 0, 0, 0);
    __builtin_amdgcn_s_setprio(0);
    asm volatile("s_barrier" ::: "memory");
    // phase 3: (mh1, nh1)
#pragma unroll
    for (int j = 0; j < 2; ++j)
#pragma unroll
      for (int ks = 0; ks < 2; ++ks) b[j][ks] = readB(bs, 1, j, ks);
    if (t + 2 < NT) { stageA(t + 2, bs, 1); stageB(t + 2, bs, 0); }
    asm volatile("s_barrier" ::: "memory");
    asm volatile("s_waitcnt lgkmcnt(0)" ::: "memory");
    __builtin_amdgcn_sched_barrier(0);
    __builtin_amdgcn_s_setprio(1);
#pragma unroll
    for (int i = 0; i < 4; ++i)
#pragma unroll
      for (int j = 0; j < 2; ++j)
#pragma unroll
        for (int ks = 0; ks < 2; ++ks)
          acc[4 + i][2 + j] = __builtin_amdgcn_mfma_f32_16x16x32_bf16(a[i][ks], b[j][ks], acc[4 + i][2 + j], 0, 0, 0);
    __builtin_amdgcn_s_setprio(0);
    if (t + 2 < NT)      asm volatile("s_waitcnt vmcnt(6)" ::: "memory");
    else if (t + 1 < NT) asm volatile("s_waitcnt vmcnt(0)" ::: "memory");
    asm volatile("s_barrier" ::: "memory");      // RAW gate: tile t+1 certified
  }

  const int colg0 = bn * 256 + wc * 64;
  if constexpr (OUT == 0) {                      // Q: (B,16,L,128) bf16
    const int hh = colg0 >> 7, d0 = colg0 & 127;
#pragma unroll
    for (int i = 0; i < 8; i++)
#pragma unroll
      for (int r = 0; r < 4; r++) {
        int m = m0 + wr * 128 + (i >> 2) * 64 + (i & 3) * 16 + l4 * 4 + r;
        int b2 = m >> 11, l = m & 2047;
        size_t base = ((size_t)(b2 * 16 + hh) * 2048 + l) * 128 + d0;
#pragma unroll
        for (int j = 0; j < 4; j++)
          Oa[base + (j >> 1) * 32 + (j & 1) * 16 + l15] = f2bf(acc[i][j][r]);
      }
  } else {                                       // proj: fp32 row-major
#pragma unroll
    for (int i = 0; i < 8; i++)
#pragma unroll
      for (int r = 0; r < 4; r++) {
        int m = m0 + wr * 128 + (i >> 2) * 64 + (i & 3) * 16 + l4 * 4 + r;
#pragma unroll
        for (int j = 0; j < 4; j++)
          OF[(size_t)m * 2048 + colg0 + (j >> 1) * 32 + (j & 1) * 16 + l15] = acc[i][j][r];
      }
  }
}

// ---------------- gemm_kv body: 256x128 region structure (R10, smem-arena form) ----------------
// smem: A region (bs,ks) at (bs*2+ks)*8192 ; B region (bs,ks) at 32768+(bs*2+ks)*4096
static __device__ __forceinline__ void gemm_kv_body(
    u16* sm, int bid, const u16* __restrict__ A, const u16* __restrict__ Wt,
    u16* __restrict__ Oa, u16* __restrict__ Ob2) {
  constexpr int MI = 4;
  const int tid = threadIdx.x;
  const int lane = tid & 63, wid = tid >> 6;
  const int wr = wid >> 1, wc = wid & 1;
  const int l15 = lane & 15, l4 = lane >> 4;

  const int swz = (bid & 7) * 32 + (bid >> 3);
  const int bn = swz >> 5, bm = swz & 31;
  const int m0 = bm * 256;
  const int n0r = bn * 128;

  auto pA = [&](int bs, int ks) { return sm + (bs * 2 + ks) * 8192; };
  auto pB = [&](int bs, int ks) { return sm + 32768 + (bs * 2 + ks) * 4096; };

  auto stage_part = [&](int kt, int bs, int ks) {
    const int kb = kt * 64 + ks * 32;
#pragma unroll
    for (int c = 0; c < 2; ++c) {
      int cidx = tid + c * 512;
      int r = cidx >> 2, q = cidx & 3;
      int cc = q ^ ((r >> 2) & 3);
      gload_lds16(A + (size_t)(m0 + r) * 2048 + kb + cc * 8,
                  pA(bs, ks) + cidx * 8);
    }
    {
      int cidx = tid;
      int r = cidx >> 2, q = cidx & 3;
      int cc = q ^ ((r >> 2) & 3);
      gload_lds16(Wt + (size_t)(n0r + r) * 2048 + kb + cc * 8,
                  pB(bs, ks) + cidx * 8);
    }
  };
  auto roff = [&](int fr, int c) {
    return (fr * 4 + (c ^ ((fr >> 2) & 3))) * 8;
  };

  const f4v Z4 = {0.f, 0.f, 0.f, 0.f};
  f4v acc[MI][4];
#pragma unroll
  for (int i = 0; i < MI; i++)
#pragma unroll
    for (int j = 0; j < 4; j++) acc[i][j] = Z4;

  stage_part(0, 0, 0); stage_part(0, 0, 1);
  stage_part(1, 1, 0); stage_part(1, 1, 1);

  const int NT = 32;
  for (int t = 0; t < NT; ++t) {
    const int bs = t & 1;
    if (t + 1 < NT) asm volatile("s_waitcnt vmcnt(6)" ::: "memory");
    else            asm volatile("s_waitcnt vmcnt(0)" ::: "memory");
    asm volatile("s_barrier" ::: "memory");
    const bool pf = (t + 2 < NT);
#pragma unroll
    for (int ks = 0; ks < 2; ++ks) {
      s8v afrg[MI], bfrg[4];
#pragma unroll
      for (int i = 0; i < MI; ++i)
        afrg[i] = *(const s8v*)&pA(bs, ks)[roff(wr * (MI * 16) + i * 16 + l15, l4)];
#pragma unroll
      for (int j = 0; j < 4; ++j)
        bfrg[j] = *(const s8v*)&pB(bs, ks)[roff(wc * 64 + j * 16 + l15, l4)];
      asm volatile("s_waitcnt lgkmcnt(0)" ::: "memory");
      __builtin_amdgcn_sched_barrier(0);
      asm volatile("s_barrier" ::: "memory");
      if (pf) stage_part(t + 2, bs, ks);
      __builtin_amdgcn_s_setprio(1);
#pragma unroll
      for (int i = 0; i < MI; ++i)
#pragma unroll
        for (int j = 0; j < 4; ++j)
          acc[i][j] = __builtin_amdgcn_mfma_f32_16x16x32_bf16(afrg[i], bfrg[j], acc[i][j], 0, 0, 0);
      __builtin_amdgcn_s_setprio(0);
    }
  }

  const int colg = bn * 128 + wc * 64;
  u16* Ob = (colg < 512) ? Oa : Ob2;
  const int hh = (colg & 511) >> 7, d0 = colg & 127;
#pragma unroll
  for (int i = 0; i < MI; i++)
#pragma unroll
    for (int r = 0; r < 4; r++) {
      int m = m0 + wr * (MI * 16) + i * 16 + l4 * 4 + r;
      int b = m >> 11, l = m & 2047;
      size_t base = ((size_t)(b * 4 + hh) * 2048 + l) * 128 + d0;
#pragma unroll
      for (int j = 0; j < 4; j++)
        Ob[base + j * 16 + l15] = f2bf(acc[i][j][r]);
    }
}

// ---------------- merged QKV GEMM: 512 blocks = 256 Q-path + 256 KV-path ----------------
__global__ __launch_bounds__(512, 2) void gemm_qkv(
    const u16* __restrict__ x, const u16* __restrict__ wq,
    const u16* __restrict__ wkv, u16* __restrict__ q,
    u16* __restrict__ kO, u16* __restrict__ vO) {
  __shared__ u16 smem[65536];                    // 128KB arena (both paths fit)
  const int bid = (int)blockIdx.x;
  if (bid < 256) gemm8_body<0>(smem, bid, x, wq, q, nullptr);
  else           gemm_kv_body(smem, bid - 256, x, wkv, kO, vO);
}

// ---------------- proj GEMM (gemm8 path, own launch) ----------------
__global__ __launch_bounds__(512, 2) void gemm_proj(
    const u16* __restrict__ y, const u16* __restrict__ wp, float* __restrict__ out) {
  __shared__ u16 smem[65536];
  gemm8_body<2>(smem, (int)blockIdx.x, y, wp, nullptr, out);
}

// ---------------- merged K-norm + V-transpose (1280 blocks) ----------------
// bid < 1024: transpose_v tile (l0=(bid&31)*64, d0=((bid>>5)&1)*64, bg=bid>>6)
// bid >= 1024: norm_rope_k rows, 256 blocks x 4 waves, stride 1024 waves
__global__ __launch_bounds__(256) void norm_transpose(
    u16* __restrict__ kbuf, const u16* __restrict__ v, u16* __restrict__ vt,
    const float* __restrict__ tc, const float* __restrict__ ts) {
  __shared__ u16 t[64][64];
  const int bid = (int)blockIdx.x;
  const int tid = threadIdx.x;
  if (bid < 1024) {
    const int l0 = (bid & 31) * 64, d0 = ((bid >> 5) & 1) * 64, bg = bid >> 6;
#pragma unroll
    for (int it = 0; it < 2; ++it) {
      int lin = it * 256 + tid;
      int r = lin >> 3, cb = lin & 7;
      s8v val = *(const s8v*)&v[((bg * 2048 + l0 + r) * 128) + d0 + cb * 8];
      *(s8v*)&t[r][(cb ^ (r & 7)) * 8] = val;
    }
    __syncthreads();
#pragma unroll
    for (int it = 0; it < 2; ++it) {
      int lin = it * 256 + tid;
      int r2 = lin >> 3, c2 = (lin & 7) * 8;
      s8v o;
#pragma unroll
      for (int j = 0; j < 8; ++j) {
        int rr = c2 + j, cc = r2;
        o[j] = (short)t[rr][(cc & 7) + 8 * ((cc >> 3) ^ (rr & 7))];
      }
      *(s8v*)&vt[((bg * 128 + d0 + r2) * 2048) + l0 + c2] = o;
    }
  } else {
    const int lane = tid & 63;
    const int gw = (bid - 1024) * 4 + (tid >> 6);
    for (int row = gw; row < 32768; row += 1024) {
      int l = row & 2047;
      u16* p = kbuf + (size_t)row * 128;
      float x1 = bf2f(p[lane]);
      float x2 = bf2f(p[lane + 64]);
      float ss = x1 * x1 + x2 * x2;
#pragma unroll
      for (int off = 32; off > 0; off >>= 1) ss += __shfl_xor(ss, off, 64);
      float r = rsqrtf(ss * (1.0f / 128.0f) + 1.1920929e-07f);
      x1 *= r; x2 *= r;
      if (l >= 16) {
        int tt = l - 16;
        float c = tc[tt * 64 + lane], s = ts[tt * 64 + lane];
        float o1 = x1 * c + x2 * s;
        float o2 = -x1 * s + x2 * c;
        x1 = o1; x2 = o2;
      }
      p[lane] = f2bf(x1);
      p[lane + 64] = f2bf(x2);
    }
  }
}

// ---------------- flash attention v3 + full-width LDS swizzle (unchanged R14) ----------------
__global__ __launch_bounds__(512, 2) void attn(const u16* __restrict__ q,
                                               const u16* __restrict__ k,
                                               const u16* __restrict__ vt,
                                               u16* __restrict__ y,
                                               const float* __restrict__ qg,
                                               const float* __restrict__ tc,
                                               const float* __restrict__ ts) {
  __shared__ u16 lK[2][64 * 128];   // row kv: 16 chunks, phys = logical ^ (kv&15)
  __shared__ u16 lVT[2][64 * 128];  // line d>>1: 16 chunks, phys = ((d&1)*8+kc) ^ (line&15)
  const int tid = threadIdx.x;
  const int lane = tid & 63, wid = tid >> 6;
  const int l31 = lane & 31, hi = lane >> 5;

  const int bid = (int)blockIdx.x;                 // 0..255
  const int bg = (bid & 7) * 2 + (bid >> 7);       // XCD k hosts bg {2k,2k+1}
  const int pairi = (bid >> 3) & 15;               // 0..15
  const int b = bg >> 2, g = bg & 3;
  const int h = g * 4 + (wid & 3);
  const int se = wid >> 2;                         // row-half 0/1

  const u16* qh = q + (size_t)(b * 16 + h) * 2048 * 128;
  const u16* kb0 = k + (size_t)(b * 4 + g) * 2048 * 128;
  const u16* vtb0 = vt + (size_t)(b * 4 + g) * 128 * 2048;
  const float gscale = qg[h] * (0.08838834764831845f * 1.4426950408889634f);

  auto stage = [&](int t, int bufsel) {
    const int kv0 = t * 64;
#pragma unroll
    for (int it = 0; it < 2; ++it) {        // K tile 64x128 (16KB)
      int lin = it * 512 + tid;
      int kj = lin >> 4, s = lin & 15;
      gload_lds16(kb0 + (size_t)(kv0 + kj) * 128 + ((s ^ (kj & 15)) * 8),
                  &lK[bufsel][lin * 8]);
    }
#pragma unroll
    for (int it = 0; it < 2; ++it) {        // VT tile 128x64 (16KB), paired-d lines
      int lin = it * 512 + tid;
      int r = lin >> 4, c = lin & 15;
      int gl = c ^ (r & 15);
      int d = 2 * r + (gl >> 3);
      gload_lds16(vtb0 + (size_t)d * 2048 + kv0 + ((gl & 7) * 8),
                  &lVT[bufsel][lin * 8]);
    }
  };

  for (int ph = 0; ph < 2; ++ph) {
    const int qt = ph ? (31 - pairi) : pairi;
    const int q0 = qt * 64;
    const int nt = qt + 1;                  // KV tiles of 64
    const int pos = q0 + 32 * se + l31;

    // ---- fused Q: RMSNorm + RoPE + gain*(1/sqrt(128))*log2(e), pack B-frags ----
    s8v qf[8];
    {
      const u16* qp = qh + (size_t)pos * 128 + hi * 8;
      s8v qr[8];
#pragma unroll
      for (int ks = 0; ks < 8; ++ks) qr[ks] = *(const s8v*)&qp[ks * 16];
      float ssum = 0.f;
#pragma unroll
      for (int ks = 0; ks < 8; ++ks)
#pragma unroll
        for (int j = 0; j < 8; ++j) {
          float v = bf2f((u16)qr[ks][j]);
          ssum += v * v;
        }
      ssum += __shfl_xor(ssum, 32, 64);
      const float rn = rsqrtf(ssum * (1.0f / 128.0f) + 1.1920929e-07f) * gscale;
      const bool rot = (pos >= 16);
      const int tt = pos - 16;
#pragma unroll
      for (int ks = 0; ks < 4; ++ks) {
        float cv[8], sv[8];
        if (rot) {
          const float* cp = &tc[tt * 64 + ks * 16 + hi * 8];
          const float* sp = &ts[tt * 64 + ks * 16 + hi * 8];
          *(float4*)&cv[0] = *(const float4*)cp;
          *(float4*)&cv[4] = *(const float4*)(cp + 4);
          *(float4*)&sv[0] = *(const float4*)sp;
          *(float4*)&sv[4] = *(const float4*)(sp + 4);
        }
        uint32_t wlo[4], whi[4];
#pragma unroll
        for (int j2 = 0; j2 < 4; ++j2) {
          float o1[2], o2[2];
#pragma unroll
          for (int e = 0; e < 2; ++e) {
            const int j = j2 * 2 + e;
            float x1 = bf2f((u16)qr[ks][j]);
            float x2 = bf2f((u16)qr[ks + 4][j]);
            float a = x1, bb = x2;
            if (rot) { a = x1 * cv[j] + x2 * sv[j]; bb = x2 * cv[j] - x1 * sv[j]; }
            o1[e] = a * rn;
            o2[e] = bb * rn;
          }
          asm("v_cvt_pk_bf16_f32 %0, %1, %2" : "=v"(wlo[j2]) : "v"(o1[0]), "v"(o1[1]));
          asm("v_cvt_pk_bf16_f32 %0, %1, %2" : "=v"(whi[j2]) : "v"(o2[0]), "v"(o2[1]));
        }
        union { uint32_t u[4]; s8v v; } ua, ub;
        ua.u[0] = wlo[0]; ua.u[1] = wlo[1]; ua.u[2] = wlo[2]; ua.u[3] = wlo[3];
        ub.u[0] = whi[0]; ub.u[1] = whi[1]; ub.u[2] = whi[2]; ub.u[3] = whi[3];
        qf[ks] = ua.v;
        qf[ks + 4] = ub.v;
      }
    }

    f16v yacc[4];
#pragma unroll
    for (int j = 0; j < 4; ++j)
#pragma unroll
      for (int r = 0; r < 16; ++r) yacc[j][r] = 0.f;
    float mrow = -1e30f, lrow = 0.f;

    stage(0, 0);
    __syncthreads();

    for (int t = 0; t < nt; ++t) {
      const int cur = t & 1;
      if (t + 1 < nt) stage(t + 1, cur ^ 1);
      const int kv0 = t * 64;

      // ---- QK^T swapped: S^T[kv][q] in exp2 domain, two 32-kv chunks ----
      f16v s0a, s1a;
#pragma unroll
      for (int r = 0; r < 16; ++r) { s0a[r] = 0.f; s1a[r] = 0.f; }
      __builtin_amdgcn_s_setprio(1);
#pragma unroll
      for (int ks = 0; ks < 8; ++ks) {
        const int slot = (2 * ks + hi) ^ (l31 & 15);
        s8v kf0 = *(const s8v*)&lK[cur][(l31)*128 + slot * 8];
        s8v kf1 = *(const s8v*)&lK[cur][(32 + l31) * 128 + slot * 8];
        s0a = __builtin_amdgcn_mfma_f32_32x32x16_bf16(kf0, qf[ks], s0a, 0, 0, 0);
        s1a = __builtin_amdgcn_mfma_f32_32x32x16_bf16(kf1, qf[ks], s1a, 0, 0, 0);
      }
      __builtin_amdgcn_s_setprio(0);

      // ---- causal mask + row max (in-register; scores already log2-scaled) ----
      const bool last = (t == nt - 1);
      float p0[16], p1[16];
      float pmax = -1e30f;
#pragma unroll
      for (int r = 0; r < 16; ++r) {
        const int kvloc = (r & 3) + 8 * (r >> 2) + 4 * hi;
        float v0 = s0a[r];
        float v1 = s1a[r];
        if (last) {
          if (kv0 + kvloc > pos) v0 = -1e30f;
          if (kv0 + 32 + kvloc > pos) v1 = -1e30f;
        }
        p0[r] = v0; p1[r] = v1;
        pmax = fmaxf(pmax, fmaxf(v0, v1));
      }
      pmax = fmaxf(pmax, __shfl_xor(pmax, 32, 64));

      // ---- defer-max (T13): THR = 8*log2e in exp2 domain ----
      if (!__all(pmax - mrow <= 11.541560327111707f)) {
        float mnew = fmaxf(mrow, pmax);
        float corr = __builtin_amdgcn_exp2f(mrow - mnew);
#pragma unroll
        for (int r = 0; r < 16; ++r) {
          const int qloc = (r & 3) + 8 * (r >> 2) + 4 * hi;
          float cb = __shfl(corr, qloc, 64);
          yacc[0][r] *= cb; yacc[1][r] *= cb; yacc[2][r] *= cb; yacc[3][r] *= cb;
        }
        lrow *= corr;
        mrow = mnew;
      }

      // ---- exp2 + fp32 row sum (denominator unrounded) ----
      float ps = 0.f;
#pragma unroll
      for (int r = 0; r < 16; ++r) {
        float e0 = __builtin_amdgcn_exp2f(p0[r] - mrow);
        float e1 = __builtin_amdgcn_exp2f(p1[r] - mrow);
        p0[r] = e0; p1[r] = e1;
        ps += e0 + e1;
      }
      ps += __shfl_xor(ps, 32, 64);
      lrow += ps;

      // ---- PV: cvt_pk pack + permlane32_swap exchange + MFMA ----
      __builtin_amdgcn_s_setprio(1);
#pragma unroll
      for (int ks = 0; ks < 4; ++ks) {
        const float* pc = (ks < 2) ? p0 : p1;
        const int rb = 8 * (ks & 1);
        uint32_t A0, A1, B0, B1;
        asm("v_cvt_pk_bf16_f32 %0, %1, %2" : "=v"(A0) : "v"(pc[rb + 0]), "v"(pc[rb + 1]));
        asm("v_cvt_pk_bf16_f32 %0, %1, %2" : "=v"(A1) : "v"(pc[rb + 2]), "v"(pc[rb + 3]));
        asm("v_cvt_pk_bf16_f32 %0, %1, %2" : "=v"(B0) : "v"(pc[rb + 4]), "v"(pc[rb + 5]));
        asm("v_cvt_pk_bf16_f32 %0, %1, %2" : "=v"(B1) : "v"(pc[rb + 6]), "v"(pc[rb + 7]));
        // after swap: A0 = [A0_lo|B0_lo] = uu0, B0 = [A0_hi|B0_hi] = uu2 (ditto A1/B1)
        asm("v_permlane32_swap_b32 %0, %1" : "+v"(A0), "+v"(B0));
        asm("v_permlane32_swap_b32 %0, %1" : "+v"(A1), "+v"(B1));
        union { uint32_t u[4]; s8v v; } uu;
        uu.u[0] = A0; uu.u[1] = A1; uu.u[2] = B0; uu.u[3] = B1;
#pragma unroll
        for (int jd = 0; jd < 4; ++jd) {
          const int rowd = 32 * jd + l31;
          const int line = rowd >> 1;
          const int gl = ((rowd & 1) << 3) | (2 * ks + hi);
          const int c = gl ^ (line & 15);
          s8v vf = *(const s8v*)&lVT[cur][line * 128 + c * 8];
          yacc[jd] = __builtin_amdgcn_mfma_f32_32x32x16_bf16(uu.v, vf, yacc[jd], 0, 0, 0);
        }
      }
      __builtin_amdgcn_s_setprio(0);
      __syncthreads();
    }

    // ---- finalize: broadcast 1/l per C-row, write y (B,L,H*128) bf16 ----
    float inv = 1.0f / lrow;
#pragma unroll
    for (int r = 0; r < 16; ++r) {
      const int qloc = (r & 3) + 8 * (r >> 2) + 4 * hi;
      float ib = __shfl(inv, qloc, 64);
      const int qrow = q0 + 32 * se + qloc;
      size_t base = ((size_t)(b * 2048 + qrow)) * 2048 + h * 128 + l31;
#pragma unroll
      for (int jd = 0; jd < 4; ++jd)
        y[base + 32 * jd] = f2bf(yacc[jd][r] * ib);
    }
  }
}

extern "C" void kernel_launch(void* const* d_in, const int* in_sizes, int n_in,
                              void* d_out, int out_size, void* d_ws, size_t ws_size,
                              hipStream_t stream) {
  const float* x  = (const float*)d_in[0];
  const float* Wq = (const float*)d_in[1];
  const float* Wk = (const float*)d_in[2];
  const float* Wv = (const float*)d_in[3];
  const float* Wp = (const float*)d_in[4];
  const float* qg = (const float*)d_in[5];
  float* out = (float*)d_out;

  char* ws = (char*)d_ws;
  size_t off = 0;
  auto alloc = [&](size_t bytes) {
    void* p = ws + off;
    off += (bytes + 255) & ~(size_t)255;
    return p;
  };
  u16* x_bf  = (u16*)alloc((size_t)8192 * 2048 * 2);   // also reused as y_bf
  u16* wq_bf = (u16*)alloc((size_t)2048 * 2048 * 2);   // also reused as vt_bf
  u16* wk_bf = (u16*)alloc((size_t)512 * 2048 * 2);    // wk|wv contiguous = KV weight
  u16* wv_bf = (u16*)alloc((size_t)512 * 2048 * 2);
  u16* wp_bf = (u16*)alloc((size_t)2048 * 2048 * 2);
  u16* q_bf  = (u16*)alloc((size_t)4 * 16 * 2048 * 128 * 2);
  u16* k_bf  = (u16*)alloc((size_t)4 * 4 * 2048 * 128 * 2);
  u16* v_bf  = (u16*)alloc((size_t)4 * 4 * 2048 * 128 * 2);
  float* tab = (float*)alloc((size_t)2032 * 64 * 2 * 4);
  u16* y_bf  = x_bf;    // x dead after QKV GEMMs
  u16* vt_bf = wq_bf;   // Wq dead after Q GEMM (same size)
  (void)wv_bf;

  prep<<<2048, 256, 0, stream>>>((const float4*)x, (const float4*)Wq,
                                 (const float4*)Wk, (const float4*)Wv,
                                 (const float4*)Wp, (uint2*)x_bf, (uint2*)wq_bf,
                                 tab, tab + 2032 * 64);
  gemm_qkv<<<dim3(512), 512, 0, stream>>>(x_bf, wq_bf, wk_bf, q_bf, k_bf, v_bf);
  norm_transpose<<<dim3(1280), 256, 0, stream>>>(k_bf, v_bf, vt_bf,
                                                 tab, tab + 2032 * 64);
  attn<<<dim3(256), 512, 0, stream>>>(q_bf, k_bf, vt_bf, y_bf, qg,
                                      tab, tab + 2032 * 64);
  gemm_proj<<<dim3(256), 512, 0, stream>>>(y_bf, wp_bf, out);
}

// Round 16
// 325.695 us; speedup vs baseline: 1.1495x; 1.0211x over previous
//
#include <hip/hip_runtime.h>
#include <stdint.h>

// Shapes (fixed): B=4 L=2048 D=2048 H=16 KVH=4 HD=128 M=16 T=2032
typedef unsigned short u16;
typedef short s8v __attribute__((ext_vector_type(8)));   // 8 bf16 (4 VGPR) MFMA frag
typedef float f4v __attribute__((ext_vector_type(4)));   // 16x16 MFMA accum
typedef float f16v __attribute__((ext_vector_type(16))); // 32x32 MFMA accum

typedef __attribute__((address_space(1))) char gchar;
typedef __attribute__((address_space(3))) char lchar;

static __device__ __forceinline__ u16 f2bf(float f) {
  uint32_t x = __float_as_uint(f);
  x += 0x7fffu + ((x >> 16) & 1u);            // RNE
  return (u16)(x >> 16);
}
static __device__ __forceinline__ float bf2f(u16 u) {
  return __uint_as_float(((uint32_t)u) << 16);
}
// async global->LDS, 16B per lane. LDS dest must be wave-linear (base + lane*16).
static __device__ __forceinline__ void gload_lds16(const void* g, void* l) {
  __builtin_amdgcn_global_load_lds((gchar*)(uintptr_t)g,
                                   (lchar*)(uint32_t)(uintptr_t)l, 16, 0, 0);
}

// ---------------- prep: x->bf16, weights->bf16, rope table (one launch) ----------------
__global__ __launch_bounds__(256) void prep(const float4* __restrict__ x,
                                            const float4* __restrict__ wq,
                                            const float4* __restrict__ wk,
                                            const float4* __restrict__ wv,
                                            const float4* __restrict__ wp,
                                            uint2* __restrict__ xbf,
                                            uint2* __restrict__ wbf,
                                            float* __restrict__ tc,
                                            float* __restrict__ ts) {
  const int gid = blockIdx.x * 256 + threadIdx.x;
  const int st = gridDim.x * 256;
  for (int i = gid; i < 4194304; i += st) {            // x: 8192x2048 fp32
    float4 v = x[i];
    uint2 o;
    o.x = (uint32_t)f2bf(v.x) | ((uint32_t)f2bf(v.y) << 16);
    o.y = (uint32_t)f2bf(v.z) | ((uint32_t)f2bf(v.w) << 16);
    xbf[i] = o;
  }
  for (int i = gid; i < 2621440; i += st) {            // wq|wk|wv|wp contiguous dst
    const float4* s;
    int off;
    if (i < 1048576)      { s = wq; off = i; }
    else if (i < 1310720) { s = wk; off = i - 1048576; }
    else if (i < 1572864) { s = wv; off = i - 1310720; }
    else                  { s = wp; off = i - 1572864; }
    float4 v = s[off];
    uint2 o;
    o.x = (uint32_t)f2bf(v.x) | ((uint32_t)f2bf(v.y) << 16);
    o.y = (uint32_t)f2bf(v.z) | ((uint32_t)f2bf(v.w) << 16);
    wbf[i] = o;
  }
  for (int i = gid; i < 2032 * 64; i += st) {          // rope table [T][64]
    int t = i >> 6, f = i & 63;
    float invf = 1.0f / powf(10000.0f, (float)f * (1.0f / 64.0f));
    float ang = (float)t * invf;
    float s, c;
    sincosf(ang, &s, &c);
    tc[i] = c;
    ts[i] = s;
  }
}

// ---------------- gemm8 body: 256x256 8-phase (R13 structure) ----------------
// R15 counter: col-major XCD chunk -> each XCD sweeps all bm -> FULL 32MB A
// re-fetched per XCD (FETCH 268MB ~= 8x32+8). Row-major chunk: each XCD owns
// 4 bm rows x all 8 bn -> 4MB A + 8MB B per XCD ~= 100MB total.
template <int OUT>
static __device__ __forceinline__ void gemm8_body(
    u16* sm, int bid, const u16* __restrict__ A, const u16* __restrict__ Wt,
    u16* __restrict__ Oa, float* __restrict__ OF) {
  const int tid = threadIdx.x;
  const int lane = tid & 63, wid = tid >> 6;
  const int wr = wid >> 2, wc = wid & 3;
  const int l15 = lane & 15, l4 = lane >> 4;

  const int swz = (bid & 7) * 32 + (bid >> 3);   // XCD chunk (256-block path)
  const int bm = swz >> 3, bn = swz & 7;         // ROW-major: 4 A-rows per XCD
  const int m0 = bm * 256;
  const int n0r = bn * 256;

  auto pA = [&](int bs, int mh) { return sm + (bs * 2 + mh) * 8192; };
  auto pB = [&](int bs, int nh) { return sm + 32768 + (bs * 2 + nh) * 8192; };

  auto stageA = [&](int kt, int bs, int mh) {
    const int kb = kt * 64;
#pragma unroll
    for (int c = 0; c < 2; ++c) {
      int cidx = tid + c * 512;
      int rr = cidx >> 3, pc = cidx & 7;
      int grow = mh * 64 + (rr & 63) + ((rr >> 6) << 7);
      int kc = pc ^ (rr & 7);
      gload_lds16(A + (size_t)(m0 + grow) * 2048 + kb + kc * 8,
                  pA(bs, mh) + cidx * 8);
    }
  };
  auto stageB = [&](int kt, int bs, int nh) {
    const int kb = kt * 64;
#pragma unroll
    for (int c = 0; c < 2; ++c) {
      int cidx = tid + c * 512;
      int rr = cidx >> 3, pc = cidx & 7;
      int gn = ((rr >> 5) << 6) + nh * 32 + (rr & 31);
      int kc = pc ^ (rr & 7);
      gload_lds16(Wt + (size_t)(n0r + gn) * 2048 + kb + kc * 8,
                  pB(bs, nh) + cidx * 8);
    }
  };
  auto readA = [&](int bs, int mh, int i, int ks) {
    int rr = wr * 64 + i * 16 + l15;
    return *(const s8v*)&pA(bs, mh)[rr * 64 + (((ks * 4 + l4) ^ (rr & 7)) << 3)];
  };
  auto readB = [&](int bs, int nh, int j, int ks) {
    int rr = wc * 32 + j * 16 + l15;
    return *(const s8v*)&pB(bs, nh)[rr * 64 + (((ks * 4 + l4) ^ (rr & 7)) << 3)];
  };

  const f4v Z4 = {0.f, 0.f, 0.f, 0.f};
  f4v acc[8][4];                 // [mh*4+i][nh*2+j]
#pragma unroll
  for (int i = 0; i < 8; i++)
#pragma unroll
    for (int j = 0; j < 4; j++) acc[i][j] = Z4;

  stageA(0, 0, 0); stageA(0, 0, 1); stageB(0, 0, 0); stageB(0, 0, 1);
  stageA(1, 1, 0); stageA(1, 1, 1); stageB(1, 1, 0);
  asm volatile("s_waitcnt vmcnt(6)" ::: "memory");   // tile0 certified
  asm volatile("s_barrier" ::: "memory");

  const int NT = 32;
  for (int t = 0; t < NT; ++t) {
    const int bs = t & 1, nbs = bs ^ 1;
    s8v a[4][2], b[2][2];
    // phase 0: (mh0, nh0)
#pragma unroll
    for (int i = 0; i < 4; ++i)
#pragma unroll
      for (int ks = 0; ks < 2; ++ks) a[i][ks] = readA(bs, 0, i, ks);
#pragma unroll
    for (int j = 0; j < 2; ++j)
#pragma unroll
      for (int ks = 0; ks < 2; ++ks) b[j][ks] = readB(bs, 0, j, ks);
    if (t + 1 < NT) stageB(t + 1, nbs, 1);
    asm volatile("s_barrier" ::: "memory");
    asm volatile("s_waitcnt lgkmcnt(0)" ::: "memory");
    __builtin_amdgcn_sched_barrier(0);
    __builtin_amdgcn_s_setprio(1);
#pragma unroll
    for (int i = 0; i < 4; ++i)
#pragma unroll
      for (int j = 0; j < 2; ++j)
#pragma unroll
        for (int ks = 0; ks < 2; ++ks)
          acc[i][j] = __builtin_amdgcn_mfma_f32_16x16x32_bf16(a[i][ks], b[j][ks], acc[i][j], 0, 0, 0);
    __builtin_amdgcn_s_setprio(0);
    asm volatile("s_barrier" ::: "memory");
    // phase 1: (mh0, nh1)
#pragma unroll
    for (int j = 0; j < 2; ++j)
#pragma unroll
      for (int ks = 0; ks < 2; ++ks) b[j][ks] = readB(bs, 1, j, ks);
    if (t + 2 < NT) stageA(t + 2, bs, 0);
    asm volatile("s_barrier" ::: "memory");
    asm volatile("s_waitcnt lgkmcnt(0)" ::: "memory");
    __builtin_amdgcn_sched_barrier(0);
    __builtin_amdgcn_s_setprio(1);
#pragma unroll
    for (int i = 0; i < 4; ++i)
#pragma unroll
      for (int j = 0; j < 2; ++j)
#pragma unroll
        for (int ks = 0; ks < 2; ++ks)
          acc[i][2 + j] = __builtin_amdgcn_mfma_f32_16x16x32_bf16(a[i][ks], b[j][ks], acc[i][2 + j], 0, 0, 0);
    __builtin_amdgcn_s_setprio(0);
    asm volatile("s_barrier" ::: "memory");
    // phase 2: (mh1, nh0)
#pragma unroll
    for (int i = 0; i < 4; ++i)
#pragma unroll
      for (int ks = 0; ks < 2; ++ks) a[i][ks] = readA(bs, 1, i, ks);
#pragma unroll
    for (int j = 0; j < 2; ++j)
#pragma unroll
      for (int ks = 0; ks < 2; ++ks) b[j][ks] = readB(bs, 0, j, ks);
    asm volatile("s_barrier" ::: "memory");
    asm volatile("s_waitcnt lgkmcnt(0)" ::: "memory");
    __builtin_amdgcn_sched_barrier(0);
    __builtin_amdgcn_s_setprio(1);
#pragma unroll
    for (int i = 0; i < 4; ++i)
#pragma unroll
      for (int j = 0; j < 2; ++j)
#pragma unroll
        for (int ks = 0; ks < 2; ++ks)
          acc[4 + i][j] = __builtin_amdgcn_mfma_f32_16x16x32_bf16(a[i][ks], b[j][ks], acc[4 + i][j], 0, 0, 0);
    __builtin_amdgcn_s_setprio(0);
    asm volatile("s_barrier" ::: "memory");
    // phase 3: (mh1, nh1)
#pragma unroll
    for (int j = 0; j < 2; ++j)
#pragma unroll
      for (int ks = 0; ks < 2; ++ks) b[j][ks] = readB(bs, 1, j, ks);
    if (t + 2 < NT) { stageA(t + 2, bs, 1); stageB(t + 2, bs, 0); }
    asm volatile("s_barrier" ::: "memory");
    asm volatile("s_waitcnt lgkmcnt(0)" ::: "memory");
    __builtin_amdgcn_sched_barrier(0);
    __builtin_amdgcn_s_setprio(1);
#pragma unroll
    for (int i = 0; i < 4; ++i)
#pragma unroll
      for (int j = 0; j < 2; ++j)
#pragma unroll
        for (int ks = 0; ks < 2; ++ks)
          acc[4 + i][2 + j] = __builtin_amdgcn_mfma_f32_16x16x32_bf16(a[i][ks], b[j][ks], acc[4 + i][2 + j], 0, 0, 0);
    __builtin_amdgcn_s_setprio(0);
    if (t + 2 < NT)      asm volatile("s_waitcnt vmcnt(6)" ::: "memory");
    else if (t + 1 < NT) asm volatile("s_waitcnt vmcnt(0)" ::: "memory");
    asm volatile("s_barrier" ::: "memory");      // RAW gate: tile t+1 certified
  }

  const int colg0 = bn * 256 + wc * 64;
  if constexpr (OUT == 0) {                      // Q: (B,16,L,128) bf16
    const int hh = colg0 >> 7, d0 = colg0 & 127;
#pragma unroll
    for (int i = 0; i < 8; i++)
#pragma unroll
      for (int r = 0; r < 4; r++) {
        int m = m0 + wr * 128 + (i >> 2) * 64 + (i & 3) * 16 + l4 * 4 + r;
        int b2 = m >> 11, l = m & 2047;
        size_t base = ((size_t)(b2 * 16 + hh) * 2048 + l) * 128 + d0;
#pragma unroll
        for (int j = 0; j < 4; j++)
          Oa[base + (j >> 1) * 32 + (j & 1) * 16 + l15] = f2bf(acc[i][j][r]);
      }
  } else {                                       // proj: fp32 row-major
#pragma unroll
    for (int i = 0; i < 8; i++)
#pragma unroll
      for (int r = 0; r < 4; r++) {
        int m = m0 + wr * 128 + (i >> 2) * 64 + (i & 3) * 16 + l4 * 4 + r;
#pragma unroll
        for (int j = 0; j < 4; j++)
          OF[(size_t)m * 2048 + colg0 + (j >> 1) * 32 + (j & 1) * 16 + l15] = acc[i][j][r];
      }
  }
}

// ---------------- gemm_kv body: 256x128 region structure (R10, row-major XCD) ----------------
static __device__ __forceinline__ void gemm_kv_body(
    u16* sm, int bid, const u16* __restrict__ A, const u16* __restrict__ Wt,
    u16* __restrict__ Oa, u16* __restrict__ Ob2) {
  constexpr int MI = 4;
  const int tid = threadIdx.x;
  const int lane = tid & 63, wid = tid >> 6;
  const int wr = wid >> 1, wc = wid & 1;
  const int l15 = lane & 15, l4 = lane >> 4;

  const int swz = (bid & 7) * 32 + (bid >> 3);
  const int bm = swz >> 3, bn = swz & 7;         // ROW-major chunk
  const int m0 = bm * 256;
  const int n0r = bn * 128;

  auto pA = [&](int bs, int ks) { return sm + (bs * 2 + ks) * 8192; };
  auto pB = [&](int bs, int ks) { return sm + 32768 + (bs * 2 + ks) * 4096; };

  auto stage_part = [&](int kt, int bs, int ks) {
    const int kb = kt * 64 + ks * 32;
#pragma unroll
    for (int c = 0; c < 2; ++c) {
      int cidx = tid + c * 512;
      int r = cidx >> 2, q = cidx & 3;
      int cc = q ^ ((r >> 2) & 3);
      gload_lds16(A + (size_t)(m0 + r) * 2048 + kb + cc * 8,
                  pA(bs, ks) + cidx * 8);
    }
    {
      int cidx = tid;
      int r = cidx >> 2, q = cidx & 3;
      int cc = q ^ ((r >> 2) & 3);
      gload_lds16(Wt + (size_t)(n0r + r) * 2048 + kb + cc * 8,
                  pB(bs, ks) + cidx * 8);
    }
  };
  auto roff = [&](int fr, int c) {
    return (fr * 4 + (c ^ ((fr >> 2) & 3))) * 8;
  };

  const f4v Z4 = {0.f, 0.f, 0.f, 0.f};
  f4v acc[MI][4];
#pragma unroll
  for (int i = 0; i < MI; i++)
#pragma unroll
    for (int j = 0; j < 4; j++) acc[i][j] = Z4;

  stage_part(0, 0, 0); stage_part(0, 0, 1);
  stage_part(1, 1, 0); stage_part(1, 1, 1);

  const int NT = 32;
  for (int t = 0; t < NT; ++t) {
    const int bs = t & 1;
    if (t + 1 < NT) asm volatile("s_waitcnt vmcnt(6)" ::: "memory");
    else            asm volatile("s_waitcnt vmcnt(0)" ::: "memory");
    asm volatile("s_barrier" ::: "memory");
    const bool pf = (t + 2 < NT);
#pragma unroll
    for (int ks = 0; ks < 2; ++ks) {
      s8v afrg[MI], bfrg[4];
#pragma unroll
      for (int i = 0; i < MI; ++i)
        afrg[i] = *(const s8v*)&pA(bs, ks)[roff(wr * (MI * 16) + i * 16 + l15, l4)];
#pragma unroll
      for (int j = 0; j < 4; ++j)
        bfrg[j] = *(const s8v*)&pB(bs, ks)[roff(wc * 64 + j * 16 + l15, l4)];
      asm volatile("s_waitcnt lgkmcnt(0)" ::: "memory");
      __builtin_amdgcn_sched_barrier(0);
      asm volatile("s_barrier" ::: "memory");
      if (pf) stage_part(t + 2, bs, ks);
      __builtin_amdgcn_s_setprio(1);
#pragma unroll
      for (int i = 0; i < MI; ++i)
#pragma unroll
        for (int j = 0; j < 4; ++j)
          acc[i][j] = __builtin_amdgcn_mfma_f32_16x16x32_bf16(afrg[i], bfrg[j], acc[i][j], 0, 0, 0);
      __builtin_amdgcn_s_setprio(0);
    }
  }

  const int colg = bn * 128 + wc * 64;
  u16* Ob = (colg < 512) ? Oa : Ob2;
  const int hh = (colg & 511) >> 7, d0 = colg & 127;
#pragma unroll
  for (int i = 0; i < MI; i++)
#pragma unroll
    for (int r = 0; r < 4; r++) {
      int m = m0 + wr * (MI * 16) + i * 16 + l4 * 4 + r;
      int b = m >> 11, l = m & 2047;
      size_t base = ((size_t)(b * 4 + hh) * 2048 + l) * 128 + d0;
#pragma unroll
      for (int j = 0; j < 4; j++)
        Ob[base + j * 16 + l15] = f2bf(acc[i][j][r]);
    }
}

// ---------------- merged QKV GEMM: 512 blocks = 256 Q-path + 256 KV-path ----------------
__global__ __launch_bounds__(512, 2) void gemm_qkv(
    const u16* __restrict__ x, const u16* __restrict__ wq,
    const u16* __restrict__ wkv, u16* __restrict__ q,
    u16* __restrict__ kO, u16* __restrict__ vO) {
  __shared__ u16 smem[65536];                    // 128KB arena (both paths fit)
  const int bid = (int)blockIdx.x;
  if (bid < 256) gemm8_body<0>(smem, bid, x, wq, q, nullptr);
  else           gemm_kv_body(smem, bid - 256, x, wkv, kO, vO);
}

// ---------------- proj GEMM (gemm8 path, own launch) ----------------
__global__ __launch_bounds__(512, 2) void gemm_proj(
    const u16* __restrict__ y, const u16* __restrict__ wp, float* __restrict__ out) {
  __shared__ u16 smem[65536];
  gemm8_body<2>(smem, (int)blockIdx.x, y, wp, nullptr, out);
}

// ---------------- merged K-norm + V-transpose (1280 blocks) ----------------
__global__ __launch_bounds__(256) void norm_transpose(
    u16* __restrict__ kbuf, const u16* __restrict__ v, u16* __restrict__ vt,
    const float* __restrict__ tc, const float* __restrict__ ts) {
  __shared__ u16 t[64][64];
  const int bid = (int)blockIdx.x;
  const int tid = threadIdx.x;
  if (bid < 1024) {
    const int l0 = (bid & 31) * 64, d0 = ((bid >> 5) & 1) * 64, bg = bid >> 6;
#pragma unroll
    for (int it = 0; it < 2; ++it) {
      int lin = it * 256 + tid;
      int r = lin >> 3, cb = lin & 7;
      s8v val = *(const s8v*)&v[((bg * 2048 + l0 + r) * 128) + d0 + cb * 8];
      *(s8v*)&t[r][(cb ^ (r & 7)) * 8] = val;
    }
    __syncthreads();
#pragma unroll
    for (int it = 0; it < 2; ++it) {
      int lin = it * 256 + tid;
      int r2 = lin >> 3, c2 = (lin & 7) * 8;
      s8v o;
#pragma unroll
      for (int j = 0; j < 8; ++j) {
        int rr = c2 + j, cc = r2;
        o[j] = (short)t[rr][(cc & 7) + 8 * ((cc >> 3) ^ (rr & 7))];
      }
      *(s8v*)&vt[((bg * 128 + d0 + r2) * 2048) + l0 + c2] = o;
    }
  } else {
    const int lane = tid & 63;
    const int gw = (bid - 1024) * 4 + (tid >> 6);
    for (int row = gw; row < 32768; row += 1024) {
      int l = row & 2047;
      u16* p = kbuf + (size_t)row * 128;
      float x1 = bf2f(p[lane]);
      float x2 = bf2f(p[lane + 64]);
      float ss = x1 * x1 + x2 * x2;
#pragma unroll
      for (int off = 32; off > 0; off >>= 1) ss += __shfl_xor(ss, off, 64);
      float r = rsqrtf(ss * (1.0f / 128.0f) + 1.1920929e-07f);
      x1 *= r; x2 *= r;
      if (l >= 16) {
        int tt = l - 16;
        float c = tc[tt * 64 + lane], s = ts[tt * 64 + lane];
        float o1 = x1 * c + x2 * s;
        float o2 = -x1 * s + x2 * c;
        x1 = o1; x2 = o2;
      }
      p[lane] = f2bf(x1);
      p[lane + 64] = f2bf(x2);
    }
  }
}

// ---------------- flash attention v3 (R14 layout) + tree-reduced softmax ----------------
// Row-max and row-sum were 31-deep serial fp chains (~250cy/tile latency);
// reassociated into depth-4 trees (fp32 sum order change only).
__global__ __launch_bounds__(512, 2) void attn(const u16* __restrict__ q,
                                               const u16* __restrict__ k,
                                               const u16* __restrict__ vt,
                                               u16* __restrict__ y,
                                               const float* __restrict__ qg,
                                               const float* __restrict__ tc,
                                               const float* __restrict__ ts) {
  __shared__ u16 lK[2][64 * 128];   // row kv: 16 chunks, phys = logical ^ (kv&15)
  __shared__ u16 lVT[2][64 * 128];  // line d>>1: 16 chunks, phys = ((d&1)*8+kc) ^ (line&15)
  const int tid = threadIdx.x;
  const int lane = tid & 63, wid = tid >> 6;
  const int l31 = lane & 31, hi = lane >> 5;

  const int bid = (int)blockIdx.x;                 // 0..255
  const int bg = (bid & 7) * 2 + (bid >> 7);       // XCD k hosts bg {2k,2k+1}
  const int pairi = (bid >> 3) & 15;               // 0..15
  const int b = bg >> 2, g = bg & 3;
  const int h = g * 4 + (wid & 3);
  const int se = wid >> 2;                         // row-half 0/1

  const u16* qh = q + (size_t)(b * 16 + h) * 2048 * 128;
  const u16* kb0 = k + (size_t)(b * 4 + g) * 2048 * 128;
  const u16* vtb0 = vt + (size_t)(b * 4 + g) * 128 * 2048;
  const float gscale = qg[h] * (0.08838834764831845f * 1.4426950408889634f);

  auto stage = [&](int t, int bufsel) {
    const int kv0 = t * 64;
#pragma unroll
    for (int it = 0; it < 2; ++it) {        // K tile 64x128 (16KB)
      int lin = it * 512 + tid;
      int kj = lin >> 4, s = lin & 15;
      gload_lds16(kb0 + (size_t)(kv0 + kj) * 128 + ((s ^ (kj & 15)) * 8),
                  &lK[bufsel][lin * 8]);
    }
#pragma unroll
    for (int it = 0; it < 2; ++it) {        // VT tile 128x64 (16KB), paired-d lines
      int lin = it * 512 + tid;
      int r = lin >> 4, c = lin & 15;
      int gl = c ^ (r & 15);
      int d = 2 * r + (gl >> 3);
      gload_lds16(vtb0 + (size_t)d * 2048 + kv0 + ((gl & 7) * 8),
                  &lVT[bufsel][lin * 8]);
    }
  };

  for (int ph = 0; ph < 2; ++ph) {
    const int qt = ph ? (31 - pairi) : pairi;
    const int q0 = qt * 64;
    const int nt = qt + 1;                  // KV tiles of 64
    const int pos = q0 + 32 * se + l31;

    // ---- fused Q: RMSNorm + RoPE + gain*(1/sqrt(128))*log2(e), pack B-frags ----
    s8v qf[8];
    {
      const u16* qp = qh + (size_t)pos * 128 + hi * 8;
      s8v qr[8];
#pragma unroll
      for (int ks = 0; ks < 8; ++ks) qr[ks] = *(const s8v*)&qp[ks * 16];
      float ssum = 0.f;
#pragma unroll
      for (int ks = 0; ks < 8; ++ks)
#pragma unroll
        for (int j = 0; j < 8; ++j) {
          float v = bf2f((u16)qr[ks][j]);
          ssum += v * v;
        }
      ssum += __shfl_xor(ssum, 32, 64);
      const float rn = rsqrtf(ssum * (1.0f / 128.0f) + 1.1920929e-07f) * gscale;
      const bool rot = (pos >= 16);
      const int tt = pos - 16;
#pragma unroll
      for (int ks = 0; ks < 4; ++ks) {
        float cv[8], sv[8];
        if (rot) {
          const float* cp = &tc[tt * 64 + ks * 16 + hi * 8];
          const float* sp = &ts[tt * 64 + ks * 16 + hi * 8];
          *(float4*)&cv[0] = *(const float4*)cp;
          *(float4*)&cv[4] = *(const float4*)(cp + 4);
          *(float4*)&sv[0] = *(const float4*)sp;
          *(float4*)&sv[4] = *(const float4*)(sp + 4);
        }
        uint32_t wlo[4], whi[4];
#pragma unroll
        for (int j2 = 0; j2 < 4; ++j2) {
          float o1[2], o2[2];
#pragma unroll
          for (int e = 0; e < 2; ++e) {
            const int j = j2 * 2 + e;
            float x1 = bf2f((u16)qr[ks][j]);
            float x2 = bf2f((u16)qr[ks + 4][j]);
            float a = x1, bb = x2;
            if (rot) { a = x1 * cv[j] + x2 * sv[j]; bb = x2 * cv[j] - x1 * sv[j]; }
            o1[e] = a * rn;
            o2[e] = bb * rn;
          }
          asm("v_cvt_pk_bf16_f32 %0, %1, %2" : "=v"(wlo[j2]) : "v"(o1[0]), "v"(o1[1]));
          asm("v_cvt_pk_bf16_f32 %0, %1, %2" : "=v"(whi[j2]) : "v"(o2[0]), "v"(o2[1]));
        }
        union { uint32_t u[4]; s8v v; } ua, ub;
        ua.u[0] = wlo[0]; ua.u[1] = wlo[1]; ua.u[2] = wlo[2]; ua.u[3] = wlo[3];
        ub.u[0] = whi[0]; ub.u[1] = whi[1]; ub.u[2] = whi[2]; ub.u[3] = whi[3];
        qf[ks] = ua.v;
        qf[ks + 4] = ub.v;
      }
    }

    f16v yacc[4];
#pragma unroll
    for (int j = 0; j < 4; ++j)
#pragma unroll
      for (int r = 0; r < 16; ++r) yacc[j][r] = 0.f;
    float mrow = -1e30f, lrow = 0.f;

    stage(0, 0);
    __syncthreads();

    for (int t = 0; t < nt; ++t) {
      const int cur = t & 1;
      if (t + 1 < nt) stage(t + 1, cur ^ 1);
      const int kv0 = t * 64;

      // ---- QK^T swapped: S^T[kv][q] in exp2 domain, two 32-kv chunks ----
      f16v s0a, s1a;
#pragma unroll
      for (int r = 0; r < 16; ++r) { s0a[r] = 0.f; s1a[r] = 0.f; }
      __builtin_amdgcn_s_setprio(1);
#pragma unroll
      for (int ks = 0; ks < 8; ++ks) {
        const int slot = (2 * ks + hi) ^ (l31 & 15);
        s8v kf0 = *(const s8v*)&lK[cur][(l31)*128 + slot * 8];
        s8v kf1 = *(const s8v*)&lK[cur][(32 + l31) * 128 + slot * 8];
        s0a = __builtin_amdgcn_mfma_f32_32x32x16_bf16(kf0, qf[ks], s0a, 0, 0, 0);
        s1a = __builtin_amdgcn_mfma_f32_32x32x16_bf16(kf1, qf[ks], s1a, 0, 0, 0);
      }
      __builtin_amdgcn_s_setprio(0);

      // ---- causal mask + row max (tree-reduced) ----
      const bool last = (t == nt - 1);
      float p0[16], p1[16], mx[16];
#pragma unroll
      for (int r = 0; r < 16; ++r) {
        const int kvloc = (r & 3) + 8 * (r >> 2) + 4 * hi;
        float v0 = s0a[r];
        float v1 = s1a[r];
        if (last) {
          if (kv0 + kvloc > pos) v0 = -1e30f;
          if (kv0 + 32 + kvloc > pos) v1 = -1e30f;
        }
        p0[r] = v0; p1[r] = v1;
        mx[r] = fmaxf(v0, v1);
      }
#pragma unroll
      for (int s2 = 8; s2 > 0; s2 >>= 1)
#pragma unroll
        for (int r = 0; r < s2; ++r) mx[r] = fmaxf(mx[r], mx[r + s2]);
      float pmax = fmaxf(mx[0], __shfl_xor(mx[0], 32, 64));

      // ---- defer-max (T13): THR = 8*log2e in exp2 domain ----
      if (!__all(pmax - mrow <= 11.541560327111707f)) {
        float mnew = fmaxf(mrow, pmax);
        float corr = __builtin_amdgcn_exp2f(mrow - mnew);
#pragma unroll
        for (int r = 0; r < 16; ++r) {
          const int qloc = (r & 3) + 8 * (r >> 2) + 4 * hi;
          float cb = __shfl(corr, qloc, 64);
          yacc[0][r] *= cb; yacc[1][r] *= cb; yacc[2][r] *= cb; yacc[3][r] *= cb;
        }
        lrow *= corr;
        mrow = mnew;
      }

      // ---- exp2 + fp32 row sum (tree-reduced) ----
      float sm[16];
#pragma unroll
      for (int r = 0; r < 16; ++r) {
        float e0 = __builtin_amdgcn_exp2f(p0[r] - mrow);
        float e1 = __builtin_amdgcn_exp2f(p1[r] - mrow);
        p0[r] = e0; p1[r] = e1;
        sm[r] = e0 + e1;
      }
#pragma unroll
      for (int s2 = 8; s2 > 0; s2 >>= 1)
#pragma unroll
        for (int r = 0; r < s2; ++r) sm[r] += sm[r + s2];
      float ps = sm[0] + __shfl_xor(sm[0], 32, 64);
      lrow += ps;

      // ---- PV: cvt_pk pack + permlane32_swap exchange + MFMA ----
      __builtin_amdgcn_s_setprio(1);
#pragma unroll
      for (int ks = 0; ks < 4; ++ks) {
        const float* pc = (ks < 2) ? p0 : p1;
        const int rb = 8 * (ks & 1);
        uint32_t A0, A1, B0, B1;
        asm("v_cvt_pk_bf16_f32 %0, %1, %2" : "=v"(A0) : "v"(pc[rb + 0]), "v"(pc[rb + 1]));
        asm("v_cvt_pk_bf16_f32 %0, %1, %2" : "=v"(A1) : "v"(pc[rb + 2]), "v"(pc[rb + 3]));
        asm("v_cvt_pk_bf16_f32 %0, %1, %2" : "=v"(B0) : "v"(pc[rb + 4]), "v"(pc[rb + 5]));
        asm("v_cvt_pk_bf16_f32 %0, %1, %2" : "=v"(B1) : "v"(pc[rb + 6]), "v"(pc[rb + 7]));
        // after swap: A0 = [A0_lo|B0_lo] = uu0, B0 = [A0_hi|B0_hi] = uu2 (ditto A1/B1)
        asm("v_permlane32_swap_b32 %0, %1" : "+v"(A0), "+v"(B0));
        asm("v_permlane32_swap_b32 %0, %1" : "+v"(A1), "+v"(B1));
        union { uint32_t u[4]; s8v v; } uu;
        uu.u[0] = A0; uu.u[1] = A1; uu.u[2] = B0; uu.u[3] = B1;
#pragma unroll
        for (int jd = 0; jd < 4; ++jd) {
          const int rowd = 32 * jd + l31;
          const int line = rowd >> 1;
          const int gl = ((rowd & 1) << 3) | (2 * ks + hi);
          const int c = gl ^ (line & 15);
          s8v vf = *(const s8v*)&lVT[cur][line * 128 + c * 8];
          yacc[jd] = __builtin_amdgcn_mfma_f32_32x32x16_bf16(uu.v, vf, yacc[jd], 0, 0, 0);
        }
      }
      __builtin_amdgcn_s_setprio(0);
      __syncthreads();
    }

    // ---- finalize: broadcast 1/l per C-row, write y (B,L,H*128) bf16 ----
    float inv = 1.0f / lrow;
#pragma unroll
    for (int r = 0; r < 16; ++r) {
      const int qloc = (r & 3) + 8 * (r >> 2) + 4 * hi;
      float ib = __shfl(inv, qloc, 64);
      const int qrow = q0 + 32 * se + qloc;
      size_t base = ((size_t)(b * 2048 + qrow)) * 2048 + h * 128 + l31;
#pragma unroll
      for (int jd = 0; jd < 4; ++jd)
        y[base + 32 * jd] = f2bf(yacc[jd][r] * ib);
    }
  }
}

extern "C" void kernel_launch(void* const* d_in, const int* in_sizes, int n_in,
                              void* d_out, int out_size, void* d_ws, size_t ws_size,
                              hipStream_t stream) {
  const float* x  = (const float*)d_in[0];
  const float* Wq = (const float*)d_in[1];
  const float* Wk = (const float*)d_in[2];
  const float* Wv = (const float*)d_in[3];
  const float* Wp = (const float*)d_in[4];
  const float* qg = (const float*)d_in[5];
  float* out = (float*)d_out;

  char* ws = (char*)d_ws;
  size_t off = 0;
  auto alloc = [&](size_t bytes) {
    void* p = ws + off;
    off += (bytes + 255) & ~(size_t)255;
    return p;
  };
  u16* x_bf  = (u16*)alloc((size_t)8192 * 2048 * 2);   // also reused as y_bf
  u16* wq_bf = (u16*)alloc((size_t)2048 * 2048 * 2);   // also reused as vt_bf
  u16* wk_bf = (u16*)alloc((size_t)512 * 2048 * 2);    // wk|wv contiguous = KV weight
  u16* wv_bf = (u16*)alloc((size_t)512 * 2048 * 2);
  u16* wp_bf = (u16*)alloc((size_t)2048 * 2048 * 2);
  u16* q_bf  = (u16*)alloc((size_t)4 * 16 * 2048 * 128 * 2);
  u16* k_bf  = (u16*)alloc((size_t)4 * 4 * 2048 * 128 * 2);
  u16* v_bf  = (u16*)alloc((size_t)4 * 4 * 2048 * 128 * 2);
  float* tab = (float*)alloc((size_t)2032 * 64 * 2 * 4);
  u16* y_bf  = x_bf;    // x dead after QKV GEMMs
  u16* vt_bf = wq_bf;   // Wq dead after Q GEMM (same size)
  (void)wv_bf;

  prep<<<2048, 256, 0, stream>>>((const float4*)x, (const float4*)Wq,
                                 (const float4*)Wk, (const float4*)Wv,
                                 (const float4*)Wp, (uint2*)x_bf, (uint2*)wq_bf,
                                 tab, tab + 2032 * 64);
  gemm_qkv<<<dim3(512), 512, 0, stream>>>(x_bf, wq_bf, wk_bf, q_bf, k_bf, v_bf);
  norm_transpose<<<dim3(1280), 256, 0, stream>>>(k_bf, v_bf, vt_bf,
                                                 tab, tab + 2032 * 64);
  attn<<<dim3(256), 512, 0, stream>>>(q_bf, k_bf, vt_bf, y_bf, qg,
                                      tab, tab + 2032 * 64);
  gemm_proj<<<dim3(256), 512, 0, stream>>>(y_bf, wp_bf, out);
}

// Round 17
// 324.968 us; speedup vs baseline: 1.1521x; 1.0022x over previous
//
#include <hip/hip_runtime.h>
#include <stdint.h>

// Shapes (fixed): B=4 L=2048 D=2048 H=16 KVH=4 HD=128 M=16 T=2032
typedef unsigned short u16;
typedef short s8v __attribute__((ext_vector_type(8)));   // 8 bf16 (4 VGPR) MFMA frag
typedef float f4v __attribute__((ext_vector_type(4)));   // 16x16 MFMA accum
typedef float f16v __attribute__((ext_vector_type(16))); // 32x32 MFMA accum

typedef __attribute__((address_space(1))) char gchar;
typedef __attribute__((address_space(3))) char lchar;

static __device__ __forceinline__ u16 f2bf(float f) {
  uint32_t x = __float_as_uint(f);
  x += 0x7fffu + ((x >> 16) & 1u);            // RNE
  return (u16)(x >> 16);
}
static __device__ __forceinline__ float bf2f(u16 u) {
  return __uint_as_float(((uint32_t)u) << 16);
}
// async global->LDS, 16B per lane. LDS dest must be wave-linear (base + lane*16).
static __device__ __forceinline__ void gload_lds16(const void* g, void* l) {
  __builtin_amdgcn_global_load_lds((gchar*)(uintptr_t)g,
                                   (lchar*)(uint32_t)(uintptr_t)l, 16, 0, 0);
}

// ---------------- prep: x->bf16, weights->bf16, rope table (one launch) ----------------
__global__ __launch_bounds__(256) void prep(const float4* __restrict__ x,
                                            const float4* __restrict__ wq,
                                            const float4* __restrict__ wk,
                                            const float4* __restrict__ wv,
                                            const float4* __restrict__ wp,
                                            uint2* __restrict__ xbf,
                                            uint2* __restrict__ wbf,
                                            float* __restrict__ tc,
                                            float* __restrict__ ts) {
  const int gid = blockIdx.x * 256 + threadIdx.x;
  const int st = gridDim.x * 256;
  for (int i = gid; i < 4194304; i += st) {            // x: 8192x2048 fp32
    float4 v = x[i];
    uint2 o;
    o.x = (uint32_t)f2bf(v.x) | ((uint32_t)f2bf(v.y) << 16);
    o.y = (uint32_t)f2bf(v.z) | ((uint32_t)f2bf(v.w) << 16);
    xbf[i] = o;
  }
  for (int i = gid; i < 2621440; i += st) {            // wq|wk|wv|wp contiguous dst
    const float4* s;
    int off;
    if (i < 1048576)      { s = wq; off = i; }
    else if (i < 1310720) { s = wk; off = i - 1048576; }
    else if (i < 1572864) { s = wv; off = i - 1310720; }
    else                  { s = wp; off = i - 1572864; }
    float4 v = s[off];
    uint2 o;
    o.x = (uint32_t)f2bf(v.x) | ((uint32_t)f2bf(v.y) << 16);
    o.y = (uint32_t)f2bf(v.z) | ((uint32_t)f2bf(v.w) << 16);
    wbf[i] = o;
  }
  for (int i = gid; i < 2032 * 64; i += st) {          // rope table [T][64]
    int t = i >> 6, f = i & 63;
    float invf = 1.0f / powf(10000.0f, (float)f * (1.0f / 64.0f));
    float ang = (float)t * invf;
    float s, c;
    sincosf(ang, &s, &c);
    tc[i] = c;
    ts[i] = s;
  }
}

// ---------------- gemm8 body v2: 256x256, K-half region phases ----------------
// R16 audit: quadrant phases re-read every B frag twice -> 32 ds_read/wave/tile,
// LDS 2048cy ~= MFMA 2065cy (1:1, R9's balance bug) + 9 barriers/tile.
// v2 = R10-verified gemm_kv region template widened to BN=256 / 4 N-waves:
//   regions [bs][ks] (A 16KB, B 16KB); phase ks: 12 ds_read (each frag ONCE),
//   lgkmcnt(0)+sched_barrier+s_barrier (WAR: region read by ALL waves),
//   stage tile t+2's [A,B][ks] halves (4 loads) into just-freed region,
//   setprio'd 32 MFMA. Tile top: vmcnt(8) (t+1's 8 loads in flight) + barrier
//   (RAW). 24 reads + 64 MFMA + 3 barriers per tile (was 32/64/9).
// FIFO ledger: steady outstanding at top = t's 8 + t+1's 8; vmcnt(8) drains
// exactly tile t's; epilogue vmcnt(0) at t=NT-1 (t+2 stages skipped earlier).
// Row-major XCD chunk (R16-verified: FETCH 268->82MB).
template <int OUT>
static __device__ __forceinline__ void gemm8_body(
    u16* sm, int bid, const u16* __restrict__ A, const u16* __restrict__ Wt,
    u16* __restrict__ Oa, float* __restrict__ OF) {
  const int tid = threadIdx.x;
  const int lane = tid & 63, wid = tid >> 6;
  const int wr = wid >> 2, wc = wid & 3;         // 2M x 4N, wave-tile 128x64
  const int l15 = lane & 15, l4 = lane >> 4;

  const int swz = (bid & 7) * 32 + (bid >> 3);   // XCD chunk (256-block path)
  const int bm = swz >> 3, bn = swz & 7;         // ROW-major: 4 A-rows per XCD
  const int m0 = bm * 256;
  const int n0r = bn * 256;

  auto pA = [&](int bs, int ks) { return sm + (bs * 2 + ks) * 8192; };
  auto pB = [&](int bs, int ks) { return sm + 32768 + (bs * 2 + ks) * 8192; };

  auto stage_part = [&](int kt, int bs, int ks) {
    const int kb = kt * 64 + ks * 32;
#pragma unroll
    for (int c = 0; c < 2; ++c) {                // A half: 256x32 = 1024 chunks
      int cidx = tid + c * 512;
      int r = cidx >> 2, q = cidx & 3;
      int cc = q ^ ((r >> 2) & 3);
      gload_lds16(A + (size_t)(m0 + r) * 2048 + kb + cc * 8,
                  pA(bs, ks) + cidx * 8);
    }
#pragma unroll
    for (int c = 0; c < 2; ++c) {                // B half: 256x32 = 1024 chunks
      int cidx = tid + c * 512;
      int r = cidx >> 2, q = cidx & 3;
      int cc = q ^ ((r >> 2) & 3);
      gload_lds16(Wt + (size_t)(n0r + r) * 2048 + kb + cc * 8,
                  pB(bs, ks) + cidx * 8);
    }
  };
  auto roff = [&](int fr, int c) {               // u16 index within a region
    return (fr * 4 + (c ^ ((fr >> 2) & 3))) * 8;
  };

  const f4v Z4 = {0.f, 0.f, 0.f, 0.f};
  f4v acc[8][4];
#pragma unroll
  for (int i = 0; i < 8; i++)
#pragma unroll
    for (int j = 0; j < 4; j++) acc[i][j] = Z4;

  // prologue: tiles 0,1 fully staged (16 loads/thread outstanding)
  stage_part(0, 0, 0); stage_part(0, 0, 1);
  stage_part(1, 1, 0); stage_part(1, 1, 1);

  const int NT = 32;                 // 2048 / 64
  for (int t = 0; t < NT; ++t) {
    const int bs = t & 1;
    if (t + 1 < NT) asm volatile("s_waitcnt vmcnt(8)" ::: "memory");
    else            asm volatile("s_waitcnt vmcnt(0)" ::: "memory");
    asm volatile("s_barrier" ::: "memory");      // RAW: ALL waves' tile t landed
    const bool pf = (t + 2 < NT);
#pragma unroll
    for (int ks = 0; ks < 2; ++ks) {
      s8v a[8], b[4];
#pragma unroll
      for (int i = 0; i < 8; ++i)
        a[i] = *(const s8v*)&pA(bs, ks)[roff(wr * 128 + i * 16 + l15, l4)];
#pragma unroll
      for (int j = 0; j < 4; ++j)
        b[j] = *(const s8v*)&pB(bs, ks)[roff(wc * 64 + j * 16 + l15, l4)];
      asm volatile("s_waitcnt lgkmcnt(0)" ::: "memory");
      __builtin_amdgcn_sched_barrier(0);
      asm volatile("s_barrier" ::: "memory");    // WAR: region [bs][ks] fully read
      if (pf) stage_part(t + 2, bs, ks);         // overwrite the freed region
      __builtin_amdgcn_s_setprio(1);
#pragma unroll
      for (int i = 0; i < 8; ++i)
#pragma unroll
        for (int j = 0; j < 4; ++j)
          acc[i][j] = __builtin_amdgcn_mfma_f32_16x16x32_bf16(a[i], b[j], acc[i][j], 0, 0, 0);
      __builtin_amdgcn_s_setprio(0);
      // no trailing barrier: next phase reads [bs][ks^1]; next tile gated at top
    }
  }

  const int colg = bn * 256 + wc * 64;
  if constexpr (OUT == 0) {                      // Q: (B,16,L,128) bf16
    const int hh = colg >> 7, d0 = colg & 127;
#pragma unroll
    for (int i = 0; i < 8; i++)
#pragma unroll
      for (int r = 0; r < 4; r++) {
        int m = m0 + wr * 128 + i * 16 + l4 * 4 + r;
        int b2 = m >> 11, l = m & 2047;
        size_t base = ((size_t)(b2 * 16 + hh) * 2048 + l) * 128 + d0;
#pragma unroll
        for (int j = 0; j < 4; j++)
          Oa[base + j * 16 + l15] = f2bf(acc[i][j][r]);
      }
  } else {                                       // proj: fp32 row-major
#pragma unroll
    for (int i = 0; i < 8; i++)
#pragma unroll
      for (int r = 0; r < 4; r++) {
        int m = m0 + wr * 128 + i * 16 + l4 * 4 + r;
#pragma unroll
        for (int j = 0; j < 4; j++)
          OF[(size_t)m * 2048 + colg + j * 16 + l15] = acc[i][j][r];
      }
  }
}

// ---------------- gemm_kv body: 256x128 region structure (R10, row-major XCD) ----------------
static __device__ __forceinline__ void gemm_kv_body(
    u16* sm, int bid, const u16* __restrict__ A, const u16* __restrict__ Wt,
    u16* __restrict__ Oa, u16* __restrict__ Ob2) {
  constexpr int MI = 4;
  const int tid = threadIdx.x;
  const int lane = tid & 63, wid = tid >> 6;
  const int wr = wid >> 1, wc = wid & 1;
  const int l15 = lane & 15, l4 = lane >> 4;

  const int swz = (bid & 7) * 32 + (bid >> 3);
  const int bm = swz >> 3, bn = swz & 7;         // ROW-major chunk
  const int m0 = bm * 256;
  const int n0r = bn * 128;

  auto pA = [&](int bs, int ks) { return sm + (bs * 2 + ks) * 8192; };
  auto pB = [&](int bs, int ks) { return sm + 32768 + (bs * 2 + ks) * 4096; };

  auto stage_part = [&](int kt, int bs, int ks) {
    const int kb = kt * 64 + ks * 32;
#pragma unroll
    for (int c = 0; c < 2; ++c) {
      int cidx = tid + c * 512;
      int r = cidx >> 2, q = cidx & 3;
      int cc = q ^ ((r >> 2) & 3);
      gload_lds16(A + (size_t)(m0 + r) * 2048 + kb + cc * 8,
                  pA(bs, ks) + cidx * 8);
    }
    {
      int cidx = tid;
      int r = cidx >> 2, q = cidx & 3;
      int cc = q ^ ((r >> 2) & 3);
      gload_lds16(Wt + (size_t)(n0r + r) * 2048 + kb + cc * 8,
                  pB(bs, ks) + cidx * 8);
    }
  };
  auto roff = [&](int fr, int c) {
    return (fr * 4 + (c ^ ((fr >> 2) & 3))) * 8;
  };

  const f4v Z4 = {0.f, 0.f, 0.f, 0.f};
  f4v acc[MI][4];
#pragma unroll
  for (int i = 0; i < MI; i++)
#pragma unroll
    for (int j = 0; j < 4; j++) acc[i][j] = Z4;

  stage_part(0, 0, 0); stage_part(0, 0, 1);
  stage_part(1, 1, 0); stage_part(1, 1, 1);

  const int NT = 32;
  for (int t = 0; t < NT; ++t) {
    const int bs = t & 1;
    if (t + 1 < NT) asm volatile("s_waitcnt vmcnt(6)" ::: "memory");
    else            asm volatile("s_waitcnt vmcnt(0)" ::: "memory");
    asm volatile("s_barrier" ::: "memory");
    const bool pf = (t + 2 < NT);
#pragma unroll
    for (int ks = 0; ks < 2; ++ks) {
      s8v afrg[MI], bfrg[4];
#pragma unroll
      for (int i = 0; i < MI; ++i)
        afrg[i] = *(const s8v*)&pA(bs, ks)[roff(wr * (MI * 16) + i * 16 + l15, l4)];
#pragma unroll
      for (int j = 0; j < 4; ++j)
        bfrg[j] = *(const s8v*)&pB(bs, ks)[roff(wc * 64 + j * 16 + l15, l4)];
      asm volatile("s_waitcnt lgkmcnt(0)" ::: "memory");
      __builtin_amdgcn_sched_barrier(0);
      asm volatile("s_barrier" ::: "memory");
      if (pf) stage_part(t + 2, bs, ks);
      __builtin_amdgcn_s_setprio(1);
#pragma unroll
      for (int i = 0; i < MI; ++i)
#pragma unroll
        for (int j = 0; j < 4; ++j)
          acc[i][j] = __builtin_amdgcn_mfma_f32_16x16x32_bf16(afrg[i], bfrg[j], acc[i][j], 0, 0, 0);
      __builtin_amdgcn_s_setprio(0);
    }
  }

  const int colg = bn * 128 + wc * 64;
  u16* Ob = (colg < 512) ? Oa : Ob2;
  const int hh = (colg & 511) >> 7, d0 = colg & 127;
#pragma unroll
  for (int i = 0; i < MI; i++)
#pragma unroll
    for (int r = 0; r < 4; r++) {
      int m = m0 + wr * (MI * 16) + i * 16 + l4 * 4 + r;
      int b = m >> 11, l = m & 2047;
      size_t base = ((size_t)(b * 4 + hh) * 2048 + l) * 128 + d0;
#pragma unroll
      for (int j = 0; j < 4; j++)
        Ob[base + j * 16 + l15] = f2bf(acc[i][j][r]);
    }
}

// ---------------- merged QKV GEMM: 512 blocks = 256 Q-path + 256 KV-path ----------------
__global__ __launch_bounds__(512, 2) void gemm_qkv(
    const u16* __restrict__ x, const u16* __restrict__ wq,
    const u16* __restrict__ wkv, u16* __restrict__ q,
    u16* __restrict__ kO, u16* __restrict__ vO) {
  __shared__ u16 smem[65536];                    // 128KB arena (both paths fit)
  const int bid = (int)blockIdx.x;
  if (bid < 256) gemm8_body<0>(smem, bid, x, wq, q, nullptr);
  else           gemm_kv_body(smem, bid - 256, x, wkv, kO, vO);
}

// ---------------- proj GEMM (gemm8 path, own launch) ----------------
__global__ __launch_bounds__(512, 2) void gemm_proj(
    const u16* __restrict__ y, const u16* __restrict__ wp, float* __restrict__ out) {
  __shared__ u16 smem[65536];
  gemm8_body<2>(smem, (int)blockIdx.x, y, wp, nullptr, out);
}

// ---------------- merged K-norm + V-transpose (1280 blocks) ----------------
__global__ __launch_bounds__(256) void norm_transpose(
    u16* __restrict__ kbuf, const u16* __restrict__ v, u16* __restrict__ vt,
    const float* __restrict__ tc, const float* __restrict__ ts) {
  __shared__ u16 t[64][64];
  const int bid = (int)blockIdx.x;
  const int tid = threadIdx.x;
  if (bid < 1024) {
    const int l0 = (bid & 31) * 64, d0 = ((bid >> 5) & 1) * 64, bg = bid >> 6;
#pragma unroll
    for (int it = 0; it < 2; ++it) {
      int lin = it * 256 + tid;
      int r = lin >> 3, cb = lin & 7;
      s8v val = *(const s8v*)&v[((bg * 2048 + l0 + r) * 128) + d0 + cb * 8];
      *(s8v*)&t[r][(cb ^ (r & 7)) * 8] = val;
    }
    __syncthreads();
#pragma unroll
    for (int it = 0; it < 2; ++it) {
      int lin = it * 256 + tid;
      int r2 = lin >> 3, c2 = (lin & 7) * 8;
      s8v o;
#pragma unroll
      for (int j = 0; j < 8; ++j) {
        int rr = c2 + j, cc = r2;
        o[j] = (short)t[rr][(cc & 7) + 8 * ((cc >> 3) ^ (rr & 7))];
      }
      *(s8v*)&vt[((bg * 128 + d0 + r2) * 2048) + l0 + c2] = o;
    }
  } else {
    const int lane = tid & 63;
    const int gw = (bid - 1024) * 4 + (tid >> 6);
    for (int row = gw; row < 32768; row += 1024) {
      int l = row & 2047;
      u16* p = kbuf + (size_t)row * 128;
      float x1 = bf2f(p[lane]);
      float x2 = bf2f(p[lane + 64]);
      float ss = x1 * x1 + x2 * x2;
#pragma unroll
      for (int off = 32; off > 0; off >>= 1) ss += __shfl_xor(ss, off, 64);
      float r = rsqrtf(ss * (1.0f / 128.0f) + 1.1920929e-07f);
      x1 *= r; x2 *= r;
      if (l >= 16) {
        int tt = l - 16;
        float c = tc[tt * 64 + lane], s = ts[tt * 64 + lane];
        float o1 = x1 * c + x2 * s;
        float o2 = -x1 * s + x2 * c;
        x1 = o1; x2 = o2;
      }
      p[lane] = f2bf(x1);
      p[lane + 64] = f2bf(x2);
    }
  }
}

// ---------------- flash attention v3 (R16: full-width swizzle + tree softmax) ----------------
__global__ __launch_bounds__(512, 2) void attn(const u16* __restrict__ q,
                                               const u16* __restrict__ k,
                                               const u16* __restrict__ vt,
                                               u16* __restrict__ y,
                                               const float* __restrict__ qg,
                                               const float* __restrict__ tc,
                                               const float* __restrict__ ts) {
  __shared__ u16 lK[2][64 * 128];   // row kv: 16 chunks, phys = logical ^ (kv&15)
  __shared__ u16 lVT[2][64 * 128];  // line d>>1: 16 chunks, phys = ((d&1)*8+kc) ^ (line&15)
  const int tid = threadIdx.x;
  const int lane = tid & 63, wid = tid >> 6;
  const int l31 = lane & 31, hi = lane >> 5;

  const int bid = (int)blockIdx.x;                 // 0..255
  const int bg = (bid & 7) * 2 + (bid >> 7);       // XCD k hosts bg {2k,2k+1}
  const int pairi = (bid >> 3) & 15;               // 0..15
  const int b = bg >> 2, g = bg & 3;
  const int h = g * 4 + (wid & 3);
  const int se = wid >> 2;                         // row-half 0/1

  const u16* qh = q + (size_t)(b * 16 + h) * 2048 * 128;
  const u16* kb0 = k + (size_t)(b * 4 + g) * 2048 * 128;
  const u16* vtb0 = vt + (size_t)(b * 4 + g) * 128 * 2048;
  const float gscale = qg[h] * (0.08838834764831845f * 1.4426950408889634f);

  auto stage = [&](int t, int bufsel) {
    const int kv0 = t * 64;
#pragma unroll
    for (int it = 0; it < 2; ++it) {        // K tile 64x128 (16KB)
      int lin = it * 512 + tid;
      int kj = lin >> 4, s = lin & 15;
      gload_lds16(kb0 + (size_t)(kv0 + kj) * 128 + ((s ^ (kj & 15)) * 8),
                  &lK[bufsel][lin * 8]);
    }
#pragma unroll
    for (int it = 0; it < 2; ++it) {        // VT tile 128x64 (16KB), paired-d lines
      int lin = it * 512 + tid;
      int r = lin >> 4, c = lin & 15;
      int gl = c ^ (r & 15);
      int d = 2 * r + (gl >> 3);
      gload_lds16(vtb0 + (size_t)d * 2048 + kv0 + ((gl & 7) * 8),
                  &lVT[bufsel][lin * 8]);
    }
  };

  for (int ph = 0; ph < 2; ++ph) {
    const int qt = ph ? (31 - pairi) : pairi;
    const int q0 = qt * 64;
    const int nt = qt + 1;                  // KV tiles of 64
    const int pos = q0 + 32 * se + l31;

    // ---- fused Q: RMSNorm + RoPE + gain*(1/sqrt(128))*log2(e), pack B-frags ----
    s8v qf[8];
    {
      const u16* qp = qh + (size_t)pos * 128 + hi * 8;
      s8v qr[8];
#pragma unroll
      for (int ks = 0; ks < 8; ++ks) qr[ks] = *(const s8v*)&qp[ks * 16];
      float ssum = 0.f;
#pragma unroll
      for (int ks = 0; ks < 8; ++ks)
#pragma unroll
        for (int j = 0; j < 8; ++j) {
          float v = bf2f((u16)qr[ks][j]);
          ssum += v * v;
        }
      ssum += __shfl_xor(ssum, 32, 64);
      const float rn = rsqrtf(ssum * (1.0f / 128.0f) + 1.1920929e-07f) * gscale;
      const bool rot = (pos >= 16);
      const int tt = pos - 16;
#pragma unroll
      for (int ks = 0; ks < 4; ++ks) {
        float cv[8], sv[8];
        if (rot) {
          const float* cp = &tc[tt * 64 + ks * 16 + hi * 8];
          const float* sp = &ts[tt * 64 + ks * 16 + hi * 8];
          *(float4*)&cv[0] = *(const float4*)cp;
          *(float4*)&cv[4] = *(const float4*)(cp + 4);
          *(float4*)&sv[0] = *(const float4*)sp;
          *(float4*)&sv[4] = *(const float4*)(sp + 4);
        }
        uint32_t wlo[4], whi[4];
#pragma unroll
        for (int j2 = 0; j2 < 4; ++j2) {
          float o1[2], o2[2];
#pragma unroll
          for (int e = 0; e < 2; ++e) {
            const int j = j2 * 2 + e;
            float x1 = bf2f((u16)qr[ks][j]);
            float x2 = bf2f((u16)qr[ks + 4][j]);
            float a = x1, bb = x2;
            if (rot) { a = x1 * cv[j] + x2 * sv[j]; bb = x2 * cv[j] - x1 * sv[j]; }
            o1[e] = a * rn;
            o2[e] = bb * rn;
          }
          asm("v_cvt_pk_bf16_f32 %0, %1, %2" : "=v"(wlo[j2]) : "v"(o1[0]), "v"(o1[1]));
          asm("v_cvt_pk_bf16_f32 %0, %1, %2" : "=v"(whi[j2]) : "v"(o2[0]), "v"(o2[1]));
        }
        union { uint32_t u[4]; s8v v; } ua, ub;
        ua.u[0] = wlo[0]; ua.u[1] = wlo[1]; ua.u[2] = wlo[2]; ua.u[3] = wlo[3];
        ub.u[0] = whi[0]; ub.u[1] = whi[1]; ub.u[2] = whi[2]; ub.u[3] = whi[3];
        qf[ks] = ua.v;
        qf[ks + 4] = ub.v;
      }
    }

    f16v yacc[4];
#pragma unroll
    for (int j = 0; j < 4; ++j)
#pragma unroll
      for (int r = 0; r < 16; ++r) yacc[j][r] = 0.f;
    float mrow = -1e30f, lrow = 0.f;

    stage(0, 0);
    __syncthreads();

    for (int t = 0; t < nt; ++t) {
      const int cur = t & 1;
      if (t + 1 < nt) stage(t + 1, cur ^ 1);
      const int kv0 = t * 64;

      // ---- QK^T swapped: S^T[kv][q] in exp2 domain, two 32-kv chunks ----
      f16v s0a, s1a;
#pragma unroll
      for (int r = 0; r < 16; ++r) { s0a[r] = 0.f; s1a[r] = 0.f; }
      __builtin_amdgcn_s_setprio(1);
#pragma unroll
      for (int ks = 0; ks < 8; ++ks) {
        const int slot = (2 * ks + hi) ^ (l31 & 15);
        s8v kf0 = *(const s8v*)&lK[cur][(l31)*128 + slot * 8];
        s8v kf1 = *(const s8v*)&lK[cur][(32 + l31) * 128 + slot * 8];
        s0a = __builtin_amdgcn_mfma_f32_32x32x16_bf16(kf0, qf[ks], s0a, 0, 0, 0);
        s1a = __builtin_amdgcn_mfma_f32_32x32x16_bf16(kf1, qf[ks], s1a, 0, 0, 0);
      }
      __builtin_amdgcn_s_setprio(0);

      // ---- causal mask + row max (tree-reduced) ----
      const bool last = (t == nt - 1);
      float p0[16], p1[16], mx[16];
#pragma unroll
      for (int r = 0; r < 16; ++r) {
        const int kvloc = (r & 3) + 8 * (r >> 2) + 4 * hi;
        float v0 = s0a[r];
        float v1 = s1a[r];
        if (last) {
          if (kv0 + kvloc > pos) v0 = -1e30f;
          if (kv0 + 32 + kvloc > pos) v1 = -1e30f;
        }
        p0[r] = v0; p1[r] = v1;
        mx[r] = fmaxf(v0, v1);
      }
#pragma unroll
      for (int s2 = 8; s2 > 0; s2 >>= 1)
#pragma unroll
        for (int r = 0; r < s2; ++r) mx[r] = fmaxf(mx[r], mx[r + s2]);
      float pmax = fmaxf(mx[0], __shfl_xor(mx[0], 32, 64));

      // ---- defer-max (T13): THR = 8*log2e in exp2 domain ----
      if (!__all(pmax - mrow <= 11.541560327111707f)) {
        float mnew = fmaxf(mrow, pmax);
        float corr = __builtin_amdgcn_exp2f(mrow - mnew);
#pragma unroll
        for (int r = 0; r < 16; ++r) {
          const int qloc = (r & 3) + 8 * (r >> 2) + 4 * hi;
          float cb = __shfl(corr, qloc, 64);
          yacc[0][r] *= cb; yacc[1][r] *= cb; yacc[2][r] *= cb; yacc[3][r] *= cb;
        }
        lrow *= corr;
        mrow = mnew;
      }

      // ---- exp2 + fp32 row sum (tree-reduced) ----
      float sm[16];
#pragma unroll
      for (int r = 0; r < 16; ++r) {
        float e0 = __builtin_amdgcn_exp2f(p0[r] - mrow);
        float e1 = __builtin_amdgcn_exp2f(p1[r] - mrow);
        p0[r] = e0; p1[r] = e1;
        sm[r] = e0 + e1;
      }
#pragma unroll
      for (int s2 = 8; s2 > 0; s2 >>= 1)
#pragma unroll
        for (int r = 0; r < s2; ++r) sm[r] += sm[r + s2];
      float ps = sm[0] + __shfl_xor(sm[0], 32, 64);
      lrow += ps;

      // ---- PV: cvt_pk pack + permlane32_swap exchange + MFMA ----
      __builtin_amdgcn_s_setprio(1);
#pragma unroll
      for (int ks = 0; ks < 4; ++ks) {
        const float* pc = (ks < 2) ? p0 : p1;
        const int rb = 8 * (ks & 1);
        uint32_t A0, A1, B0, B1;
        asm("v_cvt_pk_bf16_f32 %0, %1, %2" : "=v"(A0) : "v"(pc[rb + 0]), "v"(pc[rb + 1]));
        asm("v_cvt_pk_bf16_f32 %0, %1, %2" : "=v"(A1) : "v"(pc[rb + 2]), "v"(pc[rb + 3]));
        asm("v_cvt_pk_bf16_f32 %0, %1, %2" : "=v"(B0) : "v"(pc[rb + 4]), "v"(pc[rb + 5]));
        asm("v_cvt_pk_bf16_f32 %0, %1, %2" : "=v"(B1) : "v"(pc[rb + 6]), "v"(pc[rb + 7]));
        // after swap: A0 = [A0_lo|B0_lo] = uu0, B0 = [A0_hi|B0_hi] = uu2 (ditto A1/B1)
        asm("v_permlane32_swap_b32 %0, %1" : "+v"(A0), "+v"(B0));
        asm("v_permlane32_swap_b32 %0, %1" : "+v"(A1), "+v"(B1));
        union { uint32_t u[4]; s8v v; } uu;
        uu.u[0] = A0; uu.u[1] = A1; uu.u[2] = B0; uu.u[3] = B1;
#pragma unroll
        for (int jd = 0; jd < 4; ++jd) {
          const int rowd = 32 * jd + l31;
          const int line = rowd >> 1;
          const int gl = ((rowd & 1) << 3) | (2 * ks + hi);
          const int c = gl ^ (line & 15);
          s8v vf = *(const s8v*)&lVT[cur][line * 128 + c * 8];
          yacc[jd] = __builtin_amdgcn_mfma_f32_32x32x16_bf16(uu.v, vf, yacc[jd], 0, 0, 0);
        }
      }
      __builtin_amdgcn_s_setprio(0);
      __syncthreads();
    }

    // ---- finalize: broadcast 1/l per C-row, write y (B,L,H*128) bf16 ----
    float inv = 1.0f / lrow;
#pragma unroll
    for (int r = 0; r < 16; ++r) {
      const int qloc = (r & 3) + 8 * (r >> 2) + 4 * hi;
      float ib = __shfl(inv, qloc, 64);
      const int qrow = q0 + 32 * se + qloc;
      size_t base = ((size_t)(b * 2048 + qrow)) * 2048 + h * 128 + l31;
#pragma unroll
      for (int jd = 0; jd < 4; ++jd)
        y[base + 32 * jd] = f2bf(yacc[jd][r] * ib);
    }
  }
}

extern "C" void kernel_launch(void* const* d_in, const int* in_sizes, int n_in,
                              void* d_out, int out_size, void* d_ws, size_t ws_size,
                              hipStream_t stream) {
  const float* x  = (const float*)d_in[0];
  const float* Wq = (const float*)d_in[1];
  const float* Wk = (const float*)d_in[2];
  const float* Wv = (const float*)d_in[3];
  const float* Wp = (const float*)d_in[4];
  const float* qg = (const float*)d_in[5];
  float* out = (float*)d_out;

  char* ws = (char*)d_ws;
  size_t off = 0;
  auto alloc = [&](size_t bytes) {
    void* p = ws + off;
    off += (bytes + 255) & ~(size_t)255;
    return p;
  };
  u16* x_bf  = (u16*)alloc((size_t)8192 * 2048 * 2);   // also reused as y_bf
  u16* wq_bf = (u16*)alloc((size_t)2048 * 2048 * 2);   // also reused as vt_bf
  u16* wk_bf = (u16*)alloc((size_t)512 * 2048 * 2);    // wk|wv contiguous = KV weight
  u16* wv_bf = (u16*)alloc((size_t)512 * 2048 * 2);
  u16* wp_bf = (u16*)alloc((size_t)2048 * 2048 * 2);
  u16* q_bf  = (u16*)alloc((size_t)4 * 16 * 2048 * 128 * 2);
  u16* k_bf  = (u16*)alloc((size_t)4 * 4 * 2048 * 128 * 2);
  u16* v_bf  = (u16*)alloc((size_t)4 * 4 * 2048 * 128 * 2);
  float* tab = (float*)alloc((size_t)2032 * 64 * 2 * 4);
  u16* y_bf  = x_bf;    // x dead after QKV GEMMs
  u16* vt_bf = wq_bf;   // Wq dead after Q GEMM (same size)
  (void)wv_bf;

  prep<<<2048, 256, 0, stream>>>((const float4*)x, (const float4*)Wq,
                                 (const float4*)Wk, (const float4*)Wv,
                                 (const float4*)Wp, (uint2*)x_bf, (uint2*)wq_bf,
                                 tab, tab + 2032 * 64);
  gemm_qkv<<<dim3(512), 512, 0, stream>>>(x_bf, wq_bf, wk_bf, q_bf, k_bf, v_bf);
  norm_transpose<<<dim3(1280), 256, 0, stream>>>(k_bf, v_bf, vt_bf,
                                                 tab, tab + 2032 * 64);
  attn<<<dim3(256), 512, 0, stream>>>(q_bf, k_bf, vt_bf, y_bf, qg,
                                      tab, tab + 2032 * 64);
  gemm_proj<<<dim3(256), 512, 0, stream>>>(y_bf, wp_bf, out);
}